// Round 15
// baseline (203.625 us; speedup 1.0000x reference)
//
#include <hip/hip_runtime.h>

typedef _Float16 f16;
typedef _Float16 f16x4 __attribute__((ext_vector_type(4)));
typedef _Float16 f16x8 __attribute__((ext_vector_type(8)));
typedef float f32x4 __attribute__((ext_vector_type(4)));

#define AS1 __attribute__((address_space(1)))
#define AS3 __attribute__((address_space(3)))

__device__ __forceinline__ void gl_lds16(const f16* g, f16* l) {
  __builtin_amdgcn_global_load_lds((const AS1 void*)g, (AS3 void*)l, 16, 0, 0);
}

// ---------------- LayerNorm: x (fp32) -> H (f16), one WAVE per row ----------------
__global__ __launch_bounds__(256) void ln_kernel(const float* __restrict__ x,
                                                 const float* __restrict__ gw,
                                                 const float* __restrict__ gb,
                                                 f16* __restrict__ H) {
  const int wv = threadIdx.x >> 6, lane = threadIdx.x & 63;
  const long row = (long)blockIdx.x * 4 + wv;
  const float* xr = x + row * 1024;
  float4 v[4];
  float s = 0.f, s2 = 0.f;
#pragma unroll
  for (int j = 0; j < 4; ++j) {
    v[j] = ((const float4*)xr)[lane + 64 * j];
    s  += v[j].x + v[j].y + v[j].z + v[j].w;
    s2 += v[j].x * v[j].x + v[j].y * v[j].y + v[j].z * v[j].z + v[j].w * v[j].w;
  }
#pragma unroll
  for (int off = 32; off > 0; off >>= 1) {
    s  += __shfl_xor(s, off);
    s2 += __shfl_xor(s2, off);
  }
  const float mu = s * (1.0f / 1024.0f);
  const float rstd = rsqrtf(s2 * (1.0f / 1024.0f) - mu * mu + 1e-5f);
#pragma unroll
  for (int j = 0; j < 4; ++j) {
    const float4 w4 = ((const float4*)gw)[lane + 64 * j];
    const float4 b4 = ((const float4*)gb)[lane + 64 * j];
    f16x4 h;
    h[0] = (f16)((v[j].x - mu) * rstd * w4.x + b4.x);
    h[1] = (f16)((v[j].y - mu) * rstd * w4.y + b4.y);
    h[2] = (f16)((v[j].z - mu) * rstd * w4.z + b4.z);
    h[3] = (f16)((v[j].w - mu) * rstd * w4.w + b4.w);
    *(f16x4*)(H + row * 1024 + (lane + 64 * j) * 4) = h;
  }
}

// ---------------- transpose H -> Ht, fused colsum ----------------
__global__ __launch_bounds__(256) void transpose_cs_kernel(const f16* __restrict__ H,
                                                           f16* __restrict__ Ht,
                                                           float* __restrict__ hs) {
  __shared__ f16 tile[64][68];
  __shared__ float csum[4][64];
  const int b = blockIdx.z;
  const long Hb  = (long)b * 4096 * 1024;
  const long Htb = (long)b * 1024 * 4096;
  const int t0 = blockIdx.y * 64, c0 = blockIdx.x * 64;
  const int tid = threadIdx.x;
  const int r = tid >> 2, g0 = tid & 3;
#pragma unroll
  for (int i = 0; i < 4; ++i) {
    const int g = g0 + i * 4;
    f16x4 v = *(const f16x4*)(H + Hb + (long)(t0 + r) * 1024 + c0 + g * 4);
    *(f16x4*)&tile[r][g * 4] = v;
  }
  __syncthreads();
  {
    const int cl = tid & 63, rg = tid >> 6;
    float s = 0.f;
#pragma unroll
    for (int rr = 0; rr < 16; ++rr) s += (float)tile[rg * 16 + rr][cl];
    csum[rg][cl] = s;
  }
#pragma unroll
  for (int i = 0; i < 4; ++i) {
    const int g = g0 + i * 4;
    f16x4 v;
    v[0] = tile[g * 4 + 0][r];
    v[1] = tile[g * 4 + 1][r];
    v[2] = tile[g * 4 + 2][r];
    v[3] = tile[g * 4 + 3][r];
    *(f16x4*)(Ht + Htb + (long)(c0 + r) * 4096 + t0 + g * 4) = v;
  }
  __syncthreads();
  if (tid < 64)
    atomicAdd(&hs[b * 1024 + c0 + tid],
              csum[0][tid] + csum[1][tid] + csum[2][tid] + csum[3][tid]);
}

// ---------------- transcast4: z=0..2 transpose qkv (z>=1 also straight cast), z=3 cast proj ----------------
__global__ __launch_bounds__(256) void transcast4(const float* __restrict__ qkv_w,
                                                  const float* __restrict__ proj_w,
                                                  f16* __restrict__ WT3,
                                                  f16* __restrict__ Wh,
                                                  f16* __restrict__ Ph) {
  const int z = blockIdx.z;
  __shared__ f16 tile[64][68];
  const int r0 = blockIdx.y * 64, c0 = blockIdx.x * 64;
  const int tid = threadIdx.x;
  const int r = tid >> 2, g0 = tid & 3;
  if (z == 3) {
#pragma unroll
    for (int i = 0; i < 4; ++i) {
      const int g = g0 + i * 4;
      float4 v = *(const float4*)(proj_w + (long)(r0 + r) * 1024 + c0 + g * 4);
      f16x4 h; h[0]=(f16)v.x; h[1]=(f16)v.y; h[2]=(f16)v.z; h[3]=(f16)v.w;
      *(f16x4*)(Ph + (long)(r0 + r) * 1024 + c0 + g * 4) = h;
    }
    return;
  }
  const float* W = qkv_w + (long)z * 1048576;
  f16* WT = WT3 + (long)z * 1048576;
#pragma unroll
  for (int i = 0; i < 4; ++i) {
    const int g = g0 + i * 4;
    float4 v = *(const float4*)(W + (long)(r0 + r) * 1024 + c0 + g * 4);
    f16x4 h; h[0]=(f16)v.x; h[1]=(f16)v.y; h[2]=(f16)v.z; h[3]=(f16)v.w;
    *(f16x4*)&tile[r][g * 4] = h;
    if (z >= 1)
      *(f16x4*)(Wh + (long)z * 1048576 + (long)(r0 + r) * 1024 + c0 + g * 4) = h;
  }
  __syncthreads();
#pragma unroll
  for (int i = 0; i < 4; ++i) {
    const int g = g0 + i * 4;
    f16x4 v;
    v[0] = tile[g * 4 + 0][r];
    v[1] = tile[g * 4 + 1][r];
    v[2] = tile[g * 4 + 2][r];
    v[3] = tile[g * 4 + 3][r];
    *(f16x4*)(WT + (long)(c0 + r) * 1024 + r0 + g * 4) = v;
  }
}

// ---------------- f16row . f32vec, 1024 elems, one 64-lane wave ----------------
__device__ __forceinline__ float dot1024(const f16* __restrict__ row,
                                         const float* __restrict__ v) {
  const int lane = threadIdx.x & 63;
  float s = 0.f;
#pragma unroll
  for (int j = 0; j < 2; ++j) {
    const int d = (lane + 64 * j) * 8;
    f16x8 a = *(const f16x8*)(row + d);
    float4 h0 = *(const float4*)(v + d);
    float4 h1 = *(const float4*)(v + d + 4);
    s += (float)a[0] * h0.x + (float)a[1] * h0.y + (float)a[2] * h0.z + (float)a[3] * h0.w
       + (float)a[4] * h1.x + (float)a[5] * h1.y + (float)a[6] * h1.z + (float)a[7] * h1.w;
  }
#pragma unroll
  for (int off = 32; off > 0; off >>= 1) s += __shfl_down(s, off);
  return s;
}

__device__ __forceinline__ float dotf1024(const float* __restrict__ a,
                                          const float* __restrict__ v) {
  const int lane = threadIdx.x & 63;
  float s = 0.f;
#pragma unroll
  for (int j = 0; j < 4; ++j) {
    const int d = (lane + 64 * j) * 4;
    float4 x = *(const float4*)(a + d);
    float4 q = *(const float4*)(v + d);
    s += x.x * q.x + x.y * q.y + x.z * q.z + x.w * q.w;
  }
#pragma unroll
  for (int off = 32; off > 0; off >>= 1) s += __shfl_down(s, off);
  return s;
}

// ---------------- gemv3a: a = WqT.bk, y = WkT.bq, d = Ph.bv, scal[4] = bk.bq ----------------
__global__ void gemv3a(const f16* __restrict__ WT3, const f16* __restrict__ Ph,
                       const float* __restrict__ qkv_b, float* __restrict__ ayd,
                       float* __restrict__ scal) {
  if (blockIdx.x == 3072) {
    float s = dotf1024(qkv_b + 1024, qkv_b);
    if ((threadIdx.x & 63) == 0) scal[4] = s;
    return;
  }
  const int which = blockIdx.x >> 10, m = blockIdx.x & 1023;
  const f16* row;
  const float* v;
  if (which == 0)      { row = WT3 + (long)m * 1024;            v = qkv_b + 1024; } // a
  else if (which == 1) { row = WT3 + 1048576 + (long)m * 1024;  v = qkv_b; }        // y
  else                 { row = Ph + (long)m * 1024;             v = qkv_b + 2048; } // d
  float s = dot1024(row, v);
  if ((threadIdx.x & 63) == 0) ayd[which * 1024 + m] = s;
}

// ---------------- gemv3b: e = U.hs, f = PWv.hs, z = G.y; blocks >= 12288: scal[b] = hs_b.y ----------------
__global__ void gemv3b(const f16* __restrict__ U, const f16* __restrict__ PWv,
                       const f16* __restrict__ Gh, const float* __restrict__ hs,
                       const float* __restrict__ ayd, float* __restrict__ efz,
                       float* __restrict__ scal) {
  if (blockIdx.x >= 12288) {
    const int b = blockIdx.x - 12288;
    float s = dotf1024(hs + b * 1024, ayd + 1024);
    if ((threadIdx.x & 63) == 0) scal[b] = s;
    return;
  }
  const int sel = blockIdx.x >> 12, r = blockIdx.x & 4095;
  const int b = r >> 10, m = r & 1023;
  const f16* row;
  const float* v;
  if (sel == 0)      { row = U + (long)m * 1024;                       v = hs + b * 1024; }
  else if (sel == 1) { row = PWv + (long)m * 1024;                     v = hs + b * 1024; }
  else               { row = Gh + (long)b * 1048576 + (long)m * 1024;  v = ayd + 1024; }
  float s = dot1024(row, v);
  if ((threadIdx.x & 63) == 0) efz[sel * 4096 + r] = s;
}

// ---------------- c2_b[c] = (PWv_row_c . z_b + d_c*s_u_b + s_b*(f_b_c + 4096 d_c))/32 + proj_b[c] ----------------
__global__ void gemvC2n(const f16* __restrict__ PWv, const float* __restrict__ efz,
                        const float* __restrict__ ayd, const float* __restrict__ scal,
                        const float* __restrict__ proj_b, float* __restrict__ c2) {
  const int b = blockIdx.x >> 10, c = blockIdx.x & 1023;
  float s = dot1024(PWv + (long)c * 1024, efz + 8192 + b * 1024);
  if ((threadIdx.x & 63) == 0) {
    const float d = ayd[2048 + c];
    c2[b * 1024 + c] = (s + d * scal[b] + scal[4] * (efz[4096 + b * 1024 + c] + 4096.f * d))
                         * 0.03125f + proj_b[c];
  }
}

// ================= shared GEMM machinery (BK = 64) =================
#define GP64_COMMON()                                        \
  const int tid = threadIdx.x;                               \
  const int wave = tid >> 6, lane = tid & 63;                \
  const int lr = lane & 15, lk = lane >> 4;                  \
  const int srow = tid >> 3;                                 \
  const int slc  = (tid & 7) ^ (srow & 7);                   \
  const int kc0 = ((lk) ^ (lr & 7)) * 8;                     \
  const int kc1 = ((4 + lk) ^ (lr & 7)) * 8;

#define GEMM_WAIT8(NBUF_, r_)                                               \
  do {                                                                      \
    if constexpr (NBUF_ == 3) {                                             \
      if ((r_) >= 2)      asm volatile("s_waitcnt vmcnt(16)" ::: "memory"); \
      else if ((r_) == 1) asm volatile("s_waitcnt vmcnt(8)" ::: "memory");  \
      else                asm volatile("s_waitcnt vmcnt(0)" ::: "memory");  \
    } else {                                                                \
      if ((r_) >= 1)      asm volatile("s_waitcnt vmcnt(8)" ::: "memory");  \
      else                asm volatile("s_waitcnt vmcnt(0)" ::: "memory");  \
    }                                                                       \
  } while (0)

#define COMP64_HALF(asb_, bsb_, kc_)                                             \
  do {                                                                           \
    const f16* asb = (asb_);                                                     \
    const f16* bsb = (bsb_);                                                     \
    f16x8 af[4], bf[4];                                                          \
    _Pragma("unroll")                                                            \
    for (int mi = 0; mi < 4; ++mi)                                               \
      af[mi] = *(const f16x8*)(asb + (wm * 64 + mi * 16 + lr) * 64 + (kc_));     \
    _Pragma("unroll")                                                            \
    for (int ni = 0; ni < 4; ++ni)                                               \
      bf[ni] = *(const f16x8*)(bsb + (wn * 64 + ni * 16 + lr) * 64 + (kc_));     \
    _Pragma("unroll")                                                            \
    for (int mi = 0; mi < 4; ++mi)                                               \
      _Pragma("unroll")                                                          \
      for (int ni = 0; ni < 4; ++ni)                                             \
        acc[mi][ni] = __builtin_amdgcn_mfma_f32_16x16x32_f16(af[mi], bf[ni],     \
                                                             acc[mi][ni], 0, 0, 0); \
  } while (0)

#define GEMM_BODY_LOOP(NBUF_, NT_, STAGEM)                       \
  do {                                                           \
    if constexpr (NBUF_ == 3) {                                  \
      STAGEM(0, 0); STAGEM(1, 1);                                \
      int cur = 0, stg = 2;                                      \
      for (int t = 0; t < (NT_); ++t) {                          \
        if (t + 2 < (NT_)) STAGEM(stg, t + 2);                   \
        GEMM_WAIT8(3, (NT_) - 1 - t);                            \
        asm volatile("s_barrier" ::: "memory");                  \
        __builtin_amdgcn_s_setprio(1);                           \
        COMP64_HALF(&As[cur][0], &Bs[cur][0], kc0);              \
        COMP64_HALF(&As[cur][0], &Bs[cur][0], kc1);              \
        __builtin_amdgcn_s_setprio(0);                           \
        asm volatile("s_waitcnt lgkmcnt(0)" ::: "memory");       \
        asm volatile("s_barrier" ::: "memory");                  \
        cur = (cur + 1 == 3) ? 0 : cur + 1;                      \
        stg = (stg + 1 == 3) ? 0 : stg + 1;                      \
      }                                                          \
    } else {                                                     \
      STAGEM(0, 0);                                              \
      int cur = 0;                                               \
      for (int t = 0; t < (NT_); ++t) {                          \
        if (t + 1 < (NT_)) STAGEM(cur ^ 1, t + 1);               \
        GEMM_WAIT8(2, (NT_) - 1 - t);                            \
        asm volatile("s_barrier" ::: "memory");                  \
        __builtin_amdgcn_s_setprio(1);                           \
        COMP64_HALF(&As[cur][0], &Bs[cur][0], kc0);              \
        COMP64_HALF(&As[cur][0], &Bs[cur][0], kc1);              \
        __builtin_amdgcn_s_setprio(0);                           \
        asm volatile("s_waitcnt lgkmcnt(0)" ::: "memory");       \
        asm volatile("s_barrier" ::: "memory");                  \
        cur ^= 1;                                                \
      }                                                          \
    }                                                            \
  } while (0)

// ---------------- chain GEMM: 128x128, BK=64, NBUF=3 ----------------
template <int MODE>
__global__ __launch_bounds__(256) void gemm128(
    const f16* __restrict__ A, const f16* __restrict__ B, int K,
    long sA, long sB, long sC,
    f16* __restrict__ Ch,
    const float* __restrict__ dvec, const float* __restrict__ evec,
    const float* __restrict__ fvec, const float* __restrict__ avec) {
  const int b = blockIdx.z;
  A += (long)b * sA;
  B += (long)b * sB;
  const int nx = blockIdx.y & 7;
  const int ny = blockIdx.x;

  GP64_COMMON();
  const int wm = wave >> 1, wn = wave & 1;

  __shared__ __align__(16) f16 As[3][8192];
  __shared__ __align__(16) f16 Bs[3][8192];

  const long aoffs = (long)(ny * 128 + srow) * K + slc * 8;
  const long boffs = (long)(nx * 128 + srow) * K + slc * 8;

  f32x4 zero = {0.f, 0.f, 0.f, 0.f};
  f32x4 acc[4][4];
#pragma unroll
  for (int mi = 0; mi < 4; ++mi)
#pragma unroll
    for (int ni = 0; ni < 4; ++ni) acc[mi][ni] = zero;

#define STAGE(buf, kt)                                                              \
  do {                                                                              \
    f16* asb = &As[buf][0];                                                         \
    f16* bsb = &Bs[buf][0];                                                         \
    _Pragma("unroll")                                                               \
    for (int q = 0; q < 4; ++q) {                                                   \
      gl_lds16(A + aoffs + (long)q * 32 * K + (kt) * 64, asb + q * 2048 + tid * 8); \
      gl_lds16(B + boffs + (long)q * 32 * K + (kt) * 64, bsb + q * 2048 + tid * 8); \
    }                                                                               \
  } while (0)

  const int nt = K >> 6;
  GEMM_BODY_LOOP(3, nt, STAGE);
#undef STAGE

  const long cb = (long)b * sC;
  const int m0 = ny * 128 + wm * 64;
  const int n0 = nx * 128 + wn * 64;
#pragma unroll
  for (int mi = 0; mi < 4; ++mi)
#pragma unroll
    for (int ni = 0; ni < 4; ++ni)
#pragma unroll
      for (int j = 0; j < 4; ++j) {
        const int gm = m0 + mi * 16 + lk * 4 + j;
        const int gn = n0 + ni * 16 + lr;
        float val = acc[mi][ni][j];
        if constexpr (MODE == 0) {
          Ch[cb + (long)gm * 1024 + gn] = (f16)val;
        } else {
          const float dm = dvec[gm];
          const float fm = fvec[b * 1024 + gm];
          const float en = evec[b * 1024 + gn];
          const float an = avec[gn];
          val = (val + dm * en + (fm + 4096.f * dm) * an) * 0.03125f;
          Ch[cb + (long)gm * 1024 + gn] = (f16)val;
        }
      }
}

// ---------------- MERGED: G = H^T H (tri, split-K=4) + {U = WqT x WkT, PWv = Ph x WvT} ----------------
__global__ __launch_bounds__(256) void gemmGUV(const f16* __restrict__ Ht,
                                               const f16* __restrict__ WT3,
                                               const f16* __restrict__ Ph,
                                               f16* __restrict__ part,
                                               f16* __restrict__ U,
                                               f16* __restrict__ PWv) {
  GP64_COMMON();
  const int wm = wave >> 1, wn = wave & 1;

  __shared__ __align__(16) f16 As[2][8192];
  __shared__ __align__(16) f16 Bs[2][8192];

  const int bid = blockIdx.x;
  const f16 *Ab, *Bb;
  long rs;
  int tileid = 0, zz = 0, selt = 0;
  if (bid < 576) {
    tileid = bid % 36;
    zz = bid / 36;
    const int b = zz & 3, ks4 = zz >> 2;
    int ti = 0, trem = tileid;
    while (trem >= 8 - ti) { trem -= 8 - ti; ++ti; }
    const int tj = ti + trem;
    const f16* Hb = Ht + (long)b * 4194304;
    rs = 4096;
    Ab = Hb + (long)(ti * 128 + srow) * 4096 + (long)ks4 * 1024 + slc * 8;
    Bb = Hb + (long)(tj * 128 + srow) * 4096 + (long)ks4 * 1024 + slc * 8;
  } else {
    const int u = bid - 576;
    selt = (u >> 6) + 1;                 // 1: U, 2: PWv
    const int t = u & 63;
    const int ny = t >> 3, nxx = t & 7;
    const f16* A0 = (selt == 2) ? Ph : WT3;
    const f16* B0 = (selt == 2) ? (WT3 + 2097152) : (WT3 + 1048576);
    rs = 1024;
    Ab = A0 + (long)(ny * 128 + srow) * 1024 + slc * 8;
    Bb = B0 + (long)(nxx * 128 + srow) * 1024 + slc * 8;
  }

  f32x4 zero = {0.f, 0.f, 0.f, 0.f};
  f32x4 acc[4][4];
#pragma unroll
  for (int mi = 0; mi < 4; ++mi)
#pragma unroll
    for (int ni = 0; ni < 4; ++ni) acc[mi][ni] = zero;

#define STAGE(buf, kt)                                                            \
  do {                                                                            \
    f16* asb = &As[buf][0];                                                       \
    f16* bsb = &Bs[buf][0];                                                       \
    _Pragma("unroll")                                                             \
    for (int q = 0; q < 4; ++q) {                                                 \
      gl_lds16(Ab + (long)q * 32 * rs + (kt) * 64, asb + q * 2048 + tid * 8);     \
      gl_lds16(Bb + (long)q * 32 * rs + (kt) * 64, bsb + q * 2048 + tid * 8);     \
    }                                                                             \
  } while (0)

  GEMM_BODY_LOOP(2, 16, STAGE);
#undef STAGE

  if (selt == 0) {
    f16* P = part + ((long)zz * 36 + tileid) * 16384;
#pragma unroll
    for (int mi = 0; mi < 4; ++mi)
#pragma unroll
      for (int ni = 0; ni < 4; ++ni)
#pragma unroll
        for (int j = 0; j < 4; ++j) {
          const int gm = wm * 64 + mi * 16 + lk * 4 + j;
          const int gn = wn * 64 + ni * 16 + lr;
          P[gm * 128 + gn] = (f16)acc[mi][ni][j];
        }
  } else {
    const int u = bid - 576;
    const int t = u & 63;
    const int ny = t >> 3, nxx = t & 7;
    f16* C = (selt == 2) ? PWv : U;
    const int m0 = ny * 128 + wm * 64;
    const int n0 = nxx * 128 + wn * 64;
#pragma unroll
    for (int mi = 0; mi < 4; ++mi)
#pragma unroll
      for (int ni = 0; ni < 4; ++ni)
#pragma unroll
        for (int j = 0; j < 4; ++j) {
          const int gm = m0 + mi * 16 + lk * 4 + j;
          const int gn = n0 + ni * 16 + lr;
          C[(long)gm * 1024 + gn] = (f16)acc[mi][ni][j];
        }
  }
}

// ---------------- FINAL GEMM: 256x256 tile, 8 waves, BK=64, fine 4-phase with correct sync ----------------
// Staging of tile t+1 spread across phases in consumption order:
//   P0: SB q0,q1   P1: SB q2,q3   P2: SA q0,q2   P3: SA q1,q3
// Entry waits: P0 vmcnt(2)->barrier (6 oldest = B0-3,A0,A2 of tile t); P1 vmcnt(2|0)->barrier (A1,A3).
// Reads ALWAYS after the barrier that follows the counted vmcnt (round-13 race fixed).
__global__ __launch_bounds__(512) void gemm256f(
    const f16* __restrict__ A,       // H flat [16384][1024]
    const f16* __restrict__ Bw,      // W2T [4][1024][1024]
    const float* __restrict__ resid,
    const float* __restrict__ c2v,
    float* __restrict__ outF) {
  const int lin = blockIdx.y * 4 + blockIdx.x;
  const int xcd = lin & 7, slot = lin >> 3;
  const int ny = xcd * 8 + (slot >> 2);          // 0..63  (M tile)
  const int nx = slot & 3;                       // 0..3   (N tile)
  const int bb = ny >> 4;

  GP64_COMMON();
  const int wm = wave >> 2, wn = wave & 3;       // 2 x 4 wave grid

  __shared__ __align__(16) f16 As[2][16384];
  __shared__ __align__(16) f16 Bs[2][16384];

  const f16* Ab = A + (long)ny * 262144;
  const f16* Bb = Bw + (long)bb * 1048576 + (long)nx * 262144;
  const long offs = (long)srow * 1024 + slc * 8;

  f32x4 zero = {0.f, 0.f, 0.f, 0.f};
  f32x4 acc[8][4];
#pragma unroll
  for (int mi = 0; mi < 8; ++mi)
#pragma unroll
    for (int ni = 0; ni < 4; ++ni) acc[mi][ni] = zero;

#define SA(buf, kt, q) gl_lds16(Ab + offs + (long)(q) * 65536 + (kt) * 64, &As[buf][(q) * 4096] + tid * 8)
#define SB(buf, kt, q) gl_lds16(Bb + offs + (long)(q) * 65536 + (kt) * 64, &Bs[buf][(q) * 4096] + tid * 8)

#define RD_BF(dst, bsb, kc)                                                       \
  _Pragma("unroll")                                                               \
  for (int ni = 0; ni < 4; ++ni)                                                  \
    dst[ni] = *(const f16x8*)((bsb) + (wn * 64 + ni * 16 + lr) * 64 + (kc));
#define RD_AF(dst, asb, mh, kc)                                                   \
  _Pragma("unroll")                                                               \
  for (int mi = 0; mi < 4; ++mi)                                                  \
    dst[mi] = *(const f16x8*)((asb) + (wm * 128 + (mh) * 64 + mi * 16 + lr) * 64 + (kc));
#define MF16(af_, bf_, mo)                                                        \
  __builtin_amdgcn_s_setprio(1);                                                  \
  _Pragma("unroll")                                                               \
  for (int mi = 0; mi < 4; ++mi)                                                  \
    _Pragma("unroll")                                                             \
    for (int ni = 0; ni < 4; ++ni)                                                \
      acc[(mo) + mi][ni] = __builtin_amdgcn_mfma_f32_16x16x32_f16(af_[mi], bf_[ni], \
                                                                  acc[(mo) + mi][ni], 0, 0, 0); \
  __builtin_amdgcn_s_setprio(0);

  const int nt = 16;
  // prologue: stage tile 0 in consumption order
  SB(0, 0, 0); SB(0, 0, 1); SB(0, 0, 2); SB(0, 0, 3);
  SA(0, 0, 0); SA(0, 0, 2); SA(0, 0, 1); SA(0, 0, 3);

  int cur = 0;
  for (int t = 0; t < nt; ++t) {
    const f16* asb = &As[cur][0];
    const f16* bsb = &Bs[cur][0];
    const int nb = cur ^ 1;
    const bool st = (t + 1 < nt);
    f16x8 bf[4], af[4];

    // ---- P0: (mh0, ks0) ----
    asm volatile("s_waitcnt vmcnt(2)" ::: "memory");   // 6 oldest of tile t landed (per wave)
    asm volatile("s_barrier" ::: "memory");            // ...for ALL waves -> B0-3,A0,A2 readable
    RD_BF(bf, bsb, kc0);
    RD_AF(af, asb, 0, kc0);
    if (st) { SB(nb, t + 1, 0); SB(nb, t + 1, 1); }
    asm volatile("s_waitcnt lgkmcnt(0)" ::: "memory");
    MF16(af, bf, 0);
    asm volatile("s_barrier" ::: "memory");

    // ---- P1: (mh1, ks0) ----
    if (st) asm volatile("s_waitcnt vmcnt(2)" ::: "memory");  // A1,A3 of tile t landed
    else    asm volatile("s_waitcnt vmcnt(0)" ::: "memory");  // last iter: only A1,A3 outstanding
    asm volatile("s_barrier" ::: "memory");
    RD_AF(af, asb, 1, kc0);
    if (st) { SB(nb, t + 1, 2); SB(nb, t + 1, 3); }
    asm volatile("s_waitcnt lgkmcnt(0)" ::: "memory");
    MF16(af, bf, 4);
    asm volatile("s_barrier" ::: "memory");

    // ---- P2: (mh0, ks1) — quadrants already verified ----
    RD_BF(bf, bsb, kc1);
    RD_AF(af, asb, 0, kc1);
    if (st) { SA(nb, t + 1, 0); SA(nb, t + 1, 2); }
    asm volatile("s_waitcnt lgkmcnt(0)" ::: "memory");
    MF16(af, bf, 0);
    asm volatile("s_barrier" ::: "memory");

    // ---- P3: (mh1, ks1) ----
    RD_AF(af, asb, 1, kc1);
    if (st) { SA(nb, t + 1, 1); SA(nb, t + 1, 3); }
    asm volatile("s_waitcnt lgkmcnt(0)" ::: "memory");
    MF16(af, bf, 4);
    asm volatile("s_barrier" ::: "memory");

    cur ^= 1;
  }
#undef SA
#undef SB
#undef RD_BF
#undef RD_AF
#undef MF16

  // drain any residual DMA before reusing LDS
  asm volatile("s_waitcnt vmcnt(0)" ::: "memory");
  asm volatile("s_barrier" ::: "memory");

  // -------- LDS-staged vectorized epilogue (reuses As) --------
  float* weps = ((float*)&As[0][0]) + wave * 1088;
  const int m0 = ny * 256 + wm * 128;
  const int n0 = nx * 256 + wn * 64;
  const int err = lane >> 3;
  const int ecc = (lane & 7) * 4;
  float4 cc2[2];
#pragma unroll
  for (int q = 0; q < 2; ++q)
    cc2[q] = *(const float4*)&c2v[bb * 1024 + n0 + ecc + 32 * q];

#pragma unroll
  for (int mi = 0; mi < 8; ++mi) {
#pragma unroll
    for (int ni = 0; ni < 4; ++ni)
#pragma unroll
      for (int j = 0; j < 4; ++j)
        weps[(lk * 4 + j) * 68 + ni * 16 + lr] = acc[mi][ni][j];
    asm volatile("s_waitcnt lgkmcnt(0)" ::: "memory");
#pragma unroll
    for (int h = 0; h < 2; ++h)
#pragma unroll
      for (int q = 0; q < 2; ++q) {
        const int rr = err + 8 * h;
        const int cc = ecc + 32 * q;
        float4 o = *(const float4*)&weps[rr * 68 + cc];
        const long gbase = (long)(m0 + mi * 16 + rr) * 1024 + n0 + cc;
        const float4 rv = *(const float4*)&resid[gbase];
        float4 ov;
        ov.x = o.x + rv.x + cc2[q].x;
        ov.y = o.y + rv.y + cc2[q].y;
        ov.z = o.z + rv.z + cc2[q].z;
        ov.w = o.w + rv.w + cc2[q].w;
        *(float4*)&outF[gbase] = ov;
      }
  }
}

// ---------------- reduce triangular G partials -> Gh, mirror ----------------
__global__ __launch_bounds__(256) void treduce(const f16* __restrict__ part,
                                               f16* __restrict__ Gh) {
  const int tileid = blockIdx.x, b = blockIdx.y;
  int ti = 0, trem = tileid;
  while (trem >= 8 - ti) { trem -= 8 - ti; ++ti; }
  const int tj = ti + trem;
  __shared__ f16 tl[128][132];
  const int tid = threadIdx.x;
  f16* Gb = Gh + (long)b * 1048576;
  const long pbase = ((long)b * 36 + tileid) * 16384;
#pragma unroll
  for (int it = 0; it < 16; ++it) {
    const int e = it * 1024 + tid * 4;
    const int r = e >> 7, c = e & 127;
    f16x4 p0 = *(const f16x4*)(part + pbase + e);
    f16x4 p1 = *(const f16x4*)(part + pbase + 2359296 + e);
    f16x4 p2 = *(const f16x4*)(part + pbase + 4718592 + e);
    f16x4 p3 = *(const f16x4*)(part + pbase + 7077888 + e);
    f16x4 sv;
#pragma unroll
    for (int j = 0; j < 4; ++j)
      sv[j] = (f16)((float)p0[j] + (float)p1[j] + (float)p2[j] + (float)p3[j]);
    *(f16x4*)(Gb + (long)(ti * 128 + r) * 1024 + tj * 128 + c) = sv;
    *(f16x4*)&tl[r][c] = sv;
  }
  if (ti != tj) {
    __syncthreads();
#pragma unroll
    for (int it = 0; it < 16; ++it) {
      const int e = it * 1024 + tid * 4;
      const int r = e >> 7, c = e & 127;
      f16x4 v;
      v[0] = tl[c + 0][r];
      v[1] = tl[c + 1][r];
      v[2] = tl[c + 2][r];
      v[3] = tl[c + 3][r];
      *(f16x4*)(Gb + (long)(tj * 128 + r) * 1024 + ti * 128 + c) = v;
    }
  }
}

extern "C" void kernel_launch(void* const* d_in, const int* in_sizes, int n_in,
                              void* d_out, int out_size, void* d_ws, size_t ws_size,
                              hipStream_t stream) {
  const float* x      = (const float*)d_in[0];
  const float* norm_w = (const float*)d_in[1];
  const float* norm_b = (const float*)d_in[2];
  const float* qkv_w  = (const float*)d_in[3];
  const float* qkv_b  = (const float*)d_in[4];
  const float* proj_w = (const float*)d_in[5];
  const float* proj_b = (const float*)d_in[6];
  float* out = (float*)d_out;
  char* ws = (char*)d_ws;

  const size_t OFF_H    = 0;
  const size_t OFF_HT   = 33554432;
  const size_t OFF_T1   = 33554432;   // alias (Ht dead after gemmGUV)
  const size_t OFF_T2   = 41943040;
  const size_t OFF_WH   = 67108864;
  const size_t OFF_PH   = 73400320;
  const size_t OFF_WT3  = 75497472;
  const size_t OFF_U    = 81788928;
  const size_t OFF_PWV  = 83886080;
  const size_t OFF_GH   = 85983232;
  const size_t OFF_PART = 94371840;
  const size_t OFF_HS   = 115343360;
  const size_t OFF_AYD  = 115392512;
  const size_t OFF_SCAL = 115404800;
  const size_t OFF_EFZ  = 115405824;
  const size_t OFF_C2   = 115471360;

  f16* H    = (f16*)(ws + OFF_H);
  f16* Ht   = (f16*)(ws + OFF_HT);
  f16* T1   = (f16*)(ws + OFF_T1);
  f16* T2   = (f16*)(ws + OFF_T2);
  f16* Wh   = (f16*)(ws + OFF_WH);
  f16* Ph   = (f16*)(ws + OFF_PH);
  f16* WT3  = (f16*)(ws + OFF_WT3);
  f16* U    = (f16*)(ws + OFF_U);
  f16* PWv  = (f16*)(ws + OFF_PWV);
  f16* Gh   = (f16*)(ws + OFF_GH);
  f16* part = (f16*)(ws + OFF_PART);
  float* hs   = (float*)(ws + OFF_HS);
  float* ayd  = (float*)(ws + OFF_AYD);
  float* scal = (float*)(ws + OFF_SCAL);
  float* efz  = (float*)(ws + OFF_EFZ);
  float* c2v  = (float*)(ws + OFF_C2);

  // weight prep (one pass over qkv_w; straight casts fused)
  transcast4<<<dim3(16, 16, 4), 256, 0, stream>>>(qkv_w, proj_w, WT3, Wh, Ph);
  gemv3a<<<dim3(3073), 64, 0, stream>>>(WT3, Ph, qkv_b, ayd, scal);

  // input path
  ln_kernel<<<dim3(4096), 256, 0, stream>>>(x, norm_w, norm_b, H);
  hipMemsetAsync(ws + OFF_HS, 0, 16384, stream);
  transpose_cs_kernel<<<dim3(16, 64, 4), 256, 0, stream>>>(H, Ht, hs);

  // merged: G tri-tiles (576 blocks) + U/PWv (128 blocks)
  gemmGUV<<<dim3(704), 256, 0, stream>>>(Ht, WT3, Ph, part, U, PWv);
  treduce<<<dim3(36, 4), 256, 0, stream>>>(part, Gh);

  // gemv cluster: e, f, z, s_u  then c2 directly
  gemv3b<<<dim3(12292), 64, 0, stream>>>(U, PWv, Gh, hs, ayd, efz, scal);
  gemvC2n<<<dim3(4096), 64, 0, stream>>>(PWv, efz, ayd, scal, proj_b, c2v);

  // T1_b = U (x) G_b
  gemm128<0><<<dim3(8, 8, 4), 256, 0, stream>>>(U, Gh, 1024, 0L, 1048576L, 1048576L,
      T1, nullptr, nullptr, nullptr, nullptr);
  // W2T_b = (PWv (x) T1_b + d e^T + (f + 4096 d) a^T) / 32
  gemm128<1><<<dim3(8, 8, 4), 256, 0, stream>>>(PWv, T1, 1024, 0L, 1048576L, 1048576L,
      T2, ayd + 2048, efz, efz + 4096, ayd);

  // out = X + H (x) W2T + c2
  gemm256f<<<dim3(4, 64), 512, 0, stream>>>(H, T2, x, c2v, out);
}

// Round 16
// 195.798 us; speedup vs baseline: 1.0400x; 1.0400x over previous
//
#include <hip/hip_runtime.h>

typedef _Float16 f16;
typedef _Float16 f16x4 __attribute__((ext_vector_type(4)));
typedef _Float16 f16x8 __attribute__((ext_vector_type(8)));
typedef float f32x4 __attribute__((ext_vector_type(4)));

#define AS1 __attribute__((address_space(1)))
#define AS3 __attribute__((address_space(3)))

__device__ __forceinline__ void gl_lds16(const f16* g, f16* l) {
  __builtin_amdgcn_global_load_lds((const AS1 void*)g, (AS3 void*)l, 16, 0, 0);
}

// ---------------- LayerNorm: x (fp32) -> H (f16), one WAVE per row ----------------
__global__ __launch_bounds__(256) void ln_kernel(const float* __restrict__ x,
                                                 const float* __restrict__ gw,
                                                 const float* __restrict__ gb,
                                                 f16* __restrict__ H) {
  const int wv = threadIdx.x >> 6, lane = threadIdx.x & 63;
  const long row = (long)blockIdx.x * 4 + wv;
  const float* xr = x + row * 1024;
  float4 v[4];
  float s = 0.f, s2 = 0.f;
#pragma unroll
  for (int j = 0; j < 4; ++j) {
    v[j] = ((const float4*)xr)[lane + 64 * j];
    s  += v[j].x + v[j].y + v[j].z + v[j].w;
    s2 += v[j].x * v[j].x + v[j].y * v[j].y + v[j].z * v[j].z + v[j].w * v[j].w;
  }
#pragma unroll
  for (int off = 32; off > 0; off >>= 1) {
    s  += __shfl_xor(s, off);
    s2 += __shfl_xor(s2, off);
  }
  const float mu = s * (1.0f / 1024.0f);
  const float rstd = rsqrtf(s2 * (1.0f / 1024.0f) - mu * mu + 1e-5f);
#pragma unroll
  for (int j = 0; j < 4; ++j) {
    const float4 w4 = ((const float4*)gw)[lane + 64 * j];
    const float4 b4 = ((const float4*)gb)[lane + 64 * j];
    f16x4 h;
    h[0] = (f16)((v[j].x - mu) * rstd * w4.x + b4.x);
    h[1] = (f16)((v[j].y - mu) * rstd * w4.y + b4.y);
    h[2] = (f16)((v[j].z - mu) * rstd * w4.z + b4.z);
    h[3] = (f16)((v[j].w - mu) * rstd * w4.w + b4.w);
    *(f16x4*)(H + row * 1024 + (lane + 64 * j) * 4) = h;
  }
}

// ---------------- transpose H -> Ht, fused colsum ----------------
__global__ __launch_bounds__(256) void transpose_cs_kernel(const f16* __restrict__ H,
                                                           f16* __restrict__ Ht,
                                                           float* __restrict__ hs) {
  __shared__ f16 tile[64][68];
  __shared__ float csum[4][64];
  const int b = blockIdx.z;
  const long Hb  = (long)b * 4096 * 1024;
  const long Htb = (long)b * 1024 * 4096;
  const int t0 = blockIdx.y * 64, c0 = blockIdx.x * 64;
  const int tid = threadIdx.x;
  const int r = tid >> 2, g0 = tid & 3;
#pragma unroll
  for (int i = 0; i < 4; ++i) {
    const int g = g0 + i * 4;
    f16x4 v = *(const f16x4*)(H + Hb + (long)(t0 + r) * 1024 + c0 + g * 4);
    *(f16x4*)&tile[r][g * 4] = v;
  }
  __syncthreads();
  {
    const int cl = tid & 63, rg = tid >> 6;
    float s = 0.f;
#pragma unroll
    for (int rr = 0; rr < 16; ++rr) s += (float)tile[rg * 16 + rr][cl];
    csum[rg][cl] = s;
  }
#pragma unroll
  for (int i = 0; i < 4; ++i) {
    const int g = g0 + i * 4;
    f16x4 v;
    v[0] = tile[g * 4 + 0][r];
    v[1] = tile[g * 4 + 1][r];
    v[2] = tile[g * 4 + 2][r];
    v[3] = tile[g * 4 + 3][r];
    *(f16x4*)(Ht + Htb + (long)(c0 + r) * 4096 + t0 + g * 4) = v;
  }
  __syncthreads();
  if (tid < 64)
    atomicAdd(&hs[b * 1024 + c0 + tid],
              csum[0][tid] + csum[1][tid] + csum[2][tid] + csum[3][tid]);
}

// ---------------- transcast4: z=0..2 transpose qkv (z>=1 also straight cast), z=3 cast proj ----------------
__global__ __launch_bounds__(256) void transcast4(const float* __restrict__ qkv_w,
                                                  const float* __restrict__ proj_w,
                                                  f16* __restrict__ WT3,
                                                  f16* __restrict__ Wh,
                                                  f16* __restrict__ Ph) {
  const int z = blockIdx.z;
  __shared__ f16 tile[64][68];
  const int r0 = blockIdx.y * 64, c0 = blockIdx.x * 64;
  const int tid = threadIdx.x;
  const int r = tid >> 2, g0 = tid & 3;
  if (z == 3) {
#pragma unroll
    for (int i = 0; i < 4; ++i) {
      const int g = g0 + i * 4;
      float4 v = *(const float4*)(proj_w + (long)(r0 + r) * 1024 + c0 + g * 4);
      f16x4 h; h[0]=(f16)v.x; h[1]=(f16)v.y; h[2]=(f16)v.z; h[3]=(f16)v.w;
      *(f16x4*)(Ph + (long)(r0 + r) * 1024 + c0 + g * 4) = h;
    }
    return;
  }
  const float* W = qkv_w + (long)z * 1048576;
  f16* WT = WT3 + (long)z * 1048576;
#pragma unroll
  for (int i = 0; i < 4; ++i) {
    const int g = g0 + i * 4;
    float4 v = *(const float4*)(W + (long)(r0 + r) * 1024 + c0 + g * 4);
    f16x4 h; h[0]=(f16)v.x; h[1]=(f16)v.y; h[2]=(f16)v.z; h[3]=(f16)v.w;
    *(f16x4*)&tile[r][g * 4] = h;
    if (z >= 1)
      *(f16x4*)(Wh + (long)z * 1048576 + (long)(r0 + r) * 1024 + c0 + g * 4) = h;
  }
  __syncthreads();
#pragma unroll
  for (int i = 0; i < 4; ++i) {
    const int g = g0 + i * 4;
    f16x4 v;
    v[0] = tile[g * 4 + 0][r];
    v[1] = tile[g * 4 + 1][r];
    v[2] = tile[g * 4 + 2][r];
    v[3] = tile[g * 4 + 3][r];
    *(f16x4*)(WT + (long)(c0 + r) * 1024 + r0 + g * 4) = v;
  }
}

// ---------------- f16row . f32vec, 1024 elems, one 64-lane wave ----------------
__device__ __forceinline__ float dot1024(const f16* __restrict__ row,
                                         const float* __restrict__ v) {
  const int lane = threadIdx.x & 63;
  float s = 0.f;
#pragma unroll
  for (int j = 0; j < 2; ++j) {
    const int d = (lane + 64 * j) * 8;
    f16x8 a = *(const f16x8*)(row + d);
    float4 h0 = *(const float4*)(v + d);
    float4 h1 = *(const float4*)(v + d + 4);
    s += (float)a[0] * h0.x + (float)a[1] * h0.y + (float)a[2] * h0.z + (float)a[3] * h0.w
       + (float)a[4] * h1.x + (float)a[5] * h1.y + (float)a[6] * h1.z + (float)a[7] * h1.w;
  }
#pragma unroll
  for (int off = 32; off > 0; off >>= 1) s += __shfl_down(s, off);
  return s;
}

__device__ __forceinline__ float dotf1024(const float* __restrict__ a,
                                          const float* __restrict__ v) {
  const int lane = threadIdx.x & 63;
  float s = 0.f;
#pragma unroll
  for (int j = 0; j < 4; ++j) {
    const int d = (lane + 64 * j) * 4;
    float4 x = *(const float4*)(a + d);
    float4 q = *(const float4*)(v + d);
    s += x.x * q.x + x.y * q.y + x.z * q.z + x.w * q.w;
  }
#pragma unroll
  for (int off = 32; off > 0; off >>= 1) s += __shfl_down(s, off);
  return s;
}

// ---------------- gemv3a: a = WqT.bk, y = WkT.bq, d = Ph.bv, scal[4] = bk.bq ----------------
__global__ void gemv3a(const f16* __restrict__ WT3, const f16* __restrict__ Ph,
                       const float* __restrict__ qkv_b, float* __restrict__ ayd,
                       float* __restrict__ scal) {
  if (blockIdx.x == 3072) {
    float s = dotf1024(qkv_b + 1024, qkv_b);
    if ((threadIdx.x & 63) == 0) scal[4] = s;
    return;
  }
  const int which = blockIdx.x >> 10, m = blockIdx.x & 1023;
  const f16* row;
  const float* v;
  if (which == 0)      { row = WT3 + (long)m * 1024;            v = qkv_b + 1024; } // a
  else if (which == 1) { row = WT3 + 1048576 + (long)m * 1024;  v = qkv_b; }        // y
  else                 { row = Ph + (long)m * 1024;             v = qkv_b + 2048; } // d
  float s = dot1024(row, v);
  if ((threadIdx.x & 63) == 0) ayd[which * 1024 + m] = s;
}

// ---------------- gemv3b: e = U.hs, f = PWv.hs, z = G.y; blocks >= 12288: scal[b] = hs_b.y ----------------
__global__ void gemv3b(const f16* __restrict__ U, const f16* __restrict__ PWv,
                       const f16* __restrict__ Gh, const float* __restrict__ hs,
                       const float* __restrict__ ayd, float* __restrict__ efz,
                       float* __restrict__ scal) {
  if (blockIdx.x >= 12288) {
    const int b = blockIdx.x - 12288;
    float s = dotf1024(hs + b * 1024, ayd + 1024);
    if ((threadIdx.x & 63) == 0) scal[b] = s;
    return;
  }
  const int sel = blockIdx.x >> 12, r = blockIdx.x & 4095;
  const int b = r >> 10, m = r & 1023;
  const f16* row;
  const float* v;
  if (sel == 0)      { row = U + (long)m * 1024;                       v = hs + b * 1024; }
  else if (sel == 1) { row = PWv + (long)m * 1024;                     v = hs + b * 1024; }
  else               { row = Gh + (long)b * 1048576 + (long)m * 1024;  v = ayd + 1024; }
  float s = dot1024(row, v);
  if ((threadIdx.x & 63) == 0) efz[sel * 4096 + r] = s;
}

// ---------------- c2_b[c] = (PWv_row_c . z_b + d_c*s_u_b + s_b*(f_b_c + 4096 d_c))/32 + proj_b[c] ----------------
__global__ void gemvC2n(const f16* __restrict__ PWv, const float* __restrict__ efz,
                        const float* __restrict__ ayd, const float* __restrict__ scal,
                        const float* __restrict__ proj_b, float* __restrict__ c2) {
  const int b = blockIdx.x >> 10, c = blockIdx.x & 1023;
  float s = dot1024(PWv + (long)c * 1024, efz + 8192 + b * 1024);
  if ((threadIdx.x & 63) == 0) {
    const float d = ayd[2048 + c];
    c2[b * 1024 + c] = (s + d * scal[b] + scal[4] * (efz[4096 + b * 1024 + c] + 4096.f * d))
                         * 0.03125f + proj_b[c];
  }
}

// ================= shared GEMM machinery (BK = 64) =================
#define GP64_COMMON()                                        \
  const int tid = threadIdx.x;                               \
  const int wave = tid >> 6, lane = tid & 63;                \
  const int lr = lane & 15, lk = lane >> 4;                  \
  const int srow = tid >> 3;                                 \
  const int slc  = (tid & 7) ^ (srow & 7);                   \
  const int kc0 = ((lk) ^ (lr & 7)) * 8;                     \
  const int kc1 = ((4 + lk) ^ (lr & 7)) * 8;

#define GEMM_WAIT8(NBUF_, r_)                                               \
  do {                                                                      \
    if constexpr (NBUF_ == 3) {                                             \
      if ((r_) >= 2)      asm volatile("s_waitcnt vmcnt(16)" ::: "memory"); \
      else if ((r_) == 1) asm volatile("s_waitcnt vmcnt(8)" ::: "memory");  \
      else                asm volatile("s_waitcnt vmcnt(0)" ::: "memory");  \
    } else {                                                                \
      if ((r_) >= 1)      asm volatile("s_waitcnt vmcnt(8)" ::: "memory");  \
      else                asm volatile("s_waitcnt vmcnt(0)" ::: "memory");  \
    }                                                                       \
  } while (0)

#define COMP64_HALF(asb_, bsb_, kc_)                                             \
  do {                                                                           \
    const f16* asb = (asb_);                                                     \
    const f16* bsb = (bsb_);                                                     \
    f16x8 af[4], bf[4];                                                          \
    _Pragma("unroll")                                                            \
    for (int mi = 0; mi < 4; ++mi)                                               \
      af[mi] = *(const f16x8*)(asb + (wm * 64 + mi * 16 + lr) * 64 + (kc_));     \
    _Pragma("unroll")                                                            \
    for (int ni = 0; ni < 4; ++ni)                                               \
      bf[ni] = *(const f16x8*)(bsb + (wn * 64 + ni * 16 + lr) * 64 + (kc_));     \
    _Pragma("unroll")                                                            \
    for (int mi = 0; mi < 4; ++mi)                                               \
      _Pragma("unroll")                                                          \
      for (int ni = 0; ni < 4; ++ni)                                             \
        acc[mi][ni] = __builtin_amdgcn_mfma_f32_16x16x32_f16(af[mi], bf[ni],     \
                                                             acc[mi][ni], 0, 0, 0); \
  } while (0)

#define GEMM_BODY_LOOP(NBUF_, NT_, STAGEM)                       \
  do {                                                           \
    if constexpr (NBUF_ == 3) {                                  \
      STAGEM(0, 0); STAGEM(1, 1);                                \
      int cur = 0, stg = 2;                                      \
      for (int t = 0; t < (NT_); ++t) {                          \
        if (t + 2 < (NT_)) STAGEM(stg, t + 2);                   \
        GEMM_WAIT8(3, (NT_) - 1 - t);                            \
        asm volatile("s_barrier" ::: "memory");                  \
        __builtin_amdgcn_s_setprio(1);                           \
        COMP64_HALF(&As[cur][0], &Bs[cur][0], kc0);              \
        COMP64_HALF(&As[cur][0], &Bs[cur][0], kc1);              \
        __builtin_amdgcn_s_setprio(0);                           \
        asm volatile("s_waitcnt lgkmcnt(0)" ::: "memory");       \
        asm volatile("s_barrier" ::: "memory");                  \
        cur = (cur + 1 == 3) ? 0 : cur + 1;                      \
        stg = (stg + 1 == 3) ? 0 : stg + 1;                      \
      }                                                          \
    } else {                                                     \
      STAGEM(0, 0);                                              \
      int cur = 0;                                               \
      for (int t = 0; t < (NT_); ++t) {                          \
        if (t + 1 < (NT_)) STAGEM(cur ^ 1, t + 1);               \
        GEMM_WAIT8(2, (NT_) - 1 - t);                            \
        asm volatile("s_barrier" ::: "memory");                  \
        __builtin_amdgcn_s_setprio(1);                           \
        COMP64_HALF(&As[cur][0], &Bs[cur][0], kc0);              \
        COMP64_HALF(&As[cur][0], &Bs[cur][0], kc1);              \
        __builtin_amdgcn_s_setprio(0);                           \
        asm volatile("s_waitcnt lgkmcnt(0)" ::: "memory");       \
        asm volatile("s_barrier" ::: "memory");                  \
        cur ^= 1;                                                \
      }                                                          \
    }                                                            \
  } while (0)

// ---------------- chain GEMM: 128x128, BK=64, NBUF=3 ----------------
template <int MODE>
__global__ __launch_bounds__(256) void gemm128(
    const f16* __restrict__ A, const f16* __restrict__ B, int K,
    long sA, long sB, long sC,
    f16* __restrict__ Ch,
    const float* __restrict__ dvec, const float* __restrict__ evec,
    const float* __restrict__ fvec, const float* __restrict__ avec) {
  const int b = blockIdx.z;
  A += (long)b * sA;
  B += (long)b * sB;
  const int nx = blockIdx.y & 7;
  const int ny = blockIdx.x;

  GP64_COMMON();
  const int wm = wave >> 1, wn = wave & 1;

  __shared__ __align__(16) f16 As[3][8192];
  __shared__ __align__(16) f16 Bs[3][8192];

  const long aoffs = (long)(ny * 128 + srow) * K + slc * 8;
  const long boffs = (long)(nx * 128 + srow) * K + slc * 8;

  f32x4 zero = {0.f, 0.f, 0.f, 0.f};
  f32x4 acc[4][4];
#pragma unroll
  for (int mi = 0; mi < 4; ++mi)
#pragma unroll
    for (int ni = 0; ni < 4; ++ni) acc[mi][ni] = zero;

#define STAGE(buf, kt)                                                              \
  do {                                                                              \
    f16* asb = &As[buf][0];                                                         \
    f16* bsb = &Bs[buf][0];                                                         \
    _Pragma("unroll")                                                               \
    for (int q = 0; q < 4; ++q) {                                                   \
      gl_lds16(A + aoffs + (long)q * 32 * K + (kt) * 64, asb + q * 2048 + tid * 8); \
      gl_lds16(B + boffs + (long)q * 32 * K + (kt) * 64, bsb + q * 2048 + tid * 8); \
    }                                                                               \
  } while (0)

  const int nt = K >> 6;
  GEMM_BODY_LOOP(3, nt, STAGE);
#undef STAGE

  const long cb = (long)b * sC;
  const int m0 = ny * 128 + wm * 64;
  const int n0 = nx * 128 + wn * 64;
#pragma unroll
  for (int mi = 0; mi < 4; ++mi)
#pragma unroll
    for (int ni = 0; ni < 4; ++ni)
#pragma unroll
      for (int j = 0; j < 4; ++j) {
        const int gm = m0 + mi * 16 + lk * 4 + j;
        const int gn = n0 + ni * 16 + lr;
        float val = acc[mi][ni][j];
        if constexpr (MODE == 0) {
          Ch[cb + (long)gm * 1024 + gn] = (f16)val;
        } else {
          const float dm = dvec[gm];
          const float fm = fvec[b * 1024 + gm];
          const float en = evec[b * 1024 + gn];
          const float an = avec[gn];
          val = (val + dm * en + (fm + 4096.f * dm) * an) * 0.03125f;
          Ch[cb + (long)gm * 1024 + gn] = (f16)val;
        }
      }
}

// ---------------- MERGED: G = H^T H (tri, split-K=4) + {U = WqT x WkT, PWv = Ph x WvT} ----------------
// G blocks: bid < 576 with zz = bid & 15, tileid = bid >> 4  — all 36 tiles of one
// K-slice/batch land on XCD zz%8 (bid ≡ zz mod 8), so the 8 shared panels (2 MB)
// of each slice are served from one L2 (2 slices/XCD = 4 MB = L2 size).
__global__ __launch_bounds__(256) void gemmGUV(const f16* __restrict__ Ht,
                                               const f16* __restrict__ WT3,
                                               const f16* __restrict__ Ph,
                                               f16* __restrict__ part,
                                               f16* __restrict__ U,
                                               f16* __restrict__ PWv) {
  GP64_COMMON();
  const int wm = wave >> 1, wn = wave & 1;

  __shared__ __align__(16) f16 As[2][8192];
  __shared__ __align__(16) f16 Bs[2][8192];

  const int bid = blockIdx.x;
  const f16 *Ab, *Bb;
  long rs;
  int tileid = 0, zz = 0, selt = 0;
  if (bid < 576) {
    zz = bid & 15;           // K-slice*4 + batch  (XCD class = zz%8)
    tileid = bid >> 4;       // 0..35 triangular tile
    const int b = zz & 3, ks4 = zz >> 2;
    int ti = 0, trem = tileid;
    while (trem >= 8 - ti) { trem -= 8 - ti; ++ti; }
    const int tj = ti + trem;
    const f16* Hb = Ht + (long)b * 4194304;
    rs = 4096;
    Ab = Hb + (long)(ti * 128 + srow) * 4096 + (long)ks4 * 1024 + slc * 8;
    Bb = Hb + (long)(tj * 128 + srow) * 4096 + (long)ks4 * 1024 + slc * 8;
  } else {
    const int u = bid - 576;
    selt = (u >> 6) + 1;                 // 1: U, 2: PWv
    const int t = u & 63;
    const int ny = t >> 3, nxx = t & 7;
    const f16* A0 = (selt == 2) ? Ph : WT3;
    const f16* B0 = (selt == 2) ? (WT3 + 2097152) : (WT3 + 1048576);
    rs = 1024;
    Ab = A0 + (long)(ny * 128 + srow) * 1024 + slc * 8;
    Bb = B0 + (long)(nxx * 128 + srow) * 1024 + slc * 8;
  }

  f32x4 zero = {0.f, 0.f, 0.f, 0.f};
  f32x4 acc[4][4];
#pragma unroll
  for (int mi = 0; mi < 4; ++mi)
#pragma unroll
    for (int ni = 0; ni < 4; ++ni) acc[mi][ni] = zero;

#define STAGE(buf, kt)                                                            \
  do {                                                                            \
    f16* asb = &As[buf][0];                                                       \
    f16* bsb = &Bs[buf][0];                                                       \
    _Pragma("unroll")                                                             \
    for (int q = 0; q < 4; ++q) {                                                 \
      gl_lds16(Ab + (long)q * 32 * rs + (kt) * 64, asb + q * 2048 + tid * 8);     \
      gl_lds16(Bb + (long)q * 32 * rs + (kt) * 64, bsb + q * 2048 + tid * 8);     \
    }                                                                             \
  } while (0)

  GEMM_BODY_LOOP(2, 16, STAGE);
#undef STAGE

  if (selt == 0) {
    f16* P = part + ((long)zz * 36 + tileid) * 16384;
#pragma unroll
    for (int mi = 0; mi < 4; ++mi)
#pragma unroll
      for (int ni = 0; ni < 4; ++ni)
#pragma unroll
        for (int j = 0; j < 4; ++j) {
          const int gm = wm * 64 + mi * 16 + lk * 4 + j;
          const int gn = wn * 64 + ni * 16 + lr;
          P[gm * 128 + gn] = (f16)acc[mi][ni][j];
        }
  } else {
    const int u = bid - 576;
    const int t = u & 63;
    const int ny = t >> 3, nxx = t & 7;
    f16* C = (selt == 2) ? PWv : U;
    const int m0 = ny * 128 + wm * 64;
    const int n0 = nxx * 128 + wn * 64;
#pragma unroll
    for (int mi = 0; mi < 4; ++mi)
#pragma unroll
      for (int ni = 0; ni < 4; ++ni)
#pragma unroll
        for (int j = 0; j < 4; ++j) {
          const int gm = m0 + mi * 16 + lk * 4 + j;
          const int gn = n0 + ni * 16 + lr;
          C[(long)gm * 1024 + gn] = (f16)acc[mi][ni][j];
        }
  }
}

// ---------------- FINAL GEMM: 256x256 tile, 8 waves, BK=64, fine 4-phase with correct sync ----------------
__global__ __launch_bounds__(512) void gemm256f(
    const f16* __restrict__ A,       // H flat [16384][1024]
    const f16* __restrict__ Bw,      // W2T [4][1024][1024]
    const float* __restrict__ resid,
    const float* __restrict__ c2v,
    float* __restrict__ outF) {
  const int lin = blockIdx.y * 4 + blockIdx.x;
  const int xcd = lin & 7, slot = lin >> 3;
  const int ny = xcd * 8 + (slot >> 2);          // 0..63  (M tile)
  const int nx = slot & 3;                       // 0..3   (N tile)
  const int bb = ny >> 4;

  GP64_COMMON();
  const int wm = wave >> 2, wn = wave & 3;       // 2 x 4 wave grid

  __shared__ __align__(16) f16 As[2][16384];
  __shared__ __align__(16) f16 Bs[2][16384];

  const f16* Ab = A + (long)ny * 262144;
  const f16* Bb = Bw + (long)bb * 1048576 + (long)nx * 262144;
  const long offs = (long)srow * 1024 + slc * 8;

  f32x4 zero = {0.f, 0.f, 0.f, 0.f};
  f32x4 acc[8][4];
#pragma unroll
  for (int mi = 0; mi < 8; ++mi)
#pragma unroll
    for (int ni = 0; ni < 4; ++ni) acc[mi][ni] = zero;

#define SA(buf, kt, q) gl_lds16(Ab + offs + (long)(q) * 65536 + (kt) * 64, &As[buf][(q) * 4096] + tid * 8)
#define SB(buf, kt, q) gl_lds16(Bb + offs + (long)(q) * 65536 + (kt) * 64, &Bs[buf][(q) * 4096] + tid * 8)

#define RD_BF(dst, bsb, kc)                                                       \
  _Pragma("unroll")                                                               \
  for (int ni = 0; ni < 4; ++ni)                                                  \
    dst[ni] = *(const f16x8*)((bsb) + (wn * 64 + ni * 16 + lr) * 64 + (kc));
#define RD_AF(dst, asb, mh, kc)                                                   \
  _Pragma("unroll")                                                               \
  for (int mi = 0; mi < 4; ++mi)                                                  \
    dst[mi] = *(const f16x8*)((asb) + (wm * 128 + (mh) * 64 + mi * 16 + lr) * 64 + (kc));
#define MF16(af_, bf_, mo)                                                        \
  __builtin_amdgcn_s_setprio(1);                                                  \
  _Pragma("unroll")                                                               \
  for (int mi = 0; mi < 4; ++mi)                                                  \
    _Pragma("unroll")                                                             \
    for (int ni = 0; ni < 4; ++ni)                                                \
      acc[(mo) + mi][ni] = __builtin_amdgcn_mfma_f32_16x16x32_f16(af_[mi], bf_[ni], \
                                                                  acc[(mo) + mi][ni], 0, 0, 0); \
  __builtin_amdgcn_s_setprio(0);

  const int nt = 16;
  // prologue: stage tile 0 in consumption order
  SB(0, 0, 0); SB(0, 0, 1); SB(0, 0, 2); SB(0, 0, 3);
  SA(0, 0, 0); SA(0, 0, 2); SA(0, 0, 1); SA(0, 0, 3);

  int cur = 0;
  for (int t = 0; t < nt; ++t) {
    const f16* asb = &As[cur][0];
    const f16* bsb = &Bs[cur][0];
    const int nb = cur ^ 1;
    const bool st = (t + 1 < nt);
    f16x8 bf[4], af[4];

    // ---- P0: (mh0, ks0) ----
    asm volatile("s_waitcnt vmcnt(2)" ::: "memory");   // 6 oldest of tile t landed (per wave)
    asm volatile("s_barrier" ::: "memory");            // ...for ALL waves -> B0-3,A0,A2 readable
    RD_BF(bf, bsb, kc0);
    RD_AF(af, asb, 0, kc0);
    if (st) { SB(nb, t + 1, 0); SB(nb, t + 1, 1); }
    asm volatile("s_waitcnt lgkmcnt(0)" ::: "memory");
    MF16(af, bf, 0);
    asm volatile("s_barrier" ::: "memory");

    // ---- P1: (mh1, ks0) ----
    if (st) asm volatile("s_waitcnt vmcnt(2)" ::: "memory");  // A1,A3 of tile t landed
    else    asm volatile("s_waitcnt vmcnt(0)" ::: "memory");  // last iter: only A1,A3 outstanding
    asm volatile("s_barrier" ::: "memory");
    RD_AF(af, asb, 1, kc0);
    if (st) { SB(nb, t + 1, 2); SB(nb, t + 1, 3); }
    asm volatile("s_waitcnt lgkmcnt(0)" ::: "memory");
    MF16(af, bf, 4);
    asm volatile("s_barrier" ::: "memory");

    // ---- P2: (mh0, ks1) — quadrants already verified ----
    RD_BF(bf, bsb, kc1);
    RD_AF(af, asb, 0, kc1);
    if (st) { SA(nb, t + 1, 0); SA(nb, t + 1, 2); }
    asm volatile("s_waitcnt lgkmcnt(0)" ::: "memory");
    MF16(af, bf, 0);
    asm volatile("s_barrier" ::: "memory");

    // ---- P3: (mh1, ks1) ----
    RD_AF(af, asb, 1, kc1);
    if (st) { SA(nb, t + 1, 1); SA(nb, t + 1, 3); }
    asm volatile("s_waitcnt lgkmcnt(0)" ::: "memory");
    MF16(af, bf, 4);
    asm volatile("s_barrier" ::: "memory");

    cur ^= 1;
  }
#undef SA
#undef SB
#undef RD_BF
#undef RD_AF
#undef MF16

  // drain any residual DMA before reusing LDS
  asm volatile("s_waitcnt vmcnt(0)" ::: "memory");
  asm volatile("s_barrier" ::: "memory");

  // -------- LDS-staged vectorized epilogue (reuses As) --------
  float* weps = ((float*)&As[0][0]) + wave * 1088;
  const int m0 = ny * 256 + wm * 128;
  const int n0 = nx * 256 + wn * 64;
  const int err = lane >> 3;
  const int ecc = (lane & 7) * 4;
  float4 cc2[2];
#pragma unroll
  for (int q = 0; q < 2; ++q)
    cc2[q] = *(const float4*)&c2v[bb * 1024 + n0 + ecc + 32 * q];

#pragma unroll
  for (int mi = 0; mi < 8; ++mi) {
#pragma unroll
    for (int ni = 0; ni < 4; ++ni)
#pragma unroll
      for (int j = 0; j < 4; ++j)
        weps[(lk * 4 + j) * 68 + ni * 16 + lr] = acc[mi][ni][j];
    asm volatile("s_waitcnt lgkmcnt(0)" ::: "memory");
#pragma unroll
    for (int h = 0; h < 2; ++h)
#pragma unroll
      for (int q = 0; q < 2; ++q) {
        const int rr = err + 8 * h;
        const int cc = ecc + 32 * q;
        float4 o = *(const float4*)&weps[rr * 68 + cc];
        const long gbase = (long)(m0 + mi * 16 + rr) * 1024 + n0 + cc;
        const float4 rv = *(const float4*)&resid[gbase];
        float4 ov;
        ov.x = o.x + rv.x + cc2[q].x;
        ov.y = o.y + rv.y + cc2[q].y;
        ov.z = o.z + rv.z + cc2[q].z;
        ov.w = o.w + rv.w + cc2[q].w;
        *(float4*)&outF[gbase] = ov;
      }
  }
}

// ---------------- reduce triangular G partials -> Gh, mirror ----------------
__global__ __launch_bounds__(256) void treduce(const f16* __restrict__ part,
                                               f16* __restrict__ Gh) {
  const int tileid = blockIdx.x, b = blockIdx.y;
  int ti = 0, trem = tileid;
  while (trem >= 8 - ti) { trem -= 8 - ti; ++ti; }
  const int tj = ti + trem;
  __shared__ f16 tl[128][132];
  const int tid = threadIdx.x;
  f16* Gb = Gh + (long)b * 1048576;
  // partials laid out at [(zz)*36 + tileid]; zz = ks4*4 + b
#pragma unroll
  for (int it = 0; it < 16; ++it) {
    const int e = it * 1024 + tid * 4;
    const int r = e >> 7, c = e & 127;
    f16x4 p0 = *(const f16x4*)(part + ((long)(0 * 4 + b) * 36 + tileid) * 16384 + e);
    f16x4 p1 = *(const f16x4*)(part + ((long)(1 * 4 + b) * 36 + tileid) * 16384 + e);
    f16x4 p2 = *(const f16x4*)(part + ((long)(2 * 4 + b) * 36 + tileid) * 16384 + e);
    f16x4 p3 = *(const f16x4*)(part + ((long)(3 * 4 + b) * 36 + tileid) * 16384 + e);
    f16x4 sv;
#pragma unroll
    for (int j = 0; j < 4; ++j)
      sv[j] = (f16)((float)p0[j] + (float)p1[j] + (float)p2[j] + (float)p3[j]);
    *(f16x4*)(Gb + (long)(ti * 128 + r) * 1024 + tj * 128 + c) = sv;
    *(f16x4*)&tl[r][c] = sv;
  }
  if (ti != tj) {
    __syncthreads();
#pragma unroll
    for (int it = 0; it < 16; ++it) {
      const int e = it * 1024 + tid * 4;
      const int r = e >> 7, c = e & 127;
      f16x4 v;
      v[0] = tl[c + 0][r];
      v[1] = tl[c + 1][r];
      v[2] = tl[c + 2][r];
      v[3] = tl[c + 3][r];
      *(f16x4*)(Gb + (long)(tj * 128 + r) * 1024 + ti * 128 + c) = v;
    }
  }
}

extern "C" void kernel_launch(void* const* d_in, const int* in_sizes, int n_in,
                              void* d_out, int out_size, void* d_ws, size_t ws_size,
                              hipStream_t stream) {
  const float* x      = (const float*)d_in[0];
  const float* norm_w = (const float*)d_in[1];
  const float* norm_b = (const float*)d_in[2];
  const float* qkv_w  = (const float*)d_in[3];
  const float* qkv_b  = (const float*)d_in[4];
  const float* proj_w = (const float*)d_in[5];
  const float* proj_b = (const float*)d_in[6];
  float* out = (float*)d_out;
  char* ws = (char*)d_ws;

  const size_t OFF_H    = 0;
  const size_t OFF_HT   = 33554432;
  const size_t OFF_T1   = 33554432;   // alias (Ht dead after gemmGUV)
  const size_t OFF_T2   = 41943040;
  const size_t OFF_WH   = 67108864;
  const size_t OFF_PH   = 73400320;
  const size_t OFF_WT3  = 75497472;
  const size_t OFF_U    = 81788928;
  const size_t OFF_PWV  = 83886080;
  const size_t OFF_GH   = 85983232;
  const size_t OFF_PART = 94371840;
  const size_t OFF_HS   = 115343360;
  const size_t OFF_AYD  = 115392512;
  const size_t OFF_SCAL = 115404800;
  const size_t OFF_EFZ  = 115405824;
  const size_t OFF_C2   = 115471360;

  f16* H    = (f16*)(ws + OFF_H);
  f16* Ht   = (f16*)(ws + OFF_HT);
  f16* T1   = (f16*)(ws + OFF_T1);
  f16* T2   = (f16*)(ws + OFF_T2);
  f16* Wh   = (f16*)(ws + OFF_WH);
  f16* Ph   = (f16*)(ws + OFF_PH);
  f16* WT3  = (f16*)(ws + OFF_WT3);
  f16* U    = (f16*)(ws + OFF_U);
  f16* PWv  = (f16*)(ws + OFF_PWV);
  f16* Gh   = (f16*)(ws + OFF_GH);
  f16* part = (f16*)(ws + OFF_PART);
  float* hs   = (float*)(ws + OFF_HS);
  float* ayd  = (float*)(ws + OFF_AYD);
  float* scal = (float*)(ws + OFF_SCAL);
  float* efz  = (float*)(ws + OFF_EFZ);
  float* c2v  = (float*)(ws + OFF_C2);

  // weight prep (one pass over qkv_w; straight casts fused)
  transcast4<<<dim3(16, 16, 4), 256, 0, stream>>>(qkv_w, proj_w, WT3, Wh, Ph);
  gemv3a<<<dim3(3073), 64, 0, stream>>>(WT3, Ph, qkv_b, ayd, scal);

  // input path
  ln_kernel<<<dim3(4096), 256, 0, stream>>>(x, norm_w, norm_b, H);
  hipMemsetAsync(ws + OFF_HS, 0, 16384, stream);
  transpose_cs_kernel<<<dim3(16, 64, 4), 256, 0, stream>>>(H, Ht, hs);

  // merged: G tri-tiles (576 blocks, XCD-clustered by K-slice) + U/PWv (128 blocks)
  gemmGUV<<<dim3(704), 256, 0, stream>>>(Ht, WT3, Ph, part, U, PWv);
  treduce<<<dim3(36, 4), 256, 0, stream>>>(part, Gh);

  // gemv cluster: e, f, z, s_u  then c2 directly
  gemv3b<<<dim3(12292), 64, 0, stream>>>(U, PWv, Gh, hs, ayd, efz, scal);
  gemvC2n<<<dim3(4096), 64, 0, stream>>>(PWv, efz, ayd, scal, proj_b, c2v);

  // T1_b = U (x) G_b
  gemm128<0><<<dim3(8, 8, 4), 256, 0, stream>>>(U, Gh, 1024, 0L, 1048576L, 1048576L,
      T1, nullptr, nullptr, nullptr, nullptr);
  // W2T_b = (PWv (x) T1_b + d e^T + (f + 4096 d) a^T) / 32
  gemm128<1><<<dim3(8, 8, 4), 256, 0, stream>>>(PWv, T1, 1024, 0L, 1048576L, 1048576L,
      T2, ayd + 2048, efz, efz + 4096, ayd);

  // out = X + H (x) W2T + c2
  gemm256f<<<dim3(4, 64), 512, 0, stream>>>(H, T2, x, c2v, out);
}

// Round 17
// 190.044 us; speedup vs baseline: 1.0715x; 1.0303x over previous
//
#include <hip/hip_runtime.h>

typedef _Float16 f16;
typedef _Float16 f16x4 __attribute__((ext_vector_type(4)));
typedef _Float16 f16x8 __attribute__((ext_vector_type(8)));
typedef float f32x4 __attribute__((ext_vector_type(4)));

#define AS1 __attribute__((address_space(1)))
#define AS3 __attribute__((address_space(3)))

__device__ __forceinline__ void gl_lds16(const f16* g, f16* l) {
  __builtin_amdgcn_global_load_lds((const AS1 void*)g, (AS3 void*)l, 16, 0, 0);
}

// ---------------- LayerNorm: x (fp32) -> H (f16), one WAVE per row ----------------
__global__ __launch_bounds__(256) void ln_kernel(const float* __restrict__ x,
                                                 const float* __restrict__ gw,
                                                 const float* __restrict__ gb,
                                                 f16* __restrict__ H) {
  const int wv = threadIdx.x >> 6, lane = threadIdx.x & 63;
  const long row = (long)blockIdx.x * 4 + wv;
  const float* xr = x + row * 1024;
  float4 v[4];
  float s = 0.f, s2 = 0.f;
#pragma unroll
  for (int j = 0; j < 4; ++j) {
    v[j] = ((const float4*)xr)[lane + 64 * j];
    s  += v[j].x + v[j].y + v[j].z + v[j].w;
    s2 += v[j].x * v[j].x + v[j].y * v[j].y + v[j].z * v[j].z + v[j].w * v[j].w;
  }
#pragma unroll
  for (int off = 32; off > 0; off >>= 1) {
    s  += __shfl_xor(s, off);
    s2 += __shfl_xor(s2, off);
  }
  const float mu = s * (1.0f / 1024.0f);
  const float rstd = rsqrtf(s2 * (1.0f / 1024.0f) - mu * mu + 1e-5f);
#pragma unroll
  for (int j = 0; j < 4; ++j) {
    const float4 w4 = ((const float4*)gw)[lane + 64 * j];
    const float4 b4 = ((const float4*)gb)[lane + 64 * j];
    f16x4 h;
    h[0] = (f16)((v[j].x - mu) * rstd * w4.x + b4.x);
    h[1] = (f16)((v[j].y - mu) * rstd * w4.y + b4.y);
    h[2] = (f16)((v[j].z - mu) * rstd * w4.z + b4.z);
    h[3] = (f16)((v[j].w - mu) * rstd * w4.w + b4.w);
    *(f16x4*)(H + row * 1024 + (lane + 64 * j) * 4) = h;
  }
}

// ---------------- transpose H -> Ht, fused colsum ----------------
__global__ __launch_bounds__(256) void transpose_cs_kernel(const f16* __restrict__ H,
                                                           f16* __restrict__ Ht,
                                                           float* __restrict__ hs) {
  __shared__ f16 tile[64][68];
  __shared__ float csum[4][64];
  const int b = blockIdx.z;
  const long Hb  = (long)b * 4096 * 1024;
  const long Htb = (long)b * 1024 * 4096;
  const int t0 = blockIdx.y * 64, c0 = blockIdx.x * 64;
  const int tid = threadIdx.x;
  const int r = tid >> 2, g0 = tid & 3;
#pragma unroll
  for (int i = 0; i < 4; ++i) {
    const int g = g0 + i * 4;
    f16x4 v = *(const f16x4*)(H + Hb + (long)(t0 + r) * 1024 + c0 + g * 4);
    *(f16x4*)&tile[r][g * 4] = v;
  }
  __syncthreads();
  {
    const int cl = tid & 63, rg = tid >> 6;
    float s = 0.f;
#pragma unroll
    for (int rr = 0; rr < 16; ++rr) s += (float)tile[rg * 16 + rr][cl];
    csum[rg][cl] = s;
  }
#pragma unroll
  for (int i = 0; i < 4; ++i) {
    const int g = g0 + i * 4;
    f16x4 v;
    v[0] = tile[g * 4 + 0][r];
    v[1] = tile[g * 4 + 1][r];
    v[2] = tile[g * 4 + 2][r];
    v[3] = tile[g * 4 + 3][r];
    *(f16x4*)(Ht + Htb + (long)(c0 + r) * 4096 + t0 + g * 4) = v;
  }
  __syncthreads();
  if (tid < 64)
    atomicAdd(&hs[b * 1024 + c0 + tid],
              csum[0][tid] + csum[1][tid] + csum[2][tid] + csum[3][tid]);
}

// ---------------- transcast4: z=0..2 transpose qkv (z>=1 also straight cast), z=3 cast proj ----------------
__global__ __launch_bounds__(256) void transcast4(const float* __restrict__ qkv_w,
                                                  const float* __restrict__ proj_w,
                                                  f16* __restrict__ WT3,
                                                  f16* __restrict__ Wh,
                                                  f16* __restrict__ Ph) {
  const int z = blockIdx.z;
  __shared__ f16 tile[64][68];
  const int r0 = blockIdx.y * 64, c0 = blockIdx.x * 64;
  const int tid = threadIdx.x;
  const int r = tid >> 2, g0 = tid & 3;
  if (z == 3) {
#pragma unroll
    for (int i = 0; i < 4; ++i) {
      const int g = g0 + i * 4;
      float4 v = *(const float4*)(proj_w + (long)(r0 + r) * 1024 + c0 + g * 4);
      f16x4 h; h[0]=(f16)v.x; h[1]=(f16)v.y; h[2]=(f16)v.z; h[3]=(f16)v.w;
      *(f16x4*)(Ph + (long)(r0 + r) * 1024 + c0 + g * 4) = h;
    }
    return;
  }
  const float* W = qkv_w + (long)z * 1048576;
  f16* WT = WT3 + (long)z * 1048576;
#pragma unroll
  for (int i = 0; i < 4; ++i) {
    const int g = g0 + i * 4;
    float4 v = *(const float4*)(W + (long)(r0 + r) * 1024 + c0 + g * 4);
    f16x4 h; h[0]=(f16)v.x; h[1]=(f16)v.y; h[2]=(f16)v.z; h[3]=(f16)v.w;
    *(f16x4*)&tile[r][g * 4] = h;
    if (z >= 1)
      *(f16x4*)(Wh + (long)z * 1048576 + (long)(r0 + r) * 1024 + c0 + g * 4) = h;
  }
  __syncthreads();
#pragma unroll
  for (int i = 0; i < 4; ++i) {
    const int g = g0 + i * 4;
    f16x4 v;
    v[0] = tile[g * 4 + 0][r];
    v[1] = tile[g * 4 + 1][r];
    v[2] = tile[g * 4 + 2][r];
    v[3] = tile[g * 4 + 3][r];
    *(f16x4*)(WT + (long)(c0 + r) * 1024 + r0 + g * 4) = v;
  }
}

// ---------------- f16row . f32vec, 1024 elems, one 64-lane wave ----------------
__device__ __forceinline__ float dot1024(const f16* __restrict__ row,
                                         const float* __restrict__ v) {
  const int lane = threadIdx.x & 63;
  float s = 0.f;
#pragma unroll
  for (int j = 0; j < 2; ++j) {
    const int d = (lane + 64 * j) * 8;
    f16x8 a = *(const f16x8*)(row + d);
    float4 h0 = *(const float4*)(v + d);
    float4 h1 = *(const float4*)(v + d + 4);
    s += (float)a[0] * h0.x + (float)a[1] * h0.y + (float)a[2] * h0.z + (float)a[3] * h0.w
       + (float)a[4] * h1.x + (float)a[5] * h1.y + (float)a[6] * h1.z + (float)a[7] * h1.w;
  }
#pragma unroll
  for (int off = 32; off > 0; off >>= 1) s += __shfl_down(s, off);
  return s;
}

__device__ __forceinline__ float dotf1024(const float* __restrict__ a,
                                          const float* __restrict__ v) {
  const int lane = threadIdx.x & 63;
  float s = 0.f;
#pragma unroll
  for (int j = 0; j < 4; ++j) {
    const int d = (lane + 64 * j) * 4;
    float4 x = *(const float4*)(a + d);
    float4 q = *(const float4*)(v + d);
    s += x.x * q.x + x.y * q.y + x.z * q.z + x.w * q.w;
  }
#pragma unroll
  for (int off = 32; off > 0; off >>= 1) s += __shfl_down(s, off);
  return s;
}

// ---------------- gemv3a: a = WqT.bk, y = WkT.bq, d = Ph.bv, scal[4] = bk.bq ----------------
__global__ void gemv3a(const f16* __restrict__ WT3, const f16* __restrict__ Ph,
                       const float* __restrict__ qkv_b, float* __restrict__ ayd,
                       float* __restrict__ scal) {
  if (blockIdx.x == 3072) {
    float s = dotf1024(qkv_b + 1024, qkv_b);
    if ((threadIdx.x & 63) == 0) scal[4] = s;
    return;
  }
  const int which = blockIdx.x >> 10, m = blockIdx.x & 1023;
  const f16* row;
  const float* v;
  if (which == 0)      { row = WT3 + (long)m * 1024;            v = qkv_b + 1024; } // a
  else if (which == 1) { row = WT3 + 1048576 + (long)m * 1024;  v = qkv_b; }        // y
  else                 { row = Ph + (long)m * 1024;             v = qkv_b + 2048; } // d
  float s = dot1024(row, v);
  if ((threadIdx.x & 63) == 0) ayd[which * 1024 + m] = s;
}

// ---------------- gemv3b: e = U.hs, f = PWv.hs, z = G.y; blocks >= 12288: scal[b] = hs_b.y ----------------
__global__ void gemv3b(const f16* __restrict__ U, const f16* __restrict__ PWv,
                       const f16* __restrict__ Gh, const float* __restrict__ hs,
                       const float* __restrict__ ayd, float* __restrict__ efz,
                       float* __restrict__ scal) {
  if (blockIdx.x >= 12288) {
    const int b = blockIdx.x - 12288;
    float s = dotf1024(hs + b * 1024, ayd + 1024);
    if ((threadIdx.x & 63) == 0) scal[b] = s;
    return;
  }
  const int sel = blockIdx.x >> 12, r = blockIdx.x & 4095;
  const int b = r >> 10, m = r & 1023;
  const f16* row;
  const float* v;
  if (sel == 0)      { row = U + (long)m * 1024;                       v = hs + b * 1024; }
  else if (sel == 1) { row = PWv + (long)m * 1024;                     v = hs + b * 1024; }
  else               { row = Gh + (long)b * 1048576 + (long)m * 1024;  v = ayd + 1024; }
  float s = dot1024(row, v);
  if ((threadIdx.x & 63) == 0) efz[sel * 4096 + r] = s;
}

// ---------------- c2_b[c] = (PWv_row_c . z_b + d_c*s_u_b + s_b*(f_b_c + 4096 d_c))/32 + proj_b[c] ----------------
__global__ void gemvC2n(const f16* __restrict__ PWv, const float* __restrict__ efz,
                        const float* __restrict__ ayd, const float* __restrict__ scal,
                        const float* __restrict__ proj_b, float* __restrict__ c2) {
  const int b = blockIdx.x >> 10, c = blockIdx.x & 1023;
  float s = dot1024(PWv + (long)c * 1024, efz + 8192 + b * 1024);
  if ((threadIdx.x & 63) == 0) {
    const float d = ayd[2048 + c];
    c2[b * 1024 + c] = (s + d * scal[b] + scal[4] * (efz[4096 + b * 1024 + c] + 4096.f * d))
                         * 0.03125f + proj_b[c];
  }
}

// ================= shared GEMM machinery (BK = 64) =================
#define GP64_COMMON()                                        \
  const int tid = threadIdx.x;                               \
  const int wave = tid >> 6, lane = tid & 63;                \
  const int lr = lane & 15, lk = lane >> 4;                  \
  const int srow = tid >> 3;                                 \
  const int slc  = (tid & 7) ^ (srow & 7);                   \
  const int kc0 = ((lk) ^ (lr & 7)) * 8;                     \
  const int kc1 = ((4 + lk) ^ (lr & 7)) * 8;

#define GEMM_WAIT8(NBUF_, r_)                                               \
  do {                                                                      \
    if constexpr (NBUF_ == 3) {                                             \
      if ((r_) >= 2)      asm volatile("s_waitcnt vmcnt(16)" ::: "memory"); \
      else if ((r_) == 1) asm volatile("s_waitcnt vmcnt(8)" ::: "memory");  \
      else                asm volatile("s_waitcnt vmcnt(0)" ::: "memory");  \
    } else {                                                                \
      if ((r_) >= 1)      asm volatile("s_waitcnt vmcnt(8)" ::: "memory");  \
      else                asm volatile("s_waitcnt vmcnt(0)" ::: "memory");  \
    }                                                                       \
  } while (0)

#define COMP64_HALF(asb_, bsb_, kc_)                                             \
  do {                                                                           \
    const f16* asb = (asb_);                                                     \
    const f16* bsb = (bsb_);                                                     \
    f16x8 af[4], bf[4];                                                          \
    _Pragma("unroll")                                                            \
    for (int mi = 0; mi < 4; ++mi)                                               \
      af[mi] = *(const f16x8*)(asb + (wm * 64 + mi * 16 + lr) * 64 + (kc_));     \
    _Pragma("unroll")                                                            \
    for (int ni = 0; ni < 4; ++ni)                                               \
      bf[ni] = *(const f16x8*)(bsb + (wn * 64 + ni * 16 + lr) * 64 + (kc_));     \
    _Pragma("unroll")                                                            \
    for (int mi = 0; mi < 4; ++mi)                                               \
      _Pragma("unroll")                                                          \
      for (int ni = 0; ni < 4; ++ni)                                             \
        acc[mi][ni] = __builtin_amdgcn_mfma_f32_16x16x32_f16(af[mi], bf[ni],     \
                                                             acc[mi][ni], 0, 0, 0); \
  } while (0)

#define GEMM_BODY_LOOP(NBUF_, NT_, STAGEM)                       \
  do {                                                           \
    if constexpr (NBUF_ == 3) {                                  \
      STAGEM(0, 0); STAGEM(1, 1);                                \
      int cur = 0, stg = 2;                                      \
      for (int t = 0; t < (NT_); ++t) {                          \
        if (t + 2 < (NT_)) STAGEM(stg, t + 2);                   \
        GEMM_WAIT8(3, (NT_) - 1 - t);                            \
        asm volatile("s_barrier" ::: "memory");                  \
        __builtin_amdgcn_s_setprio(1);                           \
        COMP64_HALF(&As[cur][0], &Bs[cur][0], kc0);              \
        COMP64_HALF(&As[cur][0], &Bs[cur][0], kc1);              \
        __builtin_amdgcn_s_setprio(0);                           \
        asm volatile("s_waitcnt lgkmcnt(0)" ::: "memory");       \
        asm volatile("s_barrier" ::: "memory");                  \
        cur = (cur + 1 == 3) ? 0 : cur + 1;                      \
        stg = (stg + 1 == 3) ? 0 : stg + 1;                      \
      }                                                          \
    } else {                                                     \
      STAGEM(0, 0);                                              \
      int cur = 0;                                               \
      for (int t = 0; t < (NT_); ++t) {                          \
        if (t + 1 < (NT_)) STAGEM(cur ^ 1, t + 1);               \
        GEMM_WAIT8(2, (NT_) - 1 - t);                            \
        asm volatile("s_barrier" ::: "memory");                  \
        __builtin_amdgcn_s_setprio(1);                           \
        COMP64_HALF(&As[cur][0], &Bs[cur][0], kc0);              \
        COMP64_HALF(&As[cur][0], &Bs[cur][0], kc1);              \
        __builtin_amdgcn_s_setprio(0);                           \
        asm volatile("s_waitcnt lgkmcnt(0)" ::: "memory");       \
        asm volatile("s_barrier" ::: "memory");                  \
        cur ^= 1;                                                \
      }                                                          \
    }                                                            \
  } while (0)

// ---------------- chain GEMM: 128x128, BK=64, NBUF=3 ----------------
template <int MODE>
__global__ __launch_bounds__(256) void gemm128(
    const f16* __restrict__ A, const f16* __restrict__ B, int K,
    long sA, long sB, long sC,
    f16* __restrict__ Ch,
    const float* __restrict__ dvec, const float* __restrict__ evec,
    const float* __restrict__ fvec, const float* __restrict__ avec) {
  const int b = blockIdx.z;
  A += (long)b * sA;
  B += (long)b * sB;
  const int nx = blockIdx.y & 7;
  const int ny = blockIdx.x;

  GP64_COMMON();
  const int wm = wave >> 1, wn = wave & 1;

  __shared__ __align__(16) f16 As[3][8192];
  __shared__ __align__(16) f16 Bs[3][8192];

  const long aoffs = (long)(ny * 128 + srow) * K + slc * 8;
  const long boffs = (long)(nx * 128 + srow) * K + slc * 8;

  f32x4 zero = {0.f, 0.f, 0.f, 0.f};
  f32x4 acc[4][4];
#pragma unroll
  for (int mi = 0; mi < 4; ++mi)
#pragma unroll
    for (int ni = 0; ni < 4; ++ni) acc[mi][ni] = zero;

#define STAGE(buf, kt)                                                              \
  do {                                                                              \
    f16* asb = &As[buf][0];                                                         \
    f16* bsb = &Bs[buf][0];                                                         \
    _Pragma("unroll")                                                               \
    for (int q = 0; q < 4; ++q) {                                                   \
      gl_lds16(A + aoffs + (long)q * 32 * K + (kt) * 64, asb + q * 2048 + tid * 8); \
      gl_lds16(B + boffs + (long)q * 32 * K + (kt) * 64, bsb + q * 2048 + tid * 8); \
    }                                                                               \
  } while (0)

  const int nt = K >> 6;
  GEMM_BODY_LOOP(3, nt, STAGE);
#undef STAGE

  const long cb = (long)b * sC;
  const int m0 = ny * 128 + wm * 64;
  const int n0 = nx * 128 + wn * 64;
#pragma unroll
  for (int mi = 0; mi < 4; ++mi)
#pragma unroll
    for (int ni = 0; ni < 4; ++ni)
#pragma unroll
      for (int j = 0; j < 4; ++j) {
        const int gm = m0 + mi * 16 + lk * 4 + j;
        const int gn = n0 + ni * 16 + lr;
        float val = acc[mi][ni][j];
        if constexpr (MODE == 0) {
          Ch[cb + (long)gm * 1024 + gn] = (f16)val;
        } else {
          const float dm = dvec[gm];
          const float fm = fvec[b * 1024 + gm];
          const float en = evec[b * 1024 + gn];
          const float an = avec[gn];
          val = (val + dm * en + (fm + 4096.f * dm) * an) * 0.03125f;
          Ch[cb + (long)gm * 1024 + gn] = (f16)val;
        }
      }
}

// ---------------- MERGED: G = H^T H (tri, split-K=4) + {U, PWv}; fine 2-phase pipeline ----------------
// XCD clustering: zz = bid & 15, tileid = bid >> 4 (all 36 tiles of a K-slice on one XCD).
// Fine phases per K-tile (A quadrants by mi): phase A = mi 0-1 (needs B all + A q0,q2),
// phase B = mi 2-3 (needs A q1,q3). Staging order B0-3,A0,A2 (phase A) then A1,A3 (phase B).
// Entry waits: A: vmcnt(2)->barrier; B: vmcnt(6|0)->barrier. Reads strictly after barrier.
__global__ __launch_bounds__(256) void gemmGUV(const f16* __restrict__ Ht,
                                               const f16* __restrict__ WT3,
                                               const f16* __restrict__ Ph,
                                               f16* __restrict__ part,
                                               f16* __restrict__ U,
                                               f16* __restrict__ PWv) {
  GP64_COMMON();
  const int wm = wave >> 1, wn = wave & 1;

  __shared__ __align__(16) f16 As[2][8192];
  __shared__ __align__(16) f16 Bs[2][8192];

  const int bid = blockIdx.x;
  const f16 *Ab, *Bb;
  long rs;
  int tileid = 0, zz = 0, selt = 0;
  if (bid < 576) {
    zz = bid & 15;           // K-slice*4 + batch  (XCD class = zz%8)
    tileid = bid >> 4;       // 0..35 triangular tile
    const int b = zz & 3, ks4 = zz >> 2;
    int ti = 0, trem = tileid;
    while (trem >= 8 - ti) { trem -= 8 - ti; ++ti; }
    const int tj = ti + trem;
    const f16* Hb = Ht + (long)b * 4194304;
    rs = 4096;
    Ab = Hb + (long)(ti * 128 + srow) * 4096 + (long)ks4 * 1024 + slc * 8;
    Bb = Hb + (long)(tj * 128 + srow) * 4096 + (long)ks4 * 1024 + slc * 8;
  } else {
    const int u = bid - 576;
    selt = (u >> 6) + 1;                 // 1: U, 2: PWv
    const int t = u & 63;
    const int ny = t >> 3, nxx = t & 7;
    const f16* A0 = (selt == 2) ? Ph : WT3;
    const f16* B0 = (selt == 2) ? (WT3 + 2097152) : (WT3 + 1048576);
    rs = 1024;
    Ab = A0 + (long)(ny * 128 + srow) * 1024 + slc * 8;
    Bb = B0 + (long)(nxx * 128 + srow) * 1024 + slc * 8;
  }

  f32x4 zero = {0.f, 0.f, 0.f, 0.f};
  f32x4 acc[4][4];
#pragma unroll
  for (int mi = 0; mi < 4; ++mi)
#pragma unroll
    for (int ni = 0; ni < 4; ++ni) acc[mi][ni] = zero;

#define SAq(buf, kt, q) gl_lds16(Ab + (long)(q) * 32 * rs + (kt) * 64, &As[buf][(q) * 2048] + tid * 8)
#define SBq(buf, kt, q) gl_lds16(Bb + (long)(q) * 32 * rs + (kt) * 64, &Bs[buf][(q) * 2048] + tid * 8)

  const int nt = 16;
  // prologue: tile 0 staged in consumption order
  SBq(0, 0, 0); SBq(0, 0, 1); SBq(0, 0, 2); SBq(0, 0, 3);
  SAq(0, 0, 0); SAq(0, 0, 2); SAq(0, 0, 1); SAq(0, 0, 3);

  int cur = 0;
  for (int t = 0; t < nt; ++t) {
    const f16* asb = &As[cur][0];
    const f16* bsb = &Bs[cur][0];
    const int nb = cur ^ 1;
    const bool st = (t + 1 < nt);
    f16x8 bf[4][2], af[2][2];

    // ---- phase A: mi 0-1 ----
    asm volatile("s_waitcnt vmcnt(2)" ::: "memory");   // oldest 6 of tile t (B0-3,A0,A2)
    asm volatile("s_barrier" ::: "memory");            // visible to all waves
#pragma unroll
    for (int ni = 0; ni < 4; ++ni) {
      bf[ni][0] = *(const f16x8*)(bsb + (wn * 64 + ni * 16 + lr) * 64 + kc0);
      bf[ni][1] = *(const f16x8*)(bsb + (wn * 64 + ni * 16 + lr) * 64 + kc1);
    }
#pragma unroll
    for (int mi = 0; mi < 2; ++mi) {
      af[mi][0] = *(const f16x8*)(asb + (wm * 64 + mi * 16 + lr) * 64 + kc0);
      af[mi][1] = *(const f16x8*)(asb + (wm * 64 + mi * 16 + lr) * 64 + kc1);
    }
    if (st) { SBq(nb, t + 1, 0); SBq(nb, t + 1, 1); SBq(nb, t + 1, 2); SBq(nb, t + 1, 3);
              SAq(nb, t + 1, 0); SAq(nb, t + 1, 2); }
    asm volatile("s_waitcnt lgkmcnt(0)" ::: "memory");
    __builtin_amdgcn_s_setprio(1);
#pragma unroll
    for (int ks = 0; ks < 2; ++ks)
#pragma unroll
      for (int mi = 0; mi < 2; ++mi)
#pragma unroll
        for (int ni = 0; ni < 4; ++ni)
          acc[mi][ni] = __builtin_amdgcn_mfma_f32_16x16x32_f16(af[mi][ks], bf[ni][ks],
                                                               acc[mi][ni], 0, 0, 0);
    __builtin_amdgcn_s_setprio(0);
    asm volatile("s_barrier" ::: "memory");

    // ---- phase B: mi 2-3 ----
    if (st) asm volatile("s_waitcnt vmcnt(6)" ::: "memory");  // A1,A3 of tile t landed
    else    asm volatile("s_waitcnt vmcnt(0)" ::: "memory");
    asm volatile("s_barrier" ::: "memory");
#pragma unroll
    for (int mi = 0; mi < 2; ++mi) {
      af[mi][0] = *(const f16x8*)(asb + (wm * 64 + (mi + 2) * 16 + lr) * 64 + kc0);
      af[mi][1] = *(const f16x8*)(asb + (wm * 64 + (mi + 2) * 16 + lr) * 64 + kc1);
    }
    if (st) { SAq(nb, t + 1, 1); SAq(nb, t + 1, 3); }
    asm volatile("s_waitcnt lgkmcnt(0)" ::: "memory");
    __builtin_amdgcn_s_setprio(1);
#pragma unroll
    for (int ks = 0; ks < 2; ++ks)
#pragma unroll
      for (int mi = 0; mi < 2; ++mi)
#pragma unroll
        for (int ni = 0; ni < 4; ++ni)
          acc[mi + 2][ni] = __builtin_amdgcn_mfma_f32_16x16x32_f16(af[mi][ks], bf[ni][ks],
                                                                   acc[mi + 2][ni], 0, 0, 0);
    __builtin_amdgcn_s_setprio(0);
    asm volatile("s_barrier" ::: "memory");

    cur ^= 1;
  }
#undef SAq
#undef SBq

  if (selt == 0) {
    f16* P = part + ((long)zz * 36 + tileid) * 16384;
#pragma unroll
    for (int mi = 0; mi < 4; ++mi)
#pragma unroll
      for (int ni = 0; ni < 4; ++ni)
#pragma unroll
        for (int j = 0; j < 4; ++j) {
          const int gm = wm * 64 + mi * 16 + lk * 4 + j;
          const int gn = wn * 64 + ni * 16 + lr;
          P[gm * 128 + gn] = (f16)acc[mi][ni][j];
        }
  } else {
    const int u = bid - 576;
    const int t = u & 63;
    const int ny = t >> 3, nxx = t & 7;
    f16* C = (selt == 2) ? PWv : U;
    const int m0 = ny * 128 + wm * 64;
    const int n0 = nxx * 128 + wn * 64;
#pragma unroll
    for (int mi = 0; mi < 4; ++mi)
#pragma unroll
      for (int ni = 0; ni < 4; ++ni)
#pragma unroll
        for (int j = 0; j < 4; ++j) {
          const int gm = m0 + mi * 16 + lk * 4 + j;
          const int gn = n0 + ni * 16 + lr;
          C[(long)gm * 1024 + gn] = (f16)acc[mi][ni][j];
        }
  }
}

// ---------------- FINAL GEMM: 256x256 tile, 8 waves, BK=64, fine 4-phase with correct sync ----------------
__global__ __launch_bounds__(512) void gemm256f(
    const f16* __restrict__ A,       // H flat [16384][1024]
    const f16* __restrict__ Bw,      // W2T [4][1024][1024]
    const float* __restrict__ resid,
    const float* __restrict__ c2v,
    float* __restrict__ outF) {
  const int lin = blockIdx.y * 4 + blockIdx.x;
  const int xcd = lin & 7, slot = lin >> 3;
  const int ny = xcd * 8 + (slot >> 2);          // 0..63  (M tile)
  const int nx = slot & 3;                       // 0..3   (N tile)
  const int bb = ny >> 4;

  GP64_COMMON();
  const int wm = wave >> 2, wn = wave & 3;       // 2 x 4 wave grid

  __shared__ __align__(16) f16 As[2][16384];
  __shared__ __align__(16) f16 Bs[2][16384];

  const f16* Ab = A + (long)ny * 262144;
  const f16* Bb = Bw + (long)bb * 1048576 + (long)nx * 262144;
  const long offs = (long)srow * 1024 + slc * 8;

  f32x4 zero = {0.f, 0.f, 0.f, 0.f};
  f32x4 acc[8][4];
#pragma unroll
  for (int mi = 0; mi < 8; ++mi)
#pragma unroll
    for (int ni = 0; ni < 4; ++ni) acc[mi][ni] = zero;

#define SA(buf, kt, q) gl_lds16(Ab + offs + (long)(q) * 65536 + (kt) * 64, &As[buf][(q) * 4096] + tid * 8)
#define SB(buf, kt, q) gl_lds16(Bb + offs + (long)(q) * 65536 + (kt) * 64, &Bs[buf][(q) * 4096] + tid * 8)

#define RD_BF(dst, bsb, kc)                                                       \
  _Pragma("unroll")                                                               \
  for (int ni = 0; ni < 4; ++ni)                                                  \
    dst[ni] = *(const f16x8*)((bsb) + (wn * 64 + ni * 16 + lr) * 64 + (kc));
#define RD_AF(dst, asb, mh, kc)                                                   \
  _Pragma("unroll")                                                               \
  for (int mi = 0; mi < 4; ++mi)                                                  \
    dst[mi] = *(const f16x8*)((asb) + (wm * 128 + (mh) * 64 + mi * 16 + lr) * 64 + (kc));
#define MF16(af_, bf_, mo)                                                        \
  __builtin_amdgcn_s_setprio(1);                                                  \
  _Pragma("unroll")                                                               \
  for (int mi = 0; mi < 4; ++mi)                                                  \
    _Pragma("unroll")                                                             \
    for (int ni = 0; ni < 4; ++ni)                                                \
      acc[(mo) + mi][ni] = __builtin_amdgcn_mfma_f32_16x16x32_f16(af_[mi], bf_[ni], \
                                                                  acc[(mo) + mi][ni], 0, 0, 0); \
  __builtin_amdgcn_s_setprio(0);

  const int nt = 16;
  // prologue: stage tile 0 in consumption order
  SB(0, 0, 0); SB(0, 0, 1); SB(0, 0, 2); SB(0, 0, 3);
  SA(0, 0, 0); SA(0, 0, 2); SA(0, 0, 1); SA(0, 0, 3);

  int cur = 0;
  for (int t = 0; t < nt; ++t) {
    const f16* asb = &As[cur][0];
    const f16* bsb = &Bs[cur][0];
    const int nb = cur ^ 1;
    const bool st = (t + 1 < nt);
    f16x8 bf[4], af[4];

    // ---- P0: (mh0, ks0) ----
    asm volatile("s_waitcnt vmcnt(2)" ::: "memory");   // 6 oldest of tile t landed (per wave)
    asm volatile("s_barrier" ::: "memory");            // ...for ALL waves -> B0-3,A0,A2 readable
    RD_BF(bf, bsb, kc0);
    RD_AF(af, asb, 0, kc0);
    if (st) { SB(nb, t + 1, 0); SB(nb, t + 1, 1); }
    asm volatile("s_waitcnt lgkmcnt(0)" ::: "memory");
    MF16(af, bf, 0);
    asm volatile("s_barrier" ::: "memory");

    // ---- P1: (mh1, ks0) ----
    if (st) asm volatile("s_waitcnt vmcnt(2)" ::: "memory");  // A1,A3 of tile t landed
    else    asm volatile("s_waitcnt vmcnt(0)" ::: "memory");  // last iter: only A1,A3 outstanding
    asm volatile("s_barrier" ::: "memory");
    RD_AF(af, asb, 1, kc0);
    if (st) { SB(nb, t + 1, 2); SB(nb, t + 1, 3); }
    asm volatile("s_waitcnt lgkmcnt(0)" ::: "memory");
    MF16(af, bf, 4);
    asm volatile("s_barrier" ::: "memory");

    // ---- P2: (mh0, ks1) — quadrants already verified ----
    RD_BF(bf, bsb, kc1);
    RD_AF(af, asb, 0, kc1);
    if (st) { SA(nb, t + 1, 0); SA(nb, t + 1, 2); }
    asm volatile("s_waitcnt lgkmcnt(0)" ::: "memory");
    MF16(af, bf, 0);
    asm volatile("s_barrier" ::: "memory");

    // ---- P3: (mh1, ks1) ----
    RD_AF(af, asb, 1, kc1);
    if (st) { SA(nb, t + 1, 1); SA(nb, t + 1, 3); }
    asm volatile("s_waitcnt lgkmcnt(0)" ::: "memory");
    MF16(af, bf, 4);
    asm volatile("s_barrier" ::: "memory");

    cur ^= 1;
  }
#undef SA
#undef SB
#undef RD_BF
#undef RD_AF
#undef MF16

  // drain any residual DMA before reusing LDS
  asm volatile("s_waitcnt vmcnt(0)" ::: "memory");
  asm volatile("s_barrier" ::: "memory");

  // -------- LDS-staged vectorized epilogue (reuses As) --------
  float* weps = ((float*)&As[0][0]) + wave * 1088;
  const int m0 = ny * 256 + wm * 128;
  const int n0 = nx * 256 + wn * 64;
  const int err = lane >> 3;
  const int ecc = (lane & 7) * 4;
  float4 cc2[2];
#pragma unroll
  for (int q = 0; q < 2; ++q)
    cc2[q] = *(const float4*)&c2v[bb * 1024 + n0 + ecc + 32 * q];

#pragma unroll
  for (int mi = 0; mi < 8; ++mi) {
#pragma unroll
    for (int ni = 0; ni < 4; ++ni)
#pragma unroll
      for (int j = 0; j < 4; ++j)
        weps[(lk * 4 + j) * 68 + ni * 16 + lr] = acc[mi][ni][j];
    asm volatile("s_waitcnt lgkmcnt(0)" ::: "memory");
#pragma unroll
    for (int h = 0; h < 2; ++h)
#pragma unroll
      for (int q = 0; q < 2; ++q) {
        const int rr = err + 8 * h;
        const int cc = ecc + 32 * q;
        float4 o = *(const float4*)&weps[rr * 68 + cc];
        const long gbase = (long)(m0 + mi * 16 + rr) * 1024 + n0 + cc;
        const float4 rv = *(const float4*)&resid[gbase];
        float4 ov;
        ov.x = o.x + rv.x + cc2[q].x;
        ov.y = o.y + rv.y + cc2[q].y;
        ov.z = o.z + rv.z + cc2[q].z;
        ov.w = o.w + rv.w + cc2[q].w;
        *(float4*)&outF[gbase] = ov;
      }
  }
}

// ---------------- reduce triangular G partials -> Gh, mirror ----------------
__global__ __launch_bounds__(256) void treduce(const f16* __restrict__ part,
                                               f16* __restrict__ Gh) {
  const int tileid = blockIdx.x, b = blockIdx.y;
  int ti = 0, trem = tileid;
  while (trem >= 8 - ti) { trem -= 8 - ti; ++ti; }
  const int tj = ti + trem;
  __shared__ f16 tl[128][132];
  const int tid = threadIdx.x;
  f16* Gb = Gh + (long)b * 1048576;
#pragma unroll
  for (int it = 0; it < 16; ++it) {
    const int e = it * 1024 + tid * 4;
    const int r = e >> 7, c = e & 127;
    f16x4 p0 = *(const f16x4*)(part + ((long)(0 * 4 + b) * 36 + tileid) * 16384 + e);
    f16x4 p1 = *(const f16x4*)(part + ((long)(1 * 4 + b) * 36 + tileid) * 16384 + e);
    f16x4 p2 = *(const f16x4*)(part + ((long)(2 * 4 + b) * 36 + tileid) * 16384 + e);
    f16x4 p3 = *(const f16x4*)(part + ((long)(3 * 4 + b) * 36 + tileid) * 16384 + e);
    f16x4 sv;
#pragma unroll
    for (int j = 0; j < 4; ++j)
      sv[j] = (f16)((float)p0[j] + (float)p1[j] + (float)p2[j] + (float)p3[j]);
    *(f16x4*)(Gb + (long)(ti * 128 + r) * 1024 + tj * 128 + c) = sv;
    *(f16x4*)&tl[r][c] = sv;
  }
  if (ti != tj) {
    __syncthreads();
#pragma unroll
    for (int it = 0; it < 16; ++it) {
      const int e = it * 1024 + tid * 4;
      const int r = e >> 7, c = e & 127;
      f16x4 v;
      v[0] = tl[c + 0][r];
      v[1] = tl[c + 1][r];
      v[2] = tl[c + 2][r];
      v[3] = tl[c + 3][r];
      *(f16x4*)(Gb + (long)(tj * 128 + r) * 1024 + ti * 128 + c) = v;
    }
  }
}

extern "C" void kernel_launch(void* const* d_in, const int* in_sizes, int n_in,
                              void* d_out, int out_size, void* d_ws, size_t ws_size,
                              hipStream_t stream) {
  const float* x      = (const float*)d_in[0];
  const float* norm_w = (const float*)d_in[1];
  const float* norm_b = (const float*)d_in[2];
  const float* qkv_w  = (const float*)d_in[3];
  const float* qkv_b  = (const float*)d_in[4];
  const float* proj_w = (const float*)d_in[5];
  const float* proj_b = (const float*)d_in[6];
  float* out = (float*)d_out;
  char* ws = (char*)d_ws;

  const size_t OFF_H    = 0;
  const size_t OFF_HT   = 33554432;
  const size_t OFF_T1   = 33554432;   // alias (Ht dead after gemmGUV)
  const size_t OFF_T2   = 41943040;
  const size_t OFF_WH   = 67108864;
  const size_t OFF_PH   = 73400320;
  const size_t OFF_WT3  = 75497472;
  const size_t OFF_U    = 81788928;
  const size_t OFF_PWV  = 83886080;
  const size_t OFF_GH   = 85983232;
  const size_t OFF_PART = 94371840;
  const size_t OFF_HS   = 115343360;
  const size_t OFF_AYD  = 115392512;
  const size_t OFF_SCAL = 115404800;
  const size_t OFF_EFZ  = 115405824;
  const size_t OFF_C2   = 115471360;

  f16* H    = (f16*)(ws + OFF_H);
  f16* Ht   = (f16*)(ws + OFF_HT);
  f16* T1   = (f16*)(ws + OFF_T1);
  f16* T2   = (f16*)(ws + OFF_T2);
  f16* Wh   = (f16*)(ws + OFF_WH);
  f16* Ph   = (f16*)(ws + OFF_PH);
  f16* WT3  = (f16*)(ws + OFF_WT3);
  f16* U    = (f16*)(ws + OFF_U);
  f16* PWv  = (f16*)(ws + OFF_PWV);
  f16* Gh   = (f16*)(ws + OFF_GH);
  f16* part = (f16*)(ws + OFF_PART);
  float* hs   = (float*)(ws + OFF_HS);
  float* ayd  = (float*)(ws + OFF_AYD);
  float* scal = (float*)(ws + OFF_SCAL);
  float* efz  = (float*)(ws + OFF_EFZ);
  float* c2v  = (float*)(ws + OFF_C2);

  // weight prep (one pass over qkv_w; straight casts fused)
  transcast4<<<dim3(16, 16, 4), 256, 0, stream>>>(qkv_w, proj_w, WT3, Wh, Ph);
  gemv3a<<<dim3(3073), 64, 0, stream>>>(WT3, Ph, qkv_b, ayd, scal);

  // input path
  ln_kernel<<<dim3(4096), 256, 0, stream>>>(x, norm_w, norm_b, H);
  hipMemsetAsync(ws + OFF_HS, 0, 16384, stream);
  transpose_cs_kernel<<<dim3(16, 64, 4), 256, 0, stream>>>(H, Ht, hs);

  // merged: G tri-tiles (576 blocks, XCD-clustered by K-slice) + U/PWv (128 blocks)
  gemmGUV<<<dim3(704), 256, 0, stream>>>(Ht, WT3, Ph, part, U, PWv);
  treduce<<<dim3(36, 4), 256, 0, stream>>>(part, Gh);

  // gemv cluster: e, f, z, s_u  then c2 directly
  gemv3b<<<dim3(12292), 64, 0, stream>>>(U, PWv, Gh, hs, ayd, efz, scal);
  gemvC2n<<<dim3(4096), 64, 0, stream>>>(PWv, efz, ayd, scal, proj_b, c2v);

  // T1_b = U (x) G_b
  gemm128<0><<<dim3(8, 8, 4), 256, 0, stream>>>(U, Gh, 1024, 0L, 1048576L, 1048576L,
      T1, nullptr, nullptr, nullptr, nullptr);
  // W2T_b = (PWv (x) T1_b + d e^T + (f + 4096 d) a^T) / 32
  gemm128<1><<<dim3(8, 8, 4), 256, 0, stream>>>(PWv, T1, 1024, 0L, 1048576L, 1048576L,
      T2, ayd + 2048, efz, efz + 4096, ayd);

  // out = X + H (x) W2T + c2
  gemm256f<<<dim3(4, 64), 512, 0, stream>>>(H, T2, x, c2v, out);
}

// Round 18
// 185.583 us; speedup vs baseline: 1.0972x; 1.0240x over previous
//
#include <hip/hip_runtime.h>

typedef _Float16 f16;
typedef _Float16 f16x4 __attribute__((ext_vector_type(4)));
typedef _Float16 f16x8 __attribute__((ext_vector_type(8)));
typedef float f32x4 __attribute__((ext_vector_type(4)));

#define AS1 __attribute__((address_space(1)))
#define AS3 __attribute__((address_space(3)))

__device__ __forceinline__ void gl_lds16(const f16* g, f16* l) {
  __builtin_amdgcn_global_load_lds((const AS1 void*)g, (AS3 void*)l, 16, 0, 0);
}

// ---------------- LayerNorm: x (fp32) -> H (f16), one WAVE per row ----------------
__global__ __launch_bounds__(256) void ln_kernel(const float* __restrict__ x,
                                                 const float* __restrict__ gw,
                                                 const float* __restrict__ gb,
                                                 f16* __restrict__ H) {
  const int wv = threadIdx.x >> 6, lane = threadIdx.x & 63;
  const long row = (long)blockIdx.x * 4 + wv;
  const float* xr = x + row * 1024;
  float4 v[4];
  float s = 0.f, s2 = 0.f;
#pragma unroll
  for (int j = 0; j < 4; ++j) {
    v[j] = ((const float4*)xr)[lane + 64 * j];
    s  += v[j].x + v[j].y + v[j].z + v[j].w;
    s2 += v[j].x * v[j].x + v[j].y * v[j].y + v[j].z * v[j].z + v[j].w * v[j].w;
  }
#pragma unroll
  for (int off = 32; off > 0; off >>= 1) {
    s  += __shfl_xor(s, off);
    s2 += __shfl_xor(s2, off);
  }
  const float mu = s * (1.0f / 1024.0f);
  const float rstd = rsqrtf(s2 * (1.0f / 1024.0f) - mu * mu + 1e-5f);
#pragma unroll
  for (int j = 0; j < 4; ++j) {
    const float4 w4 = ((const float4*)gw)[lane + 64 * j];
    const float4 b4 = ((const float4*)gb)[lane + 64 * j];
    f16x4 h;
    h[0] = (f16)((v[j].x - mu) * rstd * w4.x + b4.x);
    h[1] = (f16)((v[j].y - mu) * rstd * w4.y + b4.y);
    h[2] = (f16)((v[j].z - mu) * rstd * w4.z + b4.z);
    h[3] = (f16)((v[j].w - mu) * rstd * w4.w + b4.w);
    *(f16x4*)(H + row * 1024 + (lane + 64 * j) * 4) = h;
  }
}

// ---------------- transpose H -> Ht, fused colsum ----------------
__global__ __launch_bounds__(256) void transpose_cs_kernel(const f16* __restrict__ H,
                                                           f16* __restrict__ Ht,
                                                           float* __restrict__ hs) {
  __shared__ f16 tile[64][68];
  __shared__ float csum[4][64];
  const int b = blockIdx.z;
  const long Hb  = (long)b * 4096 * 1024;
  const long Htb = (long)b * 1024 * 4096;
  const int t0 = blockIdx.y * 64, c0 = blockIdx.x * 64;
  const int tid = threadIdx.x;
  const int r = tid >> 2, g0 = tid & 3;
#pragma unroll
  for (int i = 0; i < 4; ++i) {
    const int g = g0 + i * 4;
    f16x4 v = *(const f16x4*)(H + Hb + (long)(t0 + r) * 1024 + c0 + g * 4);
    *(f16x4*)&tile[r][g * 4] = v;
  }
  __syncthreads();
  {
    const int cl = tid & 63, rg = tid >> 6;
    float s = 0.f;
#pragma unroll
    for (int rr = 0; rr < 16; ++rr) s += (float)tile[rg * 16 + rr][cl];
    csum[rg][cl] = s;
  }
#pragma unroll
  for (int i = 0; i < 4; ++i) {
    const int g = g0 + i * 4;
    f16x4 v;
    v[0] = tile[g * 4 + 0][r];
    v[1] = tile[g * 4 + 1][r];
    v[2] = tile[g * 4 + 2][r];
    v[3] = tile[g * 4 + 3][r];
    *(f16x4*)(Ht + Htb + (long)(c0 + r) * 4096 + t0 + g * 4) = v;
  }
  __syncthreads();
  if (tid < 64)
    atomicAdd(&hs[b * 1024 + c0 + tid],
              csum[0][tid] + csum[1][tid] + csum[2][tid] + csum[3][tid]);
}

// ---------------- transcast4: z=0..2 transpose qkv (z>=1 also straight cast), z=3 cast proj ----------------
__global__ __launch_bounds__(256) void transcast4(const float* __restrict__ qkv_w,
                                                  const float* __restrict__ proj_w,
                                                  f16* __restrict__ WT3,
                                                  f16* __restrict__ Wh,
                                                  f16* __restrict__ Ph) {
  const int z = blockIdx.z;
  __shared__ f16 tile[64][68];
  const int r0 = blockIdx.y * 64, c0 = blockIdx.x * 64;
  const int tid = threadIdx.x;
  const int r = tid >> 2, g0 = tid & 3;
  if (z == 3) {
#pragma unroll
    for (int i = 0; i < 4; ++i) {
      const int g = g0 + i * 4;
      float4 v = *(const float4*)(proj_w + (long)(r0 + r) * 1024 + c0 + g * 4);
      f16x4 h; h[0]=(f16)v.x; h[1]=(f16)v.y; h[2]=(f16)v.z; h[3]=(f16)v.w;
      *(f16x4*)(Ph + (long)(r0 + r) * 1024 + c0 + g * 4) = h;
    }
    return;
  }
  const float* W = qkv_w + (long)z * 1048576;
  f16* WT = WT3 + (long)z * 1048576;
#pragma unroll
  for (int i = 0; i < 4; ++i) {
    const int g = g0 + i * 4;
    float4 v = *(const float4*)(W + (long)(r0 + r) * 1024 + c0 + g * 4);
    f16x4 h; h[0]=(f16)v.x; h[1]=(f16)v.y; h[2]=(f16)v.z; h[3]=(f16)v.w;
    *(f16x4*)&tile[r][g * 4] = h;
    if (z >= 1)
      *(f16x4*)(Wh + (long)z * 1048576 + (long)(r0 + r) * 1024 + c0 + g * 4) = h;
  }
  __syncthreads();
#pragma unroll
  for (int i = 0; i < 4; ++i) {
    const int g = g0 + i * 4;
    f16x4 v;
    v[0] = tile[g * 4 + 0][r];
    v[1] = tile[g * 4 + 1][r];
    v[2] = tile[g * 4 + 2][r];
    v[3] = tile[g * 4 + 3][r];
    *(f16x4*)(WT + (long)(c0 + r) * 1024 + r0 + g * 4) = v;
  }
}

// ---------------- f16row . f32vec, 1024 elems, one 64-lane wave ----------------
__device__ __forceinline__ float dot1024(const f16* __restrict__ row,
                                         const float* __restrict__ v) {
  const int lane = threadIdx.x & 63;
  float s = 0.f;
#pragma unroll
  for (int j = 0; j < 2; ++j) {
    const int d = (lane + 64 * j) * 8;
    f16x8 a = *(const f16x8*)(row + d);
    float4 h0 = *(const float4*)(v + d);
    float4 h1 = *(const float4*)(v + d + 4);
    s += (float)a[0] * h0.x + (float)a[1] * h0.y + (float)a[2] * h0.z + (float)a[3] * h0.w
       + (float)a[4] * h1.x + (float)a[5] * h1.y + (float)a[6] * h1.z + (float)a[7] * h1.w;
  }
#pragma unroll
  for (int off = 32; off > 0; off >>= 1) s += __shfl_down(s, off);
  return s;
}

__device__ __forceinline__ float dotf1024(const float* __restrict__ a,
                                          const float* __restrict__ v) {
  const int lane = threadIdx.x & 63;
  float s = 0.f;
#pragma unroll
  for (int j = 0; j < 4; ++j) {
    const int d = (lane + 64 * j) * 4;
    float4 x = *(const float4*)(a + d);
    float4 q = *(const float4*)(v + d);
    s += x.x * q.x + x.y * q.y + x.z * q.z + x.w * q.w;
  }
#pragma unroll
  for (int off = 32; off > 0; off >>= 1) s += __shfl_down(s, off);
  return s;
}

// ---------------- gemv3a: a = WqT.bk, y = WkT.bq, d = Ph.bv, scal[4] = bk.bq ----------------
__global__ void gemv3a(const f16* __restrict__ WT3, const f16* __restrict__ Ph,
                       const float* __restrict__ qkv_b, float* __restrict__ ayd,
                       float* __restrict__ scal) {
  if (blockIdx.x == 3072) {
    float s = dotf1024(qkv_b + 1024, qkv_b);
    if ((threadIdx.x & 63) == 0) scal[4] = s;
    return;
  }
  const int which = blockIdx.x >> 10, m = blockIdx.x & 1023;
  const f16* row;
  const float* v;
  if (which == 0)      { row = WT3 + (long)m * 1024;            v = qkv_b + 1024; } // a
  else if (which == 1) { row = WT3 + 1048576 + (long)m * 1024;  v = qkv_b; }        // y
  else                 { row = Ph + (long)m * 1024;             v = qkv_b + 2048; } // d
  float s = dot1024(row, v);
  if ((threadIdx.x & 63) == 0) ayd[which * 1024 + m] = s;
}

// ---------------- gemv3b: e = U.hs, f = PWv.hs, z = G.y; blocks >= 12288: scal[b] = hs_b.y ----------------
__global__ void gemv3b(const f16* __restrict__ U, const f16* __restrict__ PWv,
                       const f16* __restrict__ Gh, const float* __restrict__ hs,
                       const float* __restrict__ ayd, float* __restrict__ efz,
                       float* __restrict__ scal) {
  if (blockIdx.x >= 12288) {
    const int b = blockIdx.x - 12288;
    float s = dotf1024(hs + b * 1024, ayd + 1024);
    if ((threadIdx.x & 63) == 0) scal[b] = s;
    return;
  }
  const int sel = blockIdx.x >> 12, r = blockIdx.x & 4095;
  const int b = r >> 10, m = r & 1023;
  const f16* row;
  const float* v;
  if (sel == 0)      { row = U + (long)m * 1024;                       v = hs + b * 1024; }
  else if (sel == 1) { row = PWv + (long)m * 1024;                     v = hs + b * 1024; }
  else               { row = Gh + (long)b * 1048576 + (long)m * 1024;  v = ayd + 1024; }
  float s = dot1024(row, v);
  if ((threadIdx.x & 63) == 0) efz[sel * 4096 + r] = s;
}

// ---------------- c2_b[c] = (PWv_row_c . z_b + d_c*s_u_b + s_b*(f_b_c + 4096 d_c))/32 + proj_b[c] ----------------
__global__ void gemvC2n(const f16* __restrict__ PWv, const float* __restrict__ efz,
                        const float* __restrict__ ayd, const float* __restrict__ scal,
                        const float* __restrict__ proj_b, float* __restrict__ c2) {
  const int b = blockIdx.x >> 10, c = blockIdx.x & 1023;
  float s = dot1024(PWv + (long)c * 1024, efz + 8192 + b * 1024);
  if ((threadIdx.x & 63) == 0) {
    const float d = ayd[2048 + c];
    c2[b * 1024 + c] = (s + d * scal[b] + scal[4] * (efz[4096 + b * 1024 + c] + 4096.f * d))
                         * 0.03125f + proj_b[c];
  }
}

// ================= shared GEMM machinery (BK = 64) =================
#define GP64_COMMON()                                        \
  const int tid = threadIdx.x;                               \
  const int wave = tid >> 6, lane = tid & 63;                \
  const int lr = lane & 15, lk = lane >> 4;                  \
  const int srow = tid >> 3;                                 \
  const int slc  = (tid & 7) ^ (srow & 7);                   \
  const int kc0 = ((lk) ^ (lr & 7)) * 8;                     \
  const int kc1 = ((4 + lk) ^ (lr & 7)) * 8;

// Fine 2-phase pipelined body for 4-wave 128x128 tiles (proven in gemmGUV r17).
// Requires: As[2][8192], Bs[2][8192], Ab/Bb pre-swizzled base ptrs, rs row stride,
// acc[4][4], wm/wn, kc0/kc1. Staging order B0-3,A0,A2 | A1,A3; waits vmcnt(2)|vmcnt(6|0).
#define FINE2_BODY(NT_)                                                           \
  do {                                                                            \
    SAq(0, 0, 0); SAq(0, 0, 2);                                                   \
    int cur = 0;                                                                  \
    /* prologue staged below in call order */                                     \
    (void)cur;                                                                    \
  } while (0)

// ---------------- chain GEMM: 128x128, BK=64, fine 2-phase (gemmGUV schedule) ----------------
template <int MODE>
__global__ __launch_bounds__(256) void gemm128(
    const f16* __restrict__ A, const f16* __restrict__ B, int K,
    long sA, long sB, long sC,
    f16* __restrict__ Ch,
    const float* __restrict__ dvec, const float* __restrict__ evec,
    const float* __restrict__ fvec, const float* __restrict__ avec) {
  const int b = blockIdx.z;
  A += (long)b * sA;
  B += (long)b * sB;
  const int nx = blockIdx.y & 7;
  const int ny = blockIdx.x;

  GP64_COMMON();
  const int wm = wave >> 1, wn = wave & 1;

  __shared__ __align__(16) f16 As[2][8192];
  __shared__ __align__(16) f16 Bs[2][8192];

  const f16* Ab = A + (long)(ny * 128 + srow) * K + slc * 8;
  const f16* Bb = B + (long)(nx * 128 + srow) * K + slc * 8;
  const long rs = K;

  f32x4 zero = {0.f, 0.f, 0.f, 0.f};
  f32x4 acc[4][4];
#pragma unroll
  for (int mi = 0; mi < 4; ++mi)
#pragma unroll
    for (int ni = 0; ni < 4; ++ni) acc[mi][ni] = zero;

#define SAq(buf, kt, q) gl_lds16(Ab + (long)(q) * 32 * rs + (kt) * 64, &As[buf][(q) * 2048] + tid * 8)
#define SBq(buf, kt, q) gl_lds16(Bb + (long)(q) * 32 * rs + (kt) * 64, &Bs[buf][(q) * 2048] + tid * 8)

  const int nt = K >> 6;
  SBq(0, 0, 0); SBq(0, 0, 1); SBq(0, 0, 2); SBq(0, 0, 3);
  SAq(0, 0, 0); SAq(0, 0, 2); SAq(0, 0, 1); SAq(0, 0, 3);

  int cur = 0;
  for (int t = 0; t < nt; ++t) {
    const f16* asb = &As[cur][0];
    const f16* bsb = &Bs[cur][0];
    const int nb = cur ^ 1;
    const bool st = (t + 1 < nt);
    f16x8 bf[4][2], af[2][2];

    // ---- phase A: mi 0-1 ----
    asm volatile("s_waitcnt vmcnt(2)" ::: "memory");
    asm volatile("s_barrier" ::: "memory");
#pragma unroll
    for (int ni = 0; ni < 4; ++ni) {
      bf[ni][0] = *(const f16x8*)(bsb + (wn * 64 + ni * 16 + lr) * 64 + kc0);
      bf[ni][1] = *(const f16x8*)(bsb + (wn * 64 + ni * 16 + lr) * 64 + kc1);
    }
#pragma unroll
    for (int mi = 0; mi < 2; ++mi) {
      af[mi][0] = *(const f16x8*)(asb + (wm * 64 + mi * 16 + lr) * 64 + kc0);
      af[mi][1] = *(const f16x8*)(asb + (wm * 64 + mi * 16 + lr) * 64 + kc1);
    }
    if (st) { SBq(nb, t + 1, 0); SBq(nb, t + 1, 1); SBq(nb, t + 1, 2); SBq(nb, t + 1, 3);
              SAq(nb, t + 1, 0); SAq(nb, t + 1, 2); }
    asm volatile("s_waitcnt lgkmcnt(0)" ::: "memory");
    __builtin_amdgcn_s_setprio(1);
#pragma unroll
    for (int ks = 0; ks < 2; ++ks)
#pragma unroll
      for (int mi = 0; mi < 2; ++mi)
#pragma unroll
        for (int ni = 0; ni < 4; ++ni)
          acc[mi][ni] = __builtin_amdgcn_mfma_f32_16x16x32_f16(af[mi][ks], bf[ni][ks],
                                                               acc[mi][ni], 0, 0, 0);
    __builtin_amdgcn_s_setprio(0);
    asm volatile("s_barrier" ::: "memory");

    // ---- phase B: mi 2-3 ----
    if (st) asm volatile("s_waitcnt vmcnt(6)" ::: "memory");
    else    asm volatile("s_waitcnt vmcnt(0)" ::: "memory");
    asm volatile("s_barrier" ::: "memory");
#pragma unroll
    for (int mi = 0; mi < 2; ++mi) {
      af[mi][0] = *(const f16x8*)(asb + (wm * 64 + (mi + 2) * 16 + lr) * 64 + kc0);
      af[mi][1] = *(const f16x8*)(asb + (wm * 64 + (mi + 2) * 16 + lr) * 64 + kc1);
    }
    if (st) { SAq(nb, t + 1, 1); SAq(nb, t + 1, 3); }
    asm volatile("s_waitcnt lgkmcnt(0)" ::: "memory");
    __builtin_amdgcn_s_setprio(1);
#pragma unroll
    for (int ks = 0; ks < 2; ++ks)
#pragma unroll
      for (int mi = 0; mi < 2; ++mi)
#pragma unroll
        for (int ni = 0; ni < 4; ++ni)
          acc[mi + 2][ni] = __builtin_amdgcn_mfma_f32_16x16x32_f16(af[mi][ks], bf[ni][ks],
                                                                   acc[mi + 2][ni], 0, 0, 0);
    __builtin_amdgcn_s_setprio(0);
    asm volatile("s_barrier" ::: "memory");

    cur ^= 1;
  }
#undef SAq
#undef SBq

  const long cb = (long)b * sC;
  const int m0 = ny * 128 + wm * 64;
  const int n0 = nx * 128 + wn * 64;
#pragma unroll
  for (int mi = 0; mi < 4; ++mi)
#pragma unroll
    for (int ni = 0; ni < 4; ++ni)
#pragma unroll
      for (int j = 0; j < 4; ++j) {
        const int gm = m0 + mi * 16 + lk * 4 + j;
        const int gn = n0 + ni * 16 + lr;
        float val = acc[mi][ni][j];
        if constexpr (MODE == 0) {
          Ch[cb + (long)gm * 1024 + gn] = (f16)val;
        } else {
          const float dm = dvec[gm];
          const float fm = fvec[b * 1024 + gm];
          const float en = evec[b * 1024 + gn];
          const float an = avec[gn];
          val = (val + dm * en + (fm + 4096.f * dm) * an) * 0.03125f;
          Ch[cb + (long)gm * 1024 + gn] = (f16)val;
        }
      }
}

// ---------------- MERGED: G = H^T H (tri, split-K=4) + {U, PWv}; fine 2-phase pipeline ----------------
__global__ __launch_bounds__(256) void gemmGUV(const f16* __restrict__ Ht,
                                               const f16* __restrict__ WT3,
                                               const f16* __restrict__ Ph,
                                               f16* __restrict__ part,
                                               f16* __restrict__ U,
                                               f16* __restrict__ PWv) {
  GP64_COMMON();
  const int wm = wave >> 1, wn = wave & 1;

  __shared__ __align__(16) f16 As[2][8192];
  __shared__ __align__(16) f16 Bs[2][8192];

  const int bid = blockIdx.x;
  const f16 *Ab, *Bb;
  long rs;
  int tileid = 0, zz = 0, selt = 0;
  if (bid < 576) {
    zz = bid & 15;           // K-slice*4 + batch  (XCD class = zz%8)
    tileid = bid >> 4;       // 0..35 triangular tile
    const int b = zz & 3, ks4 = zz >> 2;
    int ti = 0, trem = tileid;
    while (trem >= 8 - ti) { trem -= 8 - ti; ++ti; }
    const int tj = ti + trem;
    const f16* Hb = Ht + (long)b * 4194304;
    rs = 4096;
    Ab = Hb + (long)(ti * 128 + srow) * 4096 + (long)ks4 * 1024 + slc * 8;
    Bb = Hb + (long)(tj * 128 + srow) * 4096 + (long)ks4 * 1024 + slc * 8;
  } else {
    const int u = bid - 576;
    selt = (u >> 6) + 1;                 // 1: U, 2: PWv
    const int t = u & 63;
    const int ny = t >> 3, nxx = t & 7;
    const f16* A0 = (selt == 2) ? Ph : WT3;
    const f16* B0 = (selt == 2) ? (WT3 + 2097152) : (WT3 + 1048576);
    rs = 1024;
    Ab = A0 + (long)(ny * 128 + srow) * 1024 + slc * 8;
    Bb = B0 + (long)(nxx * 128 + srow) * 1024 + slc * 8;
  }

  f32x4 zero = {0.f, 0.f, 0.f, 0.f};
  f32x4 acc[4][4];
#pragma unroll
  for (int mi = 0; mi < 4; ++mi)
#pragma unroll
    for (int ni = 0; ni < 4; ++ni) acc[mi][ni] = zero;

#define SAq(buf, kt, q) gl_lds16(Ab + (long)(q) * 32 * rs + (kt) * 64, &As[buf][(q) * 2048] + tid * 8)
#define SBq(buf, kt, q) gl_lds16(Bb + (long)(q) * 32 * rs + (kt) * 64, &Bs[buf][(q) * 2048] + tid * 8)

  const int nt = 16;
  SBq(0, 0, 0); SBq(0, 0, 1); SBq(0, 0, 2); SBq(0, 0, 3);
  SAq(0, 0, 0); SAq(0, 0, 2); SAq(0, 0, 1); SAq(0, 0, 3);

  int cur = 0;
  for (int t = 0; t < nt; ++t) {
    const f16* asb = &As[cur][0];
    const f16* bsb = &Bs[cur][0];
    const int nb = cur ^ 1;
    const bool st = (t + 1 < nt);
    f16x8 bf[4][2], af[2][2];

    // ---- phase A: mi 0-1 ----
    asm volatile("s_waitcnt vmcnt(2)" ::: "memory");
    asm volatile("s_barrier" ::: "memory");
#pragma unroll
    for (int ni = 0; ni < 4; ++ni) {
      bf[ni][0] = *(const f16x8*)(bsb + (wn * 64 + ni * 16 + lr) * 64 + kc0);
      bf[ni][1] = *(const f16x8*)(bsb + (wn * 64 + ni * 16 + lr) * 64 + kc1);
    }
#pragma unroll
    for (int mi = 0; mi < 2; ++mi) {
      af[mi][0] = *(const f16x8*)(asb + (wm * 64 + mi * 16 + lr) * 64 + kc0);
      af[mi][1] = *(const f16x8*)(asb + (wm * 64 + mi * 16 + lr) * 64 + kc1);
    }
    if (st) { SBq(nb, t + 1, 0); SBq(nb, t + 1, 1); SBq(nb, t + 1, 2); SBq(nb, t + 1, 3);
              SAq(nb, t + 1, 0); SAq(nb, t + 1, 2); }
    asm volatile("s_waitcnt lgkmcnt(0)" ::: "memory");
    __builtin_amdgcn_s_setprio(1);
#pragma unroll
    for (int ks = 0; ks < 2; ++ks)
#pragma unroll
      for (int mi = 0; mi < 2; ++mi)
#pragma unroll
        for (int ni = 0; ni < 4; ++ni)
          acc[mi][ni] = __builtin_amdgcn_mfma_f32_16x16x32_f16(af[mi][ks], bf[ni][ks],
                                                               acc[mi][ni], 0, 0, 0);
    __builtin_amdgcn_s_setprio(0);
    asm volatile("s_barrier" ::: "memory");

    // ---- phase B: mi 2-3 ----
    if (st) asm volatile("s_waitcnt vmcnt(6)" ::: "memory");
    else    asm volatile("s_waitcnt vmcnt(0)" ::: "memory");
    asm volatile("s_barrier" ::: "memory");
#pragma unroll
    for (int mi = 0; mi < 2; ++mi) {
      af[mi][0] = *(const f16x8*)(asb + (wm * 64 + (mi + 2) * 16 + lr) * 64 + kc0);
      af[mi][1] = *(const f16x8*)(asb + (wm * 64 + (mi + 2) * 16 + lr) * 64 + kc1);
    }
    if (st) { SAq(nb, t + 1, 1); SAq(nb, t + 1, 3); }
    asm volatile("s_waitcnt lgkmcnt(0)" ::: "memory");
    __builtin_amdgcn_s_setprio(1);
#pragma unroll
    for (int ks = 0; ks < 2; ++ks)
#pragma unroll
      for (int mi = 0; mi < 2; ++mi)
#pragma unroll
        for (int ni = 0; ni < 4; ++ni)
          acc[mi + 2][ni] = __builtin_amdgcn_mfma_f32_16x16x32_f16(af[mi][ks], bf[ni][ks],
                                                                   acc[mi + 2][ni], 0, 0, 0);
    __builtin_amdgcn_s_setprio(0);
    asm volatile("s_barrier" ::: "memory");

    cur ^= 1;
  }
#undef SAq
#undef SBq

  if (selt == 0) {
    f16* P = part + ((long)zz * 36 + tileid) * 16384;
#pragma unroll
    for (int mi = 0; mi < 4; ++mi)
#pragma unroll
      for (int ni = 0; ni < 4; ++ni)
#pragma unroll
        for (int j = 0; j < 4; ++j) {
          const int gm = wm * 64 + mi * 16 + lk * 4 + j;
          const int gn = wn * 64 + ni * 16 + lr;
          P[gm * 128 + gn] = (f16)acc[mi][ni][j];
        }
  } else {
    const int u = bid - 576;
    const int t = u & 63;
    const int ny = t >> 3, nxx = t & 7;
    f16* C = (selt == 2) ? PWv : U;
    const int m0 = ny * 128 + wm * 64;
    const int n0 = nxx * 128 + wn * 64;
#pragma unroll
    for (int mi = 0; mi < 4; ++mi)
#pragma unroll
      for (int ni = 0; ni < 4; ++ni)
#pragma unroll
        for (int j = 0; j < 4; ++j) {
          const int gm = m0 + mi * 16 + lk * 4 + j;
          const int gn = n0 + ni * 16 + lr;
          C[(long)gm * 1024 + gn] = (f16)acc[mi][ni][j];
        }
  }
}

// ---------------- FINAL GEMM: 256x256 tile, 8 waves, BK=64, fine 4-phase with correct sync ----------------
__global__ __launch_bounds__(512) void gemm256f(
    const f16* __restrict__ A,       // H flat [16384][1024]
    const f16* __restrict__ Bw,      // W2T [4][1024][1024]
    const float* __restrict__ resid,
    const float* __restrict__ c2v,
    float* __restrict__ outF) {
  const int lin = blockIdx.y * 4 + blockIdx.x;
  const int xcd = lin & 7, slot = lin >> 3;
  const int ny = xcd * 8 + (slot >> 2);          // 0..63  (M tile)
  const int nx = slot & 3;                       // 0..3   (N tile)
  const int bb = ny >> 4;

  GP64_COMMON();
  const int wm = wave >> 2, wn = wave & 3;       // 2 x 4 wave grid

  __shared__ __align__(16) f16 As[2][16384];
  __shared__ __align__(16) f16 Bs[2][16384];

  const f16* Ab = A + (long)ny * 262144;
  const f16* Bb = Bw + (long)bb * 1048576 + (long)nx * 262144;
  const long offs = (long)srow * 1024 + slc * 8;

  f32x4 zero = {0.f, 0.f, 0.f, 0.f};
  f32x4 acc[8][4];
#pragma unroll
  for (int mi = 0; mi < 8; ++mi)
#pragma unroll
    for (int ni = 0; ni < 4; ++ni) acc[mi][ni] = zero;

#define SA(buf, kt, q) gl_lds16(Ab + offs + (long)(q) * 65536 + (kt) * 64, &As[buf][(q) * 4096] + tid * 8)
#define SB(buf, kt, q) gl_lds16(Bb + offs + (long)(q) * 65536 + (kt) * 64, &Bs[buf][(q) * 4096] + tid * 8)

#define RD_BF(dst, bsb, kc)                                                       \
  _Pragma("unroll")                                                               \
  for (int ni = 0; ni < 4; ++ni)                                                  \
    dst[ni] = *(const f16x8*)((bsb) + (wn * 64 + ni * 16 + lr) * 64 + (kc));
#define RD_AF(dst, asb, mh, kc)                                                   \
  _Pragma("unroll")                                                               \
  for (int mi = 0; mi < 4; ++mi)                                                  \
    dst[mi] = *(const f16x8*)((asb) + (wm * 128 + (mh) * 64 + mi * 16 + lr) * 64 + (kc));
#define MF16(af_, bf_, mo)                                                        \
  __builtin_amdgcn_s_setprio(1);                                                  \
  _Pragma("unroll")                                                               \
  for (int mi = 0; mi < 4; ++mi)                                                  \
    _Pragma("unroll")                                                             \
    for (int ni = 0; ni < 4; ++ni)                                                \
      acc[(mo) + mi][ni] = __builtin_amdgcn_mfma_f32_16x16x32_f16(af_[mi], bf_[ni], \
                                                                  acc[(mo) + mi][ni], 0, 0, 0); \
  __builtin_amdgcn_s_setprio(0);

  const int nt = 16;
  // prologue: stage tile 0 in consumption order
  SB(0, 0, 0); SB(0, 0, 1); SB(0, 0, 2); SB(0, 0, 3);
  SA(0, 0, 0); SA(0, 0, 2); SA(0, 0, 1); SA(0, 0, 3);

  int cur = 0;
  for (int t = 0; t < nt; ++t) {
    const f16* asb = &As[cur][0];
    const f16* bsb = &Bs[cur][0];
    const int nb = cur ^ 1;
    const bool st = (t + 1 < nt);
    f16x8 bf[4], af[4];

    // ---- P0: (mh0, ks0) ----
    asm volatile("s_waitcnt vmcnt(2)" ::: "memory");   // 6 oldest of tile t landed (per wave)
    asm volatile("s_barrier" ::: "memory");            // ...for ALL waves -> B0-3,A0,A2 readable
    RD_BF(bf, bsb, kc0);
    RD_AF(af, asb, 0, kc0);
    if (st) { SB(nb, t + 1, 0); SB(nb, t + 1, 1); }
    asm volatile("s_waitcnt lgkmcnt(0)" ::: "memory");
    MF16(af, bf, 0);
    asm volatile("s_barrier" ::: "memory");

    // ---- P1: (mh1, ks0) ----
    if (st) asm volatile("s_waitcnt vmcnt(2)" ::: "memory");  // A1,A3 of tile t landed
    else    asm volatile("s_waitcnt vmcnt(0)" ::: "memory");  // last iter: only A1,A3 outstanding
    asm volatile("s_barrier" ::: "memory");
    RD_AF(af, asb, 1, kc0);
    if (st) { SB(nb, t + 1, 2); SB(nb, t + 1, 3); }
    asm volatile("s_waitcnt lgkmcnt(0)" ::: "memory");
    MF16(af, bf, 4);
    asm volatile("s_barrier" ::: "memory");

    // ---- P2: (mh0, ks1) — quadrants already verified ----
    RD_BF(bf, bsb, kc1);
    RD_AF(af, asb, 0, kc1);
    if (st) { SA(nb, t + 1, 0); SA(nb, t + 1, 2); }
    asm volatile("s_waitcnt lgkmcnt(0)" ::: "memory");
    MF16(af, bf, 0);
    asm volatile("s_barrier" ::: "memory");

    // ---- P3: (mh1, ks1) ----
    RD_AF(af, asb, 1, kc1);
    if (st) { SA(nb, t + 1, 1); SA(nb, t + 1, 3); }
    asm volatile("s_waitcnt lgkmcnt(0)" ::: "memory");
    MF16(af, bf, 4);
    asm volatile("s_barrier" ::: "memory");

    cur ^= 1;
  }
#undef SA
#undef SB
#undef RD_BF
#undef RD_AF
#undef MF16

  // drain any residual DMA before reusing LDS
  asm volatile("s_waitcnt vmcnt(0)" ::: "memory");
  asm volatile("s_barrier" ::: "memory");

  // -------- LDS-staged vectorized epilogue (reuses As) --------
  float* weps = ((float*)&As[0][0]) + wave * 1088;
  const int m0 = ny * 256 + wm * 128;
  const int n0 = nx * 256 + wn * 64;
  const int err = lane >> 3;
  const int ecc = (lane & 7) * 4;
  float4 cc2[2];
#pragma unroll
  for (int q = 0; q < 2; ++q)
    cc2[q] = *(const float4*)&c2v[bb * 1024 + n0 + ecc + 32 * q];

#pragma unroll
  for (int mi = 0; mi < 8; ++mi) {
#pragma unroll
    for (int ni = 0; ni < 4; ++ni)
#pragma unroll
      for (int j = 0; j < 4; ++j)
        weps[(lk * 4 + j) * 68 + ni * 16 + lr] = acc[mi][ni][j];
    asm volatile("s_waitcnt lgkmcnt(0)" ::: "memory");
#pragma unroll
    for (int h = 0; h < 2; ++h)
#pragma unroll
      for (int q = 0; q < 2; ++q) {
        const int rr = err + 8 * h;
        const int cc = ecc + 32 * q;
        float4 o = *(const float4*)&weps[rr * 68 + cc];
        const long gbase = (long)(m0 + mi * 16 + rr) * 1024 + n0 + cc;
        const float4 rv = *(const float4*)&resid[gbase];
        float4 ov;
        ov.x = o.x + rv.x + cc2[q].x;
        ov.y = o.y + rv.y + cc2[q].y;
        ov.z = o.z + rv.z + cc2[q].z;
        ov.w = o.w + rv.w + cc2[q].w;
        *(float4*)&outF[gbase] = ov;
      }
  }
}

// ---------------- reduce triangular G partials -> Gh, mirror ----------------
__global__ __launch_bounds__(256) void treduce(const f16* __restrict__ part,
                                               f16* __restrict__ Gh) {
  const int tileid = blockIdx.x, b = blockIdx.y;
  int ti = 0, trem = tileid;
  while (trem >= 8 - ti) { trem -= 8 - ti; ++ti; }
  const int tj = ti + trem;
  __shared__ f16 tl[128][132];
  const int tid = threadIdx.x;
  f16* Gb = Gh + (long)b * 1048576;
#pragma unroll
  for (int it = 0; it < 16; ++it) {
    const int e = it * 1024 + tid * 4;
    const int r = e >> 7, c = e & 127;
    f16x4 p0 = *(const f16x4*)(part + ((long)(0 * 4 + b) * 36 + tileid) * 16384 + e);
    f16x4 p1 = *(const f16x4*)(part + ((long)(1 * 4 + b) * 36 + tileid) * 16384 + e);
    f16x4 p2 = *(const f16x4*)(part + ((long)(2 * 4 + b) * 36 + tileid) * 16384 + e);
    f16x4 p3 = *(const f16x4*)(part + ((long)(3 * 4 + b) * 36 + tileid) * 16384 + e);
    f16x4 sv;
#pragma unroll
    for (int j = 0; j < 4; ++j)
      sv[j] = (f16)((float)p0[j] + (float)p1[j] + (float)p2[j] + (float)p3[j]);
    *(f16x4*)(Gb + (long)(ti * 128 + r) * 1024 + tj * 128 + c) = sv;
    *(f16x4*)&tl[r][c] = sv;
  }
  if (ti != tj) {
    __syncthreads();
#pragma unroll
    for (int it = 0; it < 16; ++it) {
      const int e = it * 1024 + tid * 4;
      const int r = e >> 7, c = e & 127;
      f16x4 v;
      v[0] = tl[c + 0][r];
      v[1] = tl[c + 1][r];
      v[2] = tl[c + 2][r];
      v[3] = tl[c + 3][r];
      *(f16x4*)(Gb + (long)(tj * 128 + r) * 1024 + ti * 128 + c) = v;
    }
  }
}

extern "C" void kernel_launch(void* const* d_in, const int* in_sizes, int n_in,
                              void* d_out, int out_size, void* d_ws, size_t ws_size,
                              hipStream_t stream) {
  const float* x      = (const float*)d_in[0];
  const float* norm_w = (const float*)d_in[1];
  const float* norm_b = (const float*)d_in[2];
  const float* qkv_w  = (const float*)d_in[3];
  const float* qkv_b  = (const float*)d_in[4];
  const float* proj_w = (const float*)d_in[5];
  const float* proj_b = (const float*)d_in[6];
  float* out = (float*)d_out;
  char* ws = (char*)d_ws;

  const size_t OFF_H    = 0;
  const size_t OFF_HT   = 33554432;
  const size_t OFF_T1   = 33554432;   // alias (Ht dead after gemmGUV)
  const size_t OFF_T2   = 41943040;
  const size_t OFF_WH   = 67108864;
  const size_t OFF_PH   = 73400320;
  const size_t OFF_WT3  = 75497472;
  const size_t OFF_U    = 81788928;
  const size_t OFF_PWV  = 83886080;
  const size_t OFF_GH   = 85983232;
  const size_t OFF_PART = 94371840;
  const size_t OFF_HS   = 115343360;
  const size_t OFF_AYD  = 115392512;
  const size_t OFF_SCAL = 115404800;
  const size_t OFF_EFZ  = 115405824;
  const size_t OFF_C2   = 115471360;

  f16* H    = (f16*)(ws + OFF_H);
  f16* Ht   = (f16*)(ws + OFF_HT);
  f16* T1   = (f16*)(ws + OFF_T1);
  f16* T2   = (f16*)(ws + OFF_T2);
  f16* Wh   = (f16*)(ws + OFF_WH);
  f16* Ph   = (f16*)(ws + OFF_PH);
  f16* WT3  = (f16*)(ws + OFF_WT3);
  f16* U    = (f16*)(ws + OFF_U);
  f16* PWv  = (f16*)(ws + OFF_PWV);
  f16* Gh   = (f16*)(ws + OFF_GH);
  f16* part = (f16*)(ws + OFF_PART);
  float* hs   = (float*)(ws + OFF_HS);
  float* ayd  = (float*)(ws + OFF_AYD);
  float* scal = (float*)(ws + OFF_SCAL);
  float* efz  = (float*)(ws + OFF_EFZ);
  float* c2v  = (float*)(ws + OFF_C2);

  // weight prep (one pass over qkv_w; straight casts fused)
  transcast4<<<dim3(16, 16, 4), 256, 0, stream>>>(qkv_w, proj_w, WT3, Wh, Ph);
  gemv3a<<<dim3(3073), 64, 0, stream>>>(WT3, Ph, qkv_b, ayd, scal);

  // input path
  ln_kernel<<<dim3(4096), 256, 0, stream>>>(x, norm_w, norm_b, H);
  hipMemsetAsync(ws + OFF_HS, 0, 16384, stream);
  transpose_cs_kernel<<<dim3(16, 64, 4), 256, 0, stream>>>(H, Ht, hs);

  // merged: G tri-tiles (576 blocks, XCD-clustered by K-slice) + U/PWv (128 blocks)
  gemmGUV<<<dim3(704), 256, 0, stream>>>(Ht, WT3, Ph, part, U, PWv);
  treduce<<<dim3(36, 4), 256, 0, stream>>>(part, Gh);

  // gemv cluster: e, f, z, s_u  then c2 directly
  gemv3b<<<dim3(12292), 64, 0, stream>>>(U, PWv, Gh, hs, ayd, efz, scal);
  gemvC2n<<<dim3(4096), 64, 0, stream>>>(PWv, efz, ayd, scal, proj_b, c2v);

  // T1_b = U (x) G_b
  gemm128<0><<<dim3(8, 8, 4), 256, 0, stream>>>(U, Gh, 1024, 0L, 1048576L, 1048576L,
      T1, nullptr, nullptr, nullptr, nullptr);
  // W2T_b = (PWv (x) T1_b + d e^T + (f + 4096 d) a^T) / 32
  gemm128<1><<<dim3(8, 8, 4), 256, 0, stream>>>(PWv, T1, 1024, 0L, 1048576L, 1048576L,
      T2, ayd + 2048, efz, efz + 4096, ayd);

  // out = X + H (x) W2T + c2
  gemm256f<<<dim3(4, 64), 512, 0, stream>>>(H, T2, x, c2v, out);
}

// Round 19
// 184.815 us; speedup vs baseline: 1.1018x; 1.0042x over previous
//
#include <hip/hip_runtime.h>

typedef _Float16 f16;
typedef _Float16 f16x4 __attribute__((ext_vector_type(4)));
typedef _Float16 f16x8 __attribute__((ext_vector_type(8)));
typedef float f32x4 __attribute__((ext_vector_type(4)));

#define AS1 __attribute__((address_space(1)))
#define AS3 __attribute__((address_space(3)))

__device__ __forceinline__ void gl_lds16(const f16* g, f16* l) {
  __builtin_amdgcn_global_load_lds((const AS1 void*)g, (AS3 void*)l, 16, 0, 0);
}

// ---------------- LayerNorm: x (fp32) -> H (f16), one WAVE per row; block 0 zeroes hs ----------------
__global__ __launch_bounds__(256) void ln_kernel(const float* __restrict__ x,
                                                 const float* __restrict__ gw,
                                                 const float* __restrict__ gb,
                                                 f16* __restrict__ H,
                                                 float* __restrict__ hs) {
  if (blockIdx.x == 0) {
    // zero hs (4 x 1024 fp32) -- completes before transpose_cs dispatch (stream order)
#pragma unroll
    for (int j = 0; j < 4; ++j)
      ((float4*)hs)[threadIdx.x + 256 * j] = make_float4(0.f, 0.f, 0.f, 0.f);
  }
  const int wv = threadIdx.x >> 6, lane = threadIdx.x & 63;
  const long row = (long)blockIdx.x * 4 + wv;
  const float* xr = x + row * 1024;
  float4 v[4];
  float s = 0.f, s2 = 0.f;
#pragma unroll
  for (int j = 0; j < 4; ++j) {
    v[j] = ((const float4*)xr)[lane + 64 * j];
    s  += v[j].x + v[j].y + v[j].z + v[j].w;
    s2 += v[j].x * v[j].x + v[j].y * v[j].y + v[j].z * v[j].z + v[j].w * v[j].w;
  }
#pragma unroll
  for (int off = 32; off > 0; off >>= 1) {
    s  += __shfl_xor(s, off);
    s2 += __shfl_xor(s2, off);
  }
  const float mu = s * (1.0f / 1024.0f);
  const float rstd = rsqrtf(s2 * (1.0f / 1024.0f) - mu * mu + 1e-5f);
#pragma unroll
  for (int j = 0; j < 4; ++j) {
    const float4 w4 = ((const float4*)gw)[lane + 64 * j];
    const float4 b4 = ((const float4*)gb)[lane + 64 * j];
    f16x4 h;
    h[0] = (f16)((v[j].x - mu) * rstd * w4.x + b4.x);
    h[1] = (f16)((v[j].y - mu) * rstd * w4.y + b4.y);
    h[2] = (f16)((v[j].z - mu) * rstd * w4.z + b4.z);
    h[3] = (f16)((v[j].w - mu) * rstd * w4.w + b4.w);
    *(f16x4*)(H + row * 1024 + (lane + 64 * j) * 4) = h;
  }
}

// ---------------- transpose H -> Ht, fused colsum ----------------
__global__ __launch_bounds__(256) void transpose_cs_kernel(const f16* __restrict__ H,
                                                           f16* __restrict__ Ht,
                                                           float* __restrict__ hs) {
  __shared__ f16 tile[64][68];
  __shared__ float csum[4][64];
  const int b = blockIdx.z;
  const long Hb  = (long)b * 4096 * 1024;
  const long Htb = (long)b * 1024 * 4096;
  const int t0 = blockIdx.y * 64, c0 = blockIdx.x * 64;
  const int tid = threadIdx.x;
  const int r = tid >> 2, g0 = tid & 3;
#pragma unroll
  for (int i = 0; i < 4; ++i) {
    const int g = g0 + i * 4;
    f16x4 v = *(const f16x4*)(H + Hb + (long)(t0 + r) * 1024 + c0 + g * 4);
    *(f16x4*)&tile[r][g * 4] = v;
  }
  __syncthreads();
  {
    const int cl = tid & 63, rg = tid >> 6;
    float s = 0.f;
#pragma unroll
    for (int rr = 0; rr < 16; ++rr) s += (float)tile[rg * 16 + rr][cl];
    csum[rg][cl] = s;
  }
#pragma unroll
  for (int i = 0; i < 4; ++i) {
    const int g = g0 + i * 4;
    f16x4 v;
    v[0] = tile[g * 4 + 0][r];
    v[1] = tile[g * 4 + 1][r];
    v[2] = tile[g * 4 + 2][r];
    v[3] = tile[g * 4 + 3][r];
    *(f16x4*)(Ht + Htb + (long)(c0 + r) * 4096 + t0 + g * 4) = v;
  }
  __syncthreads();
  if (tid < 64)
    atomicAdd(&hs[b * 1024 + c0 + tid],
              csum[0][tid] + csum[1][tid] + csum[2][tid] + csum[3][tid]);
}

// ---------------- transcast4: z=0..2 transpose qkv (z>=1 also straight cast), z=3 cast proj ----------------
__global__ __launch_bounds__(256) void transcast4(const float* __restrict__ qkv_w,
                                                  const float* __restrict__ proj_w,
                                                  f16* __restrict__ WT3,
                                                  f16* __restrict__ Wh,
                                                  f16* __restrict__ Ph) {
  const int z = blockIdx.z;
  __shared__ f16 tile[64][68];
  const int r0 = blockIdx.y * 64, c0 = blockIdx.x * 64;
  const int tid = threadIdx.x;
  const int r = tid >> 2, g0 = tid & 3;
  if (z == 3) {
#pragma unroll
    for (int i = 0; i < 4; ++i) {
      const int g = g0 + i * 4;
      float4 v = *(const float4*)(proj_w + (long)(r0 + r) * 1024 + c0 + g * 4);
      f16x4 h; h[0]=(f16)v.x; h[1]=(f16)v.y; h[2]=(f16)v.z; h[3]=(f16)v.w;
      *(f16x4*)(Ph + (long)(r0 + r) * 1024 + c0 + g * 4) = h;
    }
    return;
  }
  const float* W = qkv_w + (long)z * 1048576;
  f16* WT = WT3 + (long)z * 1048576;
#pragma unroll
  for (int i = 0; i < 4; ++i) {
    const int g = g0 + i * 4;
    float4 v = *(const float4*)(W + (long)(r0 + r) * 1024 + c0 + g * 4);
    f16x4 h; h[0]=(f16)v.x; h[1]=(f16)v.y; h[2]=(f16)v.z; h[3]=(f16)v.w;
    *(f16x4*)&tile[r][g * 4] = h;
    if (z >= 1)
      *(f16x4*)(Wh + (long)z * 1048576 + (long)(r0 + r) * 1024 + c0 + g * 4) = h;
  }
  __syncthreads();
#pragma unroll
  for (int i = 0; i < 4; ++i) {
    const int g = g0 + i * 4;
    f16x4 v;
    v[0] = tile[g * 4 + 0][r];
    v[1] = tile[g * 4 + 1][r];
    v[2] = tile[g * 4 + 2][r];
    v[3] = tile[g * 4 + 3][r];
    *(f16x4*)(WT + (long)(c0 + r) * 1024 + r0 + g * 4) = v;
  }
}

// ---------------- f16row . f32vec, 1024 elems, one 64-lane wave ----------------
__device__ __forceinline__ float dot1024(const f16* __restrict__ row,
                                         const float* __restrict__ v) {
  const int lane = threadIdx.x & 63;
  float s = 0.f;
#pragma unroll
  for (int j = 0; j < 2; ++j) {
    const int d = (lane + 64 * j) * 8;
    f16x8 a = *(const f16x8*)(row + d);
    float4 h0 = *(const float4*)(v + d);
    float4 h1 = *(const float4*)(v + d + 4);
    s += (float)a[0] * h0.x + (float)a[1] * h0.y + (float)a[2] * h0.z + (float)a[3] * h0.w
       + (float)a[4] * h1.x + (float)a[5] * h1.y + (float)a[6] * h1.z + (float)a[7] * h1.w;
  }
#pragma unroll
  for (int off = 32; off > 0; off >>= 1) s += __shfl_down(s, off);
  return s;
}

__device__ __forceinline__ float dotf1024(const float* __restrict__ a,
                                          const float* __restrict__ v) {
  const int lane = threadIdx.x & 63;
  float s = 0.f;
#pragma unroll
  for (int j = 0; j < 4; ++j) {
    const int d = (lane + 64 * j) * 4;
    float4 x = *(const float4*)(a + d);
    float4 q = *(const float4*)(v + d);
    s += x.x * q.x + x.y * q.y + x.z * q.z + x.w * q.w;
  }
#pragma unroll
  for (int off = 32; off > 0; off >>= 1) s += __shfl_down(s, off);
  return s;
}

// ---------------- gemv3a: a = WqT.bk, y = WkT.bq, d = Ph.bv, scal[4] = bk.bq ----------------
__global__ void gemv3a(const f16* __restrict__ WT3, const f16* __restrict__ Ph,
                       const float* __restrict__ qkv_b, float* __restrict__ ayd,
                       float* __restrict__ scal) {
  if (blockIdx.x == 3072) {
    float s = dotf1024(qkv_b + 1024, qkv_b);
    if ((threadIdx.x & 63) == 0) scal[4] = s;
    return;
  }
  const int which = blockIdx.x >> 10, m = blockIdx.x & 1023;
  const f16* row;
  const float* v;
  if (which == 0)      { row = WT3 + (long)m * 1024;            v = qkv_b + 1024; } // a
  else if (which == 1) { row = WT3 + 1048576 + (long)m * 1024;  v = qkv_b; }        // y
  else                 { row = Ph + (long)m * 1024;             v = qkv_b + 2048; } // d
  float s = dot1024(row, v);
  if ((threadIdx.x & 63) == 0) ayd[which * 1024 + m] = s;
}

// ---------------- gemv3b: e = U.hs, f = PWv.hs, z = G.y; blocks >= 12288: scal[b] = hs_b.y ----------------
__global__ void gemv3b(const f16* __restrict__ U, const f16* __restrict__ PWv,
                       const f16* __restrict__ Gh, const float* __restrict__ hs,
                       const float* __restrict__ ayd, float* __restrict__ efz,
                       float* __restrict__ scal) {
  if (blockIdx.x >= 12288) {
    const int b = blockIdx.x - 12288;
    float s = dotf1024(hs + b * 1024, ayd + 1024);
    if ((threadIdx.x & 63) == 0) scal[b] = s;
    return;
  }
  const int sel = blockIdx.x >> 12, r = blockIdx.x & 4095;
  const int b = r >> 10, m = r & 1023;
  const f16* row;
  const float* v;
  if (sel == 0)      { row = U + (long)m * 1024;                       v = hs + b * 1024; }
  else if (sel == 1) { row = PWv + (long)m * 1024;                     v = hs + b * 1024; }
  else               { row = Gh + (long)b * 1048576 + (long)m * 1024;  v = ayd + 1024; }
  float s = dot1024(row, v);
  if ((threadIdx.x & 63) == 0) efz[sel * 4096 + r] = s;
}

// ---------------- c2_b[c] = (PWv_row_c . z_b + d_c*s_u_b + s_b*(f_b_c + 4096 d_c))/32 + proj_b[c] ----------------
__global__ void gemvC2n(const f16* __restrict__ PWv, const float* __restrict__ efz,
                        const float* __restrict__ ayd, const float* __restrict__ scal,
                        const float* __restrict__ proj_b, float* __restrict__ c2) {
  const int b = blockIdx.x >> 10, c = blockIdx.x & 1023;
  float s = dot1024(PWv + (long)c * 1024, efz + 8192 + b * 1024);
  if ((threadIdx.x & 63) == 0) {
    const float d = ayd[2048 + c];
    c2[b * 1024 + c] = (s + d * scal[b] + scal[4] * (efz[4096 + b * 1024 + c] + 4096.f * d))
                         * 0.03125f + proj_b[c];
  }
}

// ================= shared GEMM machinery (BK = 64) =================
#define GP64_COMMON()                                        \
  const int tid = threadIdx.x;                               \
  const int wave = tid >> 6, lane = tid & 63;                \
  const int lr = lane & 15, lk = lane >> 4;                  \
  const int srow = tid >> 3;                                 \
  const int slc  = (tid & 7) ^ (srow & 7);                   \
  const int kc0 = ((lk) ^ (lr & 7)) * 8;                     \
  const int kc1 = ((4 + lk) ^ (lr & 7)) * 8;

// ---------------- chain GEMM: 128x128, BK=64, fine 2-phase (proven schedule) ----------------
template <int MODE>
__global__ __launch_bounds__(256) void gemm128(
    const f16* __restrict__ A, const f16* __restrict__ B, int K,
    long sA, long sB, long sC,
    f16* __restrict__ Ch,
    const float* __restrict__ dvec, const float* __restrict__ evec,
    const float* __restrict__ fvec, const float* __restrict__ avec) {
  const int b = blockIdx.z;
  A += (long)b * sA;
  B += (long)b * sB;
  const int nx = blockIdx.y & 7;
  const int ny = blockIdx.x;

  GP64_COMMON();
  const int wm = wave >> 1, wn = wave & 1;

  __shared__ __align__(16) f16 As[2][8192];
  __shared__ __align__(16) f16 Bs[2][8192];

  const f16* Ab = A + (long)(ny * 128 + srow) * K + slc * 8;
  const f16* Bb = B + (long)(nx * 128 + srow) * K + slc * 8;
  const long rs = K;

  f32x4 zero = {0.f, 0.f, 0.f, 0.f};
  f32x4 acc[4][4];
#pragma unroll
  for (int mi = 0; mi < 4; ++mi)
#pragma unroll
    for (int ni = 0; ni < 4; ++ni) acc[mi][ni] = zero;

#define SAq(buf, kt, q) gl_lds16(Ab + (long)(q) * 32 * rs + (kt) * 64, &As[buf][(q) * 2048] + tid * 8)
#define SBq(buf, kt, q) gl_lds16(Bb + (long)(q) * 32 * rs + (kt) * 64, &Bs[buf][(q) * 2048] + tid * 8)

  const int nt = K >> 6;
  SBq(0, 0, 0); SBq(0, 0, 1); SBq(0, 0, 2); SBq(0, 0, 3);
  SAq(0, 0, 0); SAq(0, 0, 2); SAq(0, 0, 1); SAq(0, 0, 3);

  int cur = 0;
  for (int t = 0; t < nt; ++t) {
    const f16* asb = &As[cur][0];
    const f16* bsb = &Bs[cur][0];
    const int nb = cur ^ 1;
    const bool st = (t + 1 < nt);
    f16x8 bf[4][2], af[2][2];

    // ---- phase A: mi 0-1 ----
    asm volatile("s_waitcnt vmcnt(2)" ::: "memory");
    asm volatile("s_barrier" ::: "memory");
#pragma unroll
    for (int ni = 0; ni < 4; ++ni) {
      bf[ni][0] = *(const f16x8*)(bsb + (wn * 64 + ni * 16 + lr) * 64 + kc0);
      bf[ni][1] = *(const f16x8*)(bsb + (wn * 64 + ni * 16 + lr) * 64 + kc1);
    }
#pragma unroll
    for (int mi = 0; mi < 2; ++mi) {
      af[mi][0] = *(const f16x8*)(asb + (wm * 64 + mi * 16 + lr) * 64 + kc0);
      af[mi][1] = *(const f16x8*)(asb + (wm * 64 + mi * 16 + lr) * 64 + kc1);
    }
    if (st) { SBq(nb, t + 1, 0); SBq(nb, t + 1, 1); SBq(nb, t + 1, 2); SBq(nb, t + 1, 3);
              SAq(nb, t + 1, 0); SAq(nb, t + 1, 2); }
    asm volatile("s_waitcnt lgkmcnt(0)" ::: "memory");
    __builtin_amdgcn_s_setprio(1);
#pragma unroll
    for (int ks = 0; ks < 2; ++ks)
#pragma unroll
      for (int mi = 0; mi < 2; ++mi)
#pragma unroll
        for (int ni = 0; ni < 4; ++ni)
          acc[mi][ni] = __builtin_amdgcn_mfma_f32_16x16x32_f16(af[mi][ks], bf[ni][ks],
                                                               acc[mi][ni], 0, 0, 0);
    __builtin_amdgcn_s_setprio(0);
    asm volatile("s_barrier" ::: "memory");

    // ---- phase B: mi 2-3 ----
    if (st) asm volatile("s_waitcnt vmcnt(6)" ::: "memory");
    else    asm volatile("s_waitcnt vmcnt(0)" ::: "memory");
    asm volatile("s_barrier" ::: "memory");
#pragma unroll
    for (int mi = 0; mi < 2; ++mi) {
      af[mi][0] = *(const f16x8*)(asb + (wm * 64 + (mi + 2) * 16 + lr) * 64 + kc0);
      af[mi][1] = *(const f16x8*)(asb + (wm * 64 + (mi + 2) * 16 + lr) * 64 + kc1);
    }
    if (st) { SAq(nb, t + 1, 1); SAq(nb, t + 1, 3); }
    asm volatile("s_waitcnt lgkmcnt(0)" ::: "memory");
    __builtin_amdgcn_s_setprio(1);
#pragma unroll
    for (int ks = 0; ks < 2; ++ks)
#pragma unroll
      for (int mi = 0; mi < 2; ++mi)
#pragma unroll
        for (int ni = 0; ni < 4; ++ni)
          acc[mi + 2][ni] = __builtin_amdgcn_mfma_f32_16x16x32_f16(af[mi][ks], bf[ni][ks],
                                                                   acc[mi + 2][ni], 0, 0, 0);
    __builtin_amdgcn_s_setprio(0);
    asm volatile("s_barrier" ::: "memory");

    cur ^= 1;
  }
#undef SAq
#undef SBq

  const long cb = (long)b * sC;
  const int m0 = ny * 128 + wm * 64;
  const int n0 = nx * 128 + wn * 64;
#pragma unroll
  for (int mi = 0; mi < 4; ++mi)
#pragma unroll
    for (int ni = 0; ni < 4; ++ni)
#pragma unroll
      for (int j = 0; j < 4; ++j) {
        const int gm = m0 + mi * 16 + lk * 4 + j;
        const int gn = n0 + ni * 16 + lr;
        float val = acc[mi][ni][j];
        if constexpr (MODE == 0) {
          Ch[cb + (long)gm * 1024 + gn] = (f16)val;
        } else {
          const float dm = dvec[gm];
          const float fm = fvec[b * 1024 + gm];
          const float en = evec[b * 1024 + gn];
          const float an = avec[gn];
          val = (val + dm * en + (fm + 4096.f * dm) * an) * 0.03125f;
          Ch[cb + (long)gm * 1024 + gn] = (f16)val;
        }
      }
}

// ---------------- MERGED: G = H^T H (tri, split-K=4) + {U, PWv}; fine 2-phase pipeline ----------------
__global__ __launch_bounds__(256) void gemmGUV(const f16* __restrict__ Ht,
                                               const f16* __restrict__ WT3,
                                               const f16* __restrict__ Ph,
                                               f16* __restrict__ part,
                                               f16* __restrict__ U,
                                               f16* __restrict__ PWv) {
  GP64_COMMON();
  const int wm = wave >> 1, wn = wave & 1;

  __shared__ __align__(16) f16 As[2][8192];
  __shared__ __align__(16) f16 Bs[2][8192];

  const int bid = blockIdx.x;
  const f16 *Ab, *Bb;
  long rs;
  int tileid = 0, zz = 0, selt = 0;
  if (bid < 576) {
    zz = bid & 15;           // K-slice*4 + batch  (XCD class = zz%8)
    tileid = bid >> 4;       // 0..35 triangular tile
    const int b = zz & 3, ks4 = zz >> 2;
    int ti = 0, trem = tileid;
    while (trem >= 8 - ti) { trem -= 8 - ti; ++ti; }
    const int tj = ti + trem;
    const f16* Hb = Ht + (long)b * 4194304;
    rs = 4096;
    Ab = Hb + (long)(ti * 128 + srow) * 4096 + (long)ks4 * 1024 + slc * 8;
    Bb = Hb + (long)(tj * 128 + srow) * 4096 + (long)ks4 * 1024 + slc * 8;
  } else {
    const int u = bid - 576;
    selt = (u >> 6) + 1;                 // 1: U, 2: PWv
    const int t = u & 63;
    const int ny = t >> 3, nxx = t & 7;
    const f16* A0 = (selt == 2) ? Ph : WT3;
    const f16* B0 = (selt == 2) ? (WT3 + 2097152) : (WT3 + 1048576);
    rs = 1024;
    Ab = A0 + (long)(ny * 128 + srow) * 1024 + slc * 8;
    Bb = B0 + (long)(nxx * 128 + srow) * 1024 + slc * 8;
  }

  f32x4 zero = {0.f, 0.f, 0.f, 0.f};
  f32x4 acc[4][4];
#pragma unroll
  for (int mi = 0; mi < 4; ++mi)
#pragma unroll
    for (int ni = 0; ni < 4; ++ni) acc[mi][ni] = zero;

#define SAq(buf, kt, q) gl_lds16(Ab + (long)(q) * 32 * rs + (kt) * 64, &As[buf][(q) * 2048] + tid * 8)
#define SBq(buf, kt, q) gl_lds16(Bb + (long)(q) * 32 * rs + (kt) * 64, &Bs[buf][(q) * 2048] + tid * 8)

  const int nt = 16;
  SBq(0, 0, 0); SBq(0, 0, 1); SBq(0, 0, 2); SBq(0, 0, 3);
  SAq(0, 0, 0); SAq(0, 0, 2); SAq(0, 0, 1); SAq(0, 0, 3);

  int cur = 0;
  for (int t = 0; t < nt; ++t) {
    const f16* asb = &As[cur][0];
    const f16* bsb = &Bs[cur][0];
    const int nb = cur ^ 1;
    const bool st = (t + 1 < nt);
    f16x8 bf[4][2], af[2][2];

    // ---- phase A: mi 0-1 ----
    asm volatile("s_waitcnt vmcnt(2)" ::: "memory");
    asm volatile("s_barrier" ::: "memory");
#pragma unroll
    for (int ni = 0; ni < 4; ++ni) {
      bf[ni][0] = *(const f16x8*)(bsb + (wn * 64 + ni * 16 + lr) * 64 + kc0);
      bf[ni][1] = *(const f16x8*)(bsb + (wn * 64 + ni * 16 + lr) * 64 + kc1);
    }
#pragma unroll
    for (int mi = 0; mi < 2; ++mi) {
      af[mi][0] = *(const f16x8*)(asb + (wm * 64 + mi * 16 + lr) * 64 + kc0);
      af[mi][1] = *(const f16x8*)(asb + (wm * 64 + mi * 16 + lr) * 64 + kc1);
    }
    if (st) { SBq(nb, t + 1, 0); SBq(nb, t + 1, 1); SBq(nb, t + 1, 2); SBq(nb, t + 1, 3);
              SAq(nb, t + 1, 0); SAq(nb, t + 1, 2); }
    asm volatile("s_waitcnt lgkmcnt(0)" ::: "memory");
    __builtin_amdgcn_s_setprio(1);
#pragma unroll
    for (int ks = 0; ks < 2; ++ks)
#pragma unroll
      for (int mi = 0; mi < 2; ++mi)
#pragma unroll
        for (int ni = 0; ni < 4; ++ni)
          acc[mi][ni] = __builtin_amdgcn_mfma_f32_16x16x32_f16(af[mi][ks], bf[ni][ks],
                                                               acc[mi][ni], 0, 0, 0);
    __builtin_amdgcn_s_setprio(0);
    asm volatile("s_barrier" ::: "memory");

    // ---- phase B: mi 2-3 ----
    if (st) asm volatile("s_waitcnt vmcnt(6)" ::: "memory");
    else    asm volatile("s_waitcnt vmcnt(0)" ::: "memory");
    asm volatile("s_barrier" ::: "memory");
#pragma unroll
    for (int mi = 0; mi < 2; ++mi) {
      af[mi][0] = *(const f16x8*)(asb + (wm * 64 + (mi + 2) * 16 + lr) * 64 + kc0);
      af[mi][1] = *(const f16x8*)(asb + (wm * 64 + (mi + 2) * 16 + lr) * 64 + kc1);
    }
    if (st) { SAq(nb, t + 1, 1); SAq(nb, t + 1, 3); }
    asm volatile("s_waitcnt lgkmcnt(0)" ::: "memory");
    __builtin_amdgcn_s_setprio(1);
#pragma unroll
    for (int ks = 0; ks < 2; ++ks)
#pragma unroll
      for (int mi = 0; mi < 2; ++mi)
#pragma unroll
        for (int ni = 0; ni < 4; ++ni)
          acc[mi + 2][ni] = __builtin_amdgcn_mfma_f32_16x16x32_f16(af[mi][ks], bf[ni][ks],
                                                                   acc[mi + 2][ni], 0, 0, 0);
    __builtin_amdgcn_s_setprio(0);
    asm volatile("s_barrier" ::: "memory");

    cur ^= 1;
  }
#undef SAq
#undef SBq

  if (selt == 0) {
    f16* P = part + ((long)zz * 36 + tileid) * 16384;
#pragma unroll
    for (int mi = 0; mi < 4; ++mi)
#pragma unroll
      for (int ni = 0; ni < 4; ++ni)
#pragma unroll
        for (int j = 0; j < 4; ++j) {
          const int gm = wm * 64 + mi * 16 + lk * 4 + j;
          const int gn = wn * 64 + ni * 16 + lr;
          P[gm * 128 + gn] = (f16)acc[mi][ni][j];
        }
  } else {
    const int u = bid - 576;
    const int t = u & 63;
    const int ny = t >> 3, nxx = t & 7;
    f16* C = (selt == 2) ? PWv : U;
    const int m0 = ny * 128 + wm * 64;
    const int n0 = nxx * 128 + wn * 64;
#pragma unroll
    for (int mi = 0; mi < 4; ++mi)
#pragma unroll
      for (int ni = 0; ni < 4; ++ni)
#pragma unroll
        for (int j = 0; j < 4; ++j) {
          const int gm = m0 + mi * 16 + lk * 4 + j;
          const int gn = n0 + ni * 16 + lr;
          C[(long)gm * 1024 + gn] = (f16)acc[mi][ni][j];
        }
  }
}

// ---------------- FINAL GEMM: 256x256 tile, 8 waves, BK=64, fine 4-phase with correct sync ----------------
__global__ __launch_bounds__(512) void gemm256f(
    const f16* __restrict__ A,       // H flat [16384][1024]
    const f16* __restrict__ Bw,      // W2T [4][1024][1024]
    const float* __restrict__ resid,
    const float* __restrict__ c2v,
    float* __restrict__ outF) {
  const int lin = blockIdx.y * 4 + blockIdx.x;
  const int xcd = lin & 7, slot = lin >> 3;
  const int ny = xcd * 8 + (slot >> 2);          // 0..63  (M tile)
  const int nx = slot & 3;                       // 0..3   (N tile)
  const int bb = ny >> 4;

  GP64_COMMON();
  const int wm = wave >> 2, wn = wave & 3;       // 2 x 4 wave grid

  __shared__ __align__(16) f16 As[2][16384];
  __shared__ __align__(16) f16 Bs[2][16384];

  const f16* Ab = A + (long)ny * 262144;
  const f16* Bb = Bw + (long)bb * 1048576 + (long)nx * 262144;
  const long offs = (long)srow * 1024 + slc * 8;

  f32x4 zero = {0.f, 0.f, 0.f, 0.f};
  f32x4 acc[8][4];
#pragma unroll
  for (int mi = 0; mi < 8; ++mi)
#pragma unroll
    for (int ni = 0; ni < 4; ++ni) acc[mi][ni] = zero;

#define SA(buf, kt, q) gl_lds16(Ab + offs + (long)(q) * 65536 + (kt) * 64, &As[buf][(q) * 4096] + tid * 8)
#define SB(buf, kt, q) gl_lds16(Bb + offs + (long)(q) * 65536 + (kt) * 64, &Bs[buf][(q) * 4096] + tid * 8)

#define RD_BF(dst, bsb, kc)                                                       \
  _Pragma("unroll")                                                               \
  for (int ni = 0; ni < 4; ++ni)                                                  \
    dst[ni] = *(const f16x8*)((bsb) + (wn * 64 + ni * 16 + lr) * 64 + (kc));
#define RD_AF(dst, asb, mh, kc)                                                   \
  _Pragma("unroll")                                                               \
  for (int mi = 0; mi < 4; ++mi)                                                  \
    dst[mi] = *(const f16x8*)((asb) + (wm * 128 + (mh) * 64 + mi * 16 + lr) * 64 + (kc));
#define MF16(af_, bf_, mo)                                                        \
  __builtin_amdgcn_s_setprio(1);                                                  \
  _Pragma("unroll")                                                               \
  for (int mi = 0; mi < 4; ++mi)                                                  \
    _Pragma("unroll")                                                             \
    for (int ni = 0; ni < 4; ++ni)                                                \
      acc[(mo) + mi][ni] = __builtin_amdgcn_mfma_f32_16x16x32_f16(af_[mi], bf_[ni], \
                                                                  acc[(mo) + mi][ni], 0, 0, 0); \
  __builtin_amdgcn_s_setprio(0);

  const int nt = 16;
  // prologue: stage tile 0 in consumption order
  SB(0, 0, 0); SB(0, 0, 1); SB(0, 0, 2); SB(0, 0, 3);
  SA(0, 0, 0); SA(0, 0, 2); SA(0, 0, 1); SA(0, 0, 3);

  int cur = 0;
  for (int t = 0; t < nt; ++t) {
    const f16* asb = &As[cur][0];
    const f16* bsb = &Bs[cur][0];
    const int nb = cur ^ 1;
    const bool st = (t + 1 < nt);
    f16x8 bf[4], af[4];

    // ---- P0: (mh0, ks0) ----
    asm volatile("s_waitcnt vmcnt(2)" ::: "memory");   // 6 oldest of tile t landed (per wave)
    asm volatile("s_barrier" ::: "memory");            // ...for ALL waves -> B0-3,A0,A2 readable
    RD_BF(bf, bsb, kc0);
    RD_AF(af, asb, 0, kc0);
    if (st) { SB(nb, t + 1, 0); SB(nb, t + 1, 1); }
    asm volatile("s_waitcnt lgkmcnt(0)" ::: "memory");
    MF16(af, bf, 0);
    asm volatile("s_barrier" ::: "memory");

    // ---- P1: (mh1, ks0) ----
    if (st) asm volatile("s_waitcnt vmcnt(2)" ::: "memory");  // A1,A3 of tile t landed
    else    asm volatile("s_waitcnt vmcnt(0)" ::: "memory");  // last iter: only A1,A3 outstanding
    asm volatile("s_barrier" ::: "memory");
    RD_AF(af, asb, 1, kc0);
    if (st) { SB(nb, t + 1, 2); SB(nb, t + 1, 3); }
    asm volatile("s_waitcnt lgkmcnt(0)" ::: "memory");
    MF16(af, bf, 4);
    asm volatile("s_barrier" ::: "memory");

    // ---- P2: (mh0, ks1) — quadrants already verified ----
    RD_BF(bf, bsb, kc1);
    RD_AF(af, asb, 0, kc1);
    if (st) { SA(nb, t + 1, 0); SA(nb, t + 1, 2); }
    asm volatile("s_waitcnt lgkmcnt(0)" ::: "memory");
    MF16(af, bf, 0);
    asm volatile("s_barrier" ::: "memory");

    // ---- P3: (mh1, ks1) ----
    RD_AF(af, asb, 1, kc1);
    if (st) { SA(nb, t + 1, 1); SA(nb, t + 1, 3); }
    asm volatile("s_waitcnt lgkmcnt(0)" ::: "memory");
    MF16(af, bf, 4);
    asm volatile("s_barrier" ::: "memory");

    cur ^= 1;
  }
#undef SA
#undef SB
#undef RD_BF
#undef RD_AF
#undef MF16

  // drain any residual DMA before reusing LDS
  asm volatile("s_waitcnt vmcnt(0)" ::: "memory");
  asm volatile("s_barrier" ::: "memory");

  // -------- LDS-staged vectorized epilogue (reuses As) --------
  float* weps = ((float*)&As[0][0]) + wave * 1088;
  const int m0 = ny * 256 + wm * 128;
  const int n0 = nx * 256 + wn * 64;
  const int err = lane >> 3;
  const int ecc = (lane & 7) * 4;
  float4 cc2[2];
#pragma unroll
  for (int q = 0; q < 2; ++q)
    cc2[q] = *(const float4*)&c2v[bb * 1024 + n0 + ecc + 32 * q];

#pragma unroll
  for (int mi = 0; mi < 8; ++mi) {
#pragma unroll
    for (int ni = 0; ni < 4; ++ni)
#pragma unroll
      for (int j = 0; j < 4; ++j)
        weps[(lk * 4 + j) * 68 + ni * 16 + lr] = acc[mi][ni][j];
    asm volatile("s_waitcnt lgkmcnt(0)" ::: "memory");
#pragma unroll
    for (int h = 0; h < 2; ++h)
#pragma unroll
      for (int q = 0; q < 2; ++q) {
        const int rr = err + 8 * h;
        const int cc = ecc + 32 * q;
        float4 o = *(const float4*)&weps[rr * 68 + cc];
        const long gbase = (long)(m0 + mi * 16 + rr) * 1024 + n0 + cc;
        const float4 rv = *(const float4*)&resid[gbase];
        float4 ov;
        ov.x = o.x + rv.x + cc2[q].x;
        ov.y = o.y + rv.y + cc2[q].y;
        ov.z = o.z + rv.z + cc2[q].z;
        ov.w = o.w + rv.w + cc2[q].w;
        *(float4*)&outF[gbase] = ov;
      }
  }
}

// ---------------- reduce triangular G partials -> Gh, mirror ----------------
__global__ __launch_bounds__(256) void treduce(const f16* __restrict__ part,
                                               f16* __restrict__ Gh) {
  const int tileid = blockIdx.x, b = blockIdx.y;
  int ti = 0, trem = tileid;
  while (trem >= 8 - ti) { trem -= 8 - ti; ++ti; }
  const int tj = ti + trem;
  __shared__ f16 tl[128][132];
  const int tid = threadIdx.x;
  f16* Gb = Gh + (long)b * 1048576;
#pragma unroll
  for (int it = 0; it < 16; ++it) {
    const int e = it * 1024 + tid * 4;
    const int r = e >> 7, c = e & 127;
    f16x4 p0 = *(const f16x4*)(part + ((long)(0 * 4 + b) * 36 + tileid) * 16384 + e);
    f16x4 p1 = *(const f16x4*)(part + ((long)(1 * 4 + b) * 36 + tileid) * 16384 + e);
    f16x4 p2 = *(const f16x4*)(part + ((long)(2 * 4 + b) * 36 + tileid) * 16384 + e);
    f16x4 p3 = *(const f16x4*)(part + ((long)(3 * 4 + b) * 36 + tileid) * 16384 + e);
    f16x4 sv;
#pragma unroll
    for (int j = 0; j < 4; ++j)
      sv[j] = (f16)((float)p0[j] + (float)p1[j] + (float)p2[j] + (float)p3[j]);
    *(f16x4*)(Gb + (long)(ti * 128 + r) * 1024 + tj * 128 + c) = sv;
    *(f16x4*)&tl[r][c] = sv;
  }
  if (ti != tj) {
    __syncthreads();
#pragma unroll
    for (int it = 0; it < 16; ++it) {
      const int e = it * 1024 + tid * 4;
      const int r = e >> 7, c = e & 127;
      f16x4 v;
      v[0] = tl[c + 0][r];
      v[1] = tl[c + 1][r];
      v[2] = tl[c + 2][r];
      v[3] = tl[c + 3][r];
      *(f16x4*)(Gb + (long)(tj * 128 + r) * 1024 + ti * 128 + c) = v;
    }
  }
}

extern "C" void kernel_launch(void* const* d_in, const int* in_sizes, int n_in,
                              void* d_out, int out_size, void* d_ws, size_t ws_size,
                              hipStream_t stream) {
  const float* x      = (const float*)d_in[0];
  const float* norm_w = (const float*)d_in[1];
  const float* norm_b = (const float*)d_in[2];
  const float* qkv_w  = (const float*)d_in[3];
  const float* qkv_b  = (const float*)d_in[4];
  const float* proj_w = (const float*)d_in[5];
  const float* proj_b = (const float*)d_in[6];
  float* out = (float*)d_out;
  char* ws = (char*)d_ws;

  const size_t OFF_H    = 0;
  const size_t OFF_HT   = 33554432;
  const size_t OFF_T1   = 33554432;   // alias (Ht dead after gemmGUV)
  const size_t OFF_T2   = 41943040;
  const size_t OFF_WH   = 67108864;
  const size_t OFF_PH   = 73400320;
  const size_t OFF_WT3  = 75497472;
  const size_t OFF_U    = 81788928;
  const size_t OFF_PWV  = 83886080;
  const size_t OFF_GH   = 85983232;
  const size_t OFF_PART = 94371840;
  const size_t OFF_HS   = 115343360;
  const size_t OFF_AYD  = 115392512;
  const size_t OFF_SCAL = 115404800;
  const size_t OFF_EFZ  = 115405824;
  const size_t OFF_C2   = 115471360;

  f16* H    = (f16*)(ws + OFF_H);
  f16* Ht   = (f16*)(ws + OFF_HT);
  f16* T1   = (f16*)(ws + OFF_T1);
  f16* T2   = (f16*)(ws + OFF_T2);
  f16* Wh   = (f16*)(ws + OFF_WH);
  f16* Ph   = (f16*)(ws + OFF_PH);
  f16* WT3  = (f16*)(ws + OFF_WT3);
  f16* U    = (f16*)(ws + OFF_U);
  f16* PWv  = (f16*)(ws + OFF_PWV);
  f16* Gh   = (f16*)(ws + OFF_GH);
  f16* part = (f16*)(ws + OFF_PART);
  float* hs   = (float*)(ws + OFF_HS);
  float* ayd  = (float*)(ws + OFF_AYD);
  float* scal = (float*)(ws + OFF_SCAL);
  float* efz  = (float*)(ws + OFF_EFZ);
  float* c2v  = (float*)(ws + OFF_C2);

  // weight prep (one pass over qkv_w; straight casts fused)
  transcast4<<<dim3(16, 16, 4), 256, 0, stream>>>(qkv_w, proj_w, WT3, Wh, Ph);
  gemv3a<<<dim3(3073), 64, 0, stream>>>(WT3, Ph, qkv_b, ayd, scal);

  // input path (ln block 0 zeroes hs; completes before transpose_cs)
  ln_kernel<<<dim3(4096), 256, 0, stream>>>(x, norm_w, norm_b, H, hs);
  transpose_cs_kernel<<<dim3(16, 64, 4), 256, 0, stream>>>(H, Ht, hs);

  // merged: G tri-tiles (576 blocks, XCD-clustered by K-slice) + U/PWv (128 blocks)
  gemmGUV<<<dim3(704), 256, 0, stream>>>(Ht, WT3, Ph, part, U, PWv);
  treduce<<<dim3(36, 4), 256, 0, stream>>>(part, Gh);

  // gemv cluster: e, f, z, s_u  then c2 directly
  gemv3b<<<dim3(12292), 64, 0, stream>>>(U, PWv, Gh, hs, ayd, efz, scal);
  gemvC2n<<<dim3(4096), 64, 0, stream>>>(PWv, efz, ayd, scal, proj_b, c2v);

  // T1_b = U (x) G_b
  gemm128<0><<<dim3(8, 8, 4), 256, 0, stream>>>(U, Gh, 1024, 0L, 1048576L, 1048576L,
      T1, nullptr, nullptr, nullptr, nullptr);
  // W2T_b = (PWv (x) T1_b + d e^T + (f + 4096 d) a^T) / 32
  gemm128<1><<<dim3(8, 8, 4), 256, 0, stream>>>(PWv, T1, 1024, 0L, 1048576L, 1048576L,
      T2, ayd + 2048, efz, efz + 4096, ayd);

  // out = X + H (x) W2T + c2
  gemm256f<<<dim3(4, 64), 512, 0, stream>>>(H, T2, x, c2v, out);
}

// Round 20
// 178.492 us; speedup vs baseline: 1.1408x; 1.0354x over previous
//
#include <hip/hip_runtime.h>

typedef _Float16 f16;
typedef _Float16 f16x4 __attribute__((ext_vector_type(4)));
typedef _Float16 f16x8 __attribute__((ext_vector_type(8)));
typedef float f32x4 __attribute__((ext_vector_type(4)));

#define AS1 __attribute__((address_space(1)))
#define AS3 __attribute__((address_space(3)))

__device__ __forceinline__ void gl_lds16(const f16* g, f16* l) {
  __builtin_amdgcn_global_load_lds((const AS1 void*)g, (AS3 void*)l, 16, 0, 0);
}

// ---------------- LayerNorm: x (fp32) -> H (f16), one WAVE per row; block 0 zeroes hs ----------------
__global__ __launch_bounds__(256) void ln_kernel(const float* __restrict__ x,
                                                 const float* __restrict__ gw,
                                                 const float* __restrict__ gb,
                                                 f16* __restrict__ H,
                                                 float* __restrict__ hs) {
  if (blockIdx.x == 0) {
#pragma unroll
    for (int j = 0; j < 4; ++j)
      ((float4*)hs)[threadIdx.x + 256 * j] = make_float4(0.f, 0.f, 0.f, 0.f);
  }
  const int wv = threadIdx.x >> 6, lane = threadIdx.x & 63;
  const long row = (long)blockIdx.x * 4 + wv;
  const float* xr = x + row * 1024;
  float4 v[4];
  float s = 0.f, s2 = 0.f;
#pragma unroll
  for (int j = 0; j < 4; ++j) {
    v[j] = ((const float4*)xr)[lane + 64 * j];
    s  += v[j].x + v[j].y + v[j].z + v[j].w;
    s2 += v[j].x * v[j].x + v[j].y * v[j].y + v[j].z * v[j].z + v[j].w * v[j].w;
  }
#pragma unroll
  for (int off = 32; off > 0; off >>= 1) {
    s  += __shfl_xor(s, off);
    s2 += __shfl_xor(s2, off);
  }
  const float mu = s * (1.0f / 1024.0f);
  const float rstd = rsqrtf(s2 * (1.0f / 1024.0f) - mu * mu + 1e-5f);
#pragma unroll
  for (int j = 0; j < 4; ++j) {
    const float4 w4 = ((const float4*)gw)[lane + 64 * j];
    const float4 b4 = ((const float4*)gb)[lane + 64 * j];
    f16x4 h;
    h[0] = (f16)((v[j].x - mu) * rstd * w4.x + b4.x);
    h[1] = (f16)((v[j].y - mu) * rstd * w4.y + b4.y);
    h[2] = (f16)((v[j].z - mu) * rstd * w4.z + b4.z);
    h[3] = (f16)((v[j].w - mu) * rstd * w4.w + b4.w);
    *(f16x4*)(H + row * 1024 + (lane + 64 * j) * 4) = h;
  }
}

// ---------------- transpose H -> Ht, fused colsum ----------------
__global__ __launch_bounds__(256) void transpose_cs_kernel(const f16* __restrict__ H,
                                                           f16* __restrict__ Ht,
                                                           float* __restrict__ hs) {
  __shared__ f16 tile[64][68];
  __shared__ float csum[4][64];
  const int b = blockIdx.z;
  const long Hb  = (long)b * 4096 * 1024;
  const long Htb = (long)b * 1024 * 4096;
  const int t0 = blockIdx.y * 64, c0 = blockIdx.x * 64;
  const int tid = threadIdx.x;
  const int r = tid >> 2, g0 = tid & 3;
#pragma unroll
  for (int i = 0; i < 4; ++i) {
    const int g = g0 + i * 4;
    f16x4 v = *(const f16x4*)(H + Hb + (long)(t0 + r) * 1024 + c0 + g * 4);
    *(f16x4*)&tile[r][g * 4] = v;
  }
  __syncthreads();
  {
    const int cl = tid & 63, rg = tid >> 6;
    float s = 0.f;
#pragma unroll
    for (int rr = 0; rr < 16; ++rr) s += (float)tile[rg * 16 + rr][cl];
    csum[rg][cl] = s;
  }
#pragma unroll
  for (int i = 0; i < 4; ++i) {
    const int g = g0 + i * 4;
    f16x4 v;
    v[0] = tile[g * 4 + 0][r];
    v[1] = tile[g * 4 + 1][r];
    v[2] = tile[g * 4 + 2][r];
    v[3] = tile[g * 4 + 3][r];
    *(f16x4*)(Ht + Htb + (long)(c0 + r) * 4096 + t0 + g * 4) = v;
  }
  __syncthreads();
  if (tid < 64)
    atomicAdd(&hs[b * 1024 + c0 + tid],
              csum[0][tid] + csum[1][tid] + csum[2][tid] + csum[3][tid]);
}

// ---------------- transcast4: z=0..2 transpose qkv (z>=1 also straight cast), z=3 cast proj ----------------
__global__ __launch_bounds__(256) void transcast4(const float* __restrict__ qkv_w,
                                                  const float* __restrict__ proj_w,
                                                  f16* __restrict__ WT3,
                                                  f16* __restrict__ Wh,
                                                  f16* __restrict__ Ph) {
  const int z = blockIdx.z;
  __shared__ f16 tile[64][68];
  const int r0 = blockIdx.y * 64, c0 = blockIdx.x * 64;
  const int tid = threadIdx.x;
  const int r = tid >> 2, g0 = tid & 3;
  if (z == 3) {
#pragma unroll
    for (int i = 0; i < 4; ++i) {
      const int g = g0 + i * 4;
      float4 v = *(const float4*)(proj_w + (long)(r0 + r) * 1024 + c0 + g * 4);
      f16x4 h; h[0]=(f16)v.x; h[1]=(f16)v.y; h[2]=(f16)v.z; h[3]=(f16)v.w;
      *(f16x4*)(Ph + (long)(r0 + r) * 1024 + c0 + g * 4) = h;
    }
    return;
  }
  const float* W = qkv_w + (long)z * 1048576;
  f16* WT = WT3 + (long)z * 1048576;
#pragma unroll
  for (int i = 0; i < 4; ++i) {
    const int g = g0 + i * 4;
    float4 v = *(const float4*)(W + (long)(r0 + r) * 1024 + c0 + g * 4);
    f16x4 h; h[0]=(f16)v.x; h[1]=(f16)v.y; h[2]=(f16)v.z; h[3]=(f16)v.w;
    *(f16x4*)&tile[r][g * 4] = h;
    if (z >= 1)
      *(f16x4*)(Wh + (long)z * 1048576 + (long)(r0 + r) * 1024 + c0 + g * 4) = h;
  }
  __syncthreads();
#pragma unroll
  for (int i = 0; i < 4; ++i) {
    const int g = g0 + i * 4;
    f16x4 v;
    v[0] = tile[g * 4 + 0][r];
    v[1] = tile[g * 4 + 1][r];
    v[2] = tile[g * 4 + 2][r];
    v[3] = tile[g * 4 + 3][r];
    *(f16x4*)(WT + (long)(c0 + r) * 1024 + r0 + g * 4) = v;
  }
}

// ---------------- f16row . f32vec, 1024 elems, one 64-lane wave ----------------
__device__ __forceinline__ float dot1024(const f16* __restrict__ row,
                                         const float* __restrict__ v) {
  const int lane = threadIdx.x & 63;
  float s = 0.f;
#pragma unroll
  for (int j = 0; j < 2; ++j) {
    const int d = (lane + 64 * j) * 8;
    f16x8 a = *(const f16x8*)(row + d);
    float4 h0 = *(const float4*)(v + d);
    float4 h1 = *(const float4*)(v + d + 4);
    s += (float)a[0] * h0.x + (float)a[1] * h0.y + (float)a[2] * h0.z + (float)a[3] * h0.w
       + (float)a[4] * h1.x + (float)a[5] * h1.y + (float)a[6] * h1.z + (float)a[7] * h1.w;
  }
#pragma unroll
  for (int off = 32; off > 0; off >>= 1) s += __shfl_down(s, off);
  return s;
}

__device__ __forceinline__ float dotf1024(const float* __restrict__ a,
                                          const float* __restrict__ v) {
  const int lane = threadIdx.x & 63;
  float s = 0.f;
#pragma unroll
  for (int j = 0; j < 4; ++j) {
    const int d = (lane + 64 * j) * 4;
    float4 x = *(const float4*)(a + d);
    float4 q = *(const float4*)(v + d);
    s += x.x * q.x + x.y * q.y + x.z * q.z + x.w * q.w;
  }
#pragma unroll
  for (int off = 32; off > 0; off >>= 1) s += __shfl_down(s, off);
  return s;
}

// ---------------- gemv3a: a = WqT.bk, y = WkT.bq, d = Ph.bv, scal[4] = bk.bq ----------------
__global__ void gemv3a(const f16* __restrict__ WT3, const f16* __restrict__ Ph,
                       const float* __restrict__ qkv_b, float* __restrict__ ayd,
                       float* __restrict__ scal) {
  if (blockIdx.x == 3072) {
    float s = dotf1024(qkv_b + 1024, qkv_b);
    if ((threadIdx.x & 63) == 0) scal[4] = s;
    return;
  }
  const int which = blockIdx.x >> 10, m = blockIdx.x & 1023;
  const f16* row;
  const float* v;
  if (which == 0)      { row = WT3 + (long)m * 1024;            v = qkv_b + 1024; } // a
  else if (which == 1) { row = WT3 + 1048576 + (long)m * 1024;  v = qkv_b; }        // y
  else                 { row = Ph + (long)m * 1024;             v = qkv_b + 2048; } // d
  float s = dot1024(row, v);
  if ((threadIdx.x & 63) == 0) ayd[which * 1024 + m] = s;
}

// ================= shared GEMM machinery (BK = 64) =================
#define GP64_COMMON()                                        \
  const int tid = threadIdx.x;                               \
  const int wave = tid >> 6, lane = tid & 63;                \
  const int lr = lane & 15, lk = lane >> 4;                  \
  const int srow = tid >> 3;                                 \
  const int slc  = (tid & 7) ^ (srow & 7);                   \
  const int kc0 = ((lk) ^ (lr & 7)) * 8;                     \
  const int kc1 = ((4 + lk) ^ (lr & 7)) * 8;

// fine 2-phase K-loop for 4-wave 128x128 (proven r17/r18): defines the full loop.
// Requires SAq/SBq macros, As/Bs, acc, wm/wn, kc0/kc1 in scope; nt iterations.
#define FINE2_LOOP(NT_)                                                            \
  SBq(0, 0, 0); SBq(0, 0, 1); SBq(0, 0, 2); SBq(0, 0, 3);                          \
  SAq(0, 0, 0); SAq(0, 0, 2); SAq(0, 0, 1); SAq(0, 0, 3);                          \
  int cur = 0;                                                                     \
  for (int t = 0; t < (NT_); ++t) {                                                \
    const f16* asb = &As[cur][0];                                                  \
    const f16* bsb = &Bs[cur][0];                                                  \
    const int nb = cur ^ 1;                                                        \
    const bool st = (t + 1 < (NT_));                                               \
    f16x8 bf[4][2], af[2][2];                                                      \
    asm volatile("s_waitcnt vmcnt(2)" ::: "memory");                               \
    asm volatile("s_barrier" ::: "memory");                                        \
    _Pragma("unroll")                                                              \
    for (int ni = 0; ni < 4; ++ni) {                                               \
      bf[ni][0] = *(const f16x8*)(bsb + (wn * 64 + ni * 16 + lr) * 64 + kc0);      \
      bf[ni][1] = *(const f16x8*)(bsb + (wn * 64 + ni * 16 + lr) * 64 + kc1);      \
    }                                                                              \
    _Pragma("unroll")                                                              \
    for (int mi = 0; mi < 2; ++mi) {                                               \
      af[mi][0] = *(const f16x8*)(asb + (wm * 64 + mi * 16 + lr) * 64 + kc0);      \
      af[mi][1] = *(const f16x8*)(asb + (wm * 64 + mi * 16 + lr) * 64 + kc1);      \
    }                                                                              \
    if (st) { SBq(nb, t + 1, 0); SBq(nb, t + 1, 1); SBq(nb, t + 1, 2);             \
              SBq(nb, t + 1, 3); SAq(nb, t + 1, 0); SAq(nb, t + 1, 2); }           \
    asm volatile("s_waitcnt lgkmcnt(0)" ::: "memory");                             \
    __builtin_amdgcn_s_setprio(1);                                                 \
    _Pragma("unroll")                                                              \
    for (int ks = 0; ks < 2; ++ks)                                                 \
      _Pragma("unroll")                                                            \
      for (int mi = 0; mi < 2; ++mi)                                               \
        _Pragma("unroll")                                                          \
        for (int ni = 0; ni < 4; ++ni)                                             \
          acc[mi][ni] = __builtin_amdgcn_mfma_f32_16x16x32_f16(af[mi][ks],         \
                            bf[ni][ks], acc[mi][ni], 0, 0, 0);                     \
    __builtin_amdgcn_s_setprio(0);                                                 \
    asm volatile("s_barrier" ::: "memory");                                        \
    if (st) asm volatile("s_waitcnt vmcnt(6)" ::: "memory");                       \
    else    asm volatile("s_waitcnt vmcnt(0)" ::: "memory");                       \
    asm volatile("s_barrier" ::: "memory");                                        \
    _Pragma("unroll")                                                              \
    for (int mi = 0; mi < 2; ++mi) {                                               \
      af[mi][0] = *(const f16x8*)(asb + (wm * 64 + (mi + 2) * 16 + lr) * 64 + kc0);\
      af[mi][1] = *(const f16x8*)(asb + (wm * 64 + (mi + 2) * 16 + lr) * 64 + kc1);\
    }                                                                              \
    if (st) { SAq(nb, t + 1, 1); SAq(nb, t + 1, 3); }                              \
    asm volatile("s_waitcnt lgkmcnt(0)" ::: "memory");                             \
    __builtin_amdgcn_s_setprio(1);                                                 \
    _Pragma("unroll")                                                              \
    for (int ks = 0; ks < 2; ++ks)                                                 \
      _Pragma("unroll")                                                            \
      for (int mi = 0; mi < 2; ++mi)                                               \
        _Pragma("unroll")                                                          \
        for (int ni = 0; ni < 4; ++ni)                                             \
          acc[mi + 2][ni] = __builtin_amdgcn_mfma_f32_16x16x32_f16(af[mi][ks],     \
                                bf[ni][ks], acc[mi + 2][ni], 0, 0, 0);             \
    __builtin_amdgcn_s_setprio(0);                                                 \
    asm volatile("s_barrier" ::: "memory");                                        \
    cur ^= 1;                                                                      \
  }

// ---------------- MERGED A: T1_b = U x G_b  (bid<256)  +  gemv3b cluster (bid>=256) ----------------
__global__ __launch_bounds__(256) void gemmT1_g3b(
    const f16* __restrict__ U, const f16* __restrict__ Gh, f16* __restrict__ T1,
    const f16* __restrict__ PWv, const float* __restrict__ hs,
    const float* __restrict__ ayd, float* __restrict__ efz,
    float* __restrict__ scal) {
  GP64_COMMON();
  __shared__ __align__(16) f16 As[2][8192];
  __shared__ __align__(16) f16 Bs[2][8192];

  const int bid = blockIdx.x;
  if (bid >= 256) {
    // gemv3b: e = U.hs, f = PWv.hs, z = G.y, scal[b] = hs_b.y   (4 rows/block, 1/wave)
    const int u = (bid - 256) * 4 + wave;     // 0..12291
    if (u >= 12288) {
      const int b = u - 12288;
      float s = dotf1024(hs + b * 1024, ayd + 1024);
      if (lane == 0) scal[b] = s;
      return;
    }
    const int sel = u >> 12, r = u & 4095;
    const int b = r >> 10, m = r & 1023;
    const f16* row;
    const float* v;
    if (sel == 0)      { row = U + (long)m * 1024;                       v = hs + b * 1024; }
    else if (sel == 1) { row = PWv + (long)m * 1024;                     v = hs + b * 1024; }
    else               { row = Gh + (long)b * 1048576 + (long)m * 1024;  v = ayd + 1024; }
    float s = dot1024(row, v);
    if (lane == 0) efz[sel * 4096 + r] = s;
    return;
  }

  // gemm path (flattened grid, XCD class preserved: lin%8 == ny)
  const int ny = bid & 7, nx = (bid >> 3) & 7, b = bid >> 6;
  const int wm = wave >> 1, wn = wave & 1;
  const f16* Ab = U + (long)(ny * 128 + srow) * 1024 + slc * 8;
  const f16* Bb = Gh + (long)b * 1048576 + (long)(nx * 128 + srow) * 1024 + slc * 8;

  f32x4 zero = {0.f, 0.f, 0.f, 0.f};
  f32x4 acc[4][4];
#pragma unroll
  for (int mi = 0; mi < 4; ++mi)
#pragma unroll
    for (int ni = 0; ni < 4; ++ni) acc[mi][ni] = zero;

#define SAq(buf, kt, q) gl_lds16(Ab + (long)(q) * 32768 + (kt) * 64, &As[buf][(q) * 2048] + tid * 8)
#define SBq(buf, kt, q) gl_lds16(Bb + (long)(q) * 32768 + (kt) * 64, &Bs[buf][(q) * 2048] + tid * 8)
  FINE2_LOOP(16)
#undef SAq
#undef SBq

  f16* C = T1 + (long)b * 1048576;
  const int m0 = ny * 128 + wm * 64;
  const int n0 = nx * 128 + wn * 64;
#pragma unroll
  for (int mi = 0; mi < 4; ++mi)
#pragma unroll
    for (int ni = 0; ni < 4; ++ni)
#pragma unroll
      for (int j = 0; j < 4; ++j) {
        const int gm = m0 + mi * 16 + lk * 4 + j;
        const int gn = n0 + ni * 16 + lr;
        C[(long)gm * 1024 + gn] = (f16)acc[mi][ni][j];
      }
}

// ---------------- MERGED B: W2T_b = (PWv x T1_b + rank-1)/32 (bid<256) + c2 gemv (bid>=256) ----------------
__global__ __launch_bounds__(256) void gemmW2_c2(
    const f16* __restrict__ PWv, const f16* __restrict__ T1, f16* __restrict__ T2,
    const float* __restrict__ ayd, const float* __restrict__ efz,
    const float* __restrict__ scal, const float* __restrict__ proj_b,
    float* __restrict__ c2v) {
  GP64_COMMON();
  __shared__ __align__(16) f16 As[2][8192];
  __shared__ __align__(16) f16 Bs[2][8192];

  const int bid = blockIdx.x;
  if (bid >= 256) {
    // c2_b[c] = (PWv_row_c . z_b + d_c*s_u_b + s_b*(f_b_c + 4096 d_c))/32 + proj_b[c]
    const int u = (bid - 256) * 4 + wave;     // 0..4095
    const int b = u >> 10, c = u & 1023;
    float s = dot1024(PWv + (long)c * 1024, efz + 8192 + b * 1024);
    if (lane == 0) {
      const float d = ayd[2048 + c];
      c2v[b * 1024 + c] = (s + d * scal[b] + scal[4] * (efz[4096 + b * 1024 + c] + 4096.f * d))
                            * 0.03125f + proj_b[c];
    }
    return;
  }

  const int ny = bid & 7, nx = (bid >> 3) & 7, b = bid >> 6;
  const int wm = wave >> 1, wn = wave & 1;
  const f16* Ab = PWv + (long)(ny * 128 + srow) * 1024 + slc * 8;
  const f16* Bb = T1 + (long)b * 1048576 + (long)(nx * 128 + srow) * 1024 + slc * 8;

  f32x4 zero = {0.f, 0.f, 0.f, 0.f};
  f32x4 acc[4][4];
#pragma unroll
  for (int mi = 0; mi < 4; ++mi)
#pragma unroll
    for (int ni = 0; ni < 4; ++ni) acc[mi][ni] = zero;

#define SAq(buf, kt, q) gl_lds16(Ab + (long)(q) * 32768 + (kt) * 64, &As[buf][(q) * 2048] + tid * 8)
#define SBq(buf, kt, q) gl_lds16(Bb + (long)(q) * 32768 + (kt) * 64, &Bs[buf][(q) * 2048] + tid * 8)
  FINE2_LOOP(16)
#undef SAq
#undef SBq

  f16* C = T2 + (long)b * 1048576;
  const int m0 = ny * 128 + wm * 64;
  const int n0 = nx * 128 + wn * 64;
#pragma unroll
  for (int mi = 0; mi < 4; ++mi)
#pragma unroll
    for (int ni = 0; ni < 4; ++ni)
#pragma unroll
      for (int j = 0; j < 4; ++j) {
        const int gm = m0 + mi * 16 + lk * 4 + j;
        const int gn = n0 + ni * 16 + lr;
        const float dm = ayd[2048 + gm];
        const float fm = efz[4096 + b * 1024 + gm];
        const float en = efz[b * 1024 + gn];
        const float an = ayd[gn];
        float val = (acc[mi][ni][j] + dm * en + (fm + 4096.f * dm) * an) * 0.03125f;
        C[(long)gm * 1024 + gn] = (f16)val;
      }
}

// ---------------- MERGED: G = H^T H (tri, split-K=4) + {U, PWv}; fine 2-phase pipeline ----------------
__global__ __launch_bounds__(256) void gemmGUV(const f16* __restrict__ Ht,
                                               const f16* __restrict__ WT3,
                                               const f16* __restrict__ Ph,
                                               f16* __restrict__ part,
                                               f16* __restrict__ U,
                                               f16* __restrict__ PWv) {
  GP64_COMMON();
  const int wm = wave >> 1, wn = wave & 1;

  __shared__ __align__(16) f16 As[2][8192];
  __shared__ __align__(16) f16 Bs[2][8192];

  const int bid = blockIdx.x;
  const f16 *Ab, *Bb;
  long rs;
  int tileid = 0, zz = 0, selt = 0;
  if (bid < 576) {
    zz = bid & 15;           // K-slice*4 + batch  (XCD class = zz%8)
    tileid = bid >> 4;       // 0..35 triangular tile
    const int b = zz & 3, ks4 = zz >> 2;
    int ti = 0, trem = tileid;
    while (trem >= 8 - ti) { trem -= 8 - ti; ++ti; }
    const int tj = ti + trem;
    const f16* Hb = Ht + (long)b * 4194304;
    rs = 4096;
    Ab = Hb + (long)(ti * 128 + srow) * 4096 + (long)ks4 * 1024 + slc * 8;
    Bb = Hb + (long)(tj * 128 + srow) * 4096 + (long)ks4 * 1024 + slc * 8;
  } else {
    const int u = bid - 576;
    selt = (u >> 6) + 1;                 // 1: U, 2: PWv
    const int t = u & 63;
    const int ny = t >> 3, nxx = t & 7;
    const f16* A0 = (selt == 2) ? Ph : WT3;
    const f16* B0 = (selt == 2) ? (WT3 + 2097152) : (WT3 + 1048576);
    rs = 1024;
    Ab = A0 + (long)(ny * 128 + srow) * 1024 + slc * 8;
    Bb = B0 + (long)(nxx * 128 + srow) * 1024 + slc * 8;
  }

  f32x4 zero = {0.f, 0.f, 0.f, 0.f};
  f32x4 acc[4][4];
#pragma unroll
  for (int mi = 0; mi < 4; ++mi)
#pragma unroll
    for (int ni = 0; ni < 4; ++ni) acc[mi][ni] = zero;

#define SAq(buf, kt, q) gl_lds16(Ab + (long)(q) * 32 * rs + (kt) * 64, &As[buf][(q) * 2048] + tid * 8)
#define SBq(buf, kt, q) gl_lds16(Bb + (long)(q) * 32 * rs + (kt) * 64, &Bs[buf][(q) * 2048] + tid * 8)
  FINE2_LOOP(16)
#undef SAq
#undef SBq

  if (selt == 0) {
    f16* P = part + ((long)zz * 36 + tileid) * 16384;
#pragma unroll
    for (int mi = 0; mi < 4; ++mi)
#pragma unroll
      for (int ni = 0; ni < 4; ++ni)
#pragma unroll
        for (int j = 0; j < 4; ++j) {
          const int gm = wm * 64 + mi * 16 + lk * 4 + j;
          const int gn = wn * 64 + ni * 16 + lr;
          P[gm * 128 + gn] = (f16)acc[mi][ni][j];
        }
  } else {
    const int u = bid - 576;
    const int t = u & 63;
    const int ny = t >> 3, nxx = t & 7;
    f16* C = (selt == 2) ? PWv : U;
    const int m0 = ny * 128 + wm * 64;
    const int n0 = nxx * 128 + wn * 64;
#pragma unroll
    for (int mi = 0; mi < 4; ++mi)
#pragma unroll
      for (int ni = 0; ni < 4; ++ni)
#pragma unroll
        for (int j = 0; j < 4; ++j) {
          const int gm = m0 + mi * 16 + lk * 4 + j;
          const int gn = n0 + ni * 16 + lr;
          C[(long)gm * 1024 + gn] = (f16)acc[mi][ni][j];
        }
  }
}

// ---------------- FINAL GEMM: 256x256 tile, 8 waves, BK=64, fine 4-phase with correct sync ----------------
__global__ __launch_bounds__(512) void gemm256f(
    const f16* __restrict__ A,       // H flat [16384][1024]
    const f16* __restrict__ Bw,      // W2T [4][1024][1024]
    const float* __restrict__ resid,
    const float* __restrict__ c2v,
    float* __restrict__ outF) {
  const int lin = blockIdx.y * 4 + blockIdx.x;
  const int xcd = lin & 7, slot = lin >> 3;
  const int ny = xcd * 8 + (slot >> 2);          // 0..63  (M tile)
  const int nx = slot & 3;                       // 0..3   (N tile)
  const int bb = ny >> 4;

  GP64_COMMON();
  const int wm = wave >> 2, wn = wave & 3;       // 2 x 4 wave grid

  __shared__ __align__(16) f16 As[2][16384];
  __shared__ __align__(16) f16 Bs[2][16384];

  const f16* Ab = A + (long)ny * 262144;
  const f16* Bb = Bw + (long)bb * 1048576 + (long)nx * 262144;
  const long offs = (long)srow * 1024 + slc * 8;

  f32x4 zero = {0.f, 0.f, 0.f, 0.f};
  f32x4 acc[8][4];
#pragma unroll
  for (int mi = 0; mi < 8; ++mi)
#pragma unroll
    for (int ni = 0; ni < 4; ++ni) acc[mi][ni] = zero;

#define SA(buf, kt, q) gl_lds16(Ab + offs + (long)(q) * 65536 + (kt) * 64, &As[buf][(q) * 4096] + tid * 8)
#define SB(buf, kt, q) gl_lds16(Bb + offs + (long)(q) * 65536 + (kt) * 64, &Bs[buf][(q) * 4096] + tid * 8)

#define RD_BF(dst, bsb, kc)                                                       \
  _Pragma("unroll")                                                               \
  for (int ni = 0; ni < 4; ++ni)                                                  \
    dst[ni] = *(const f16x8*)((bsb) + (wn * 64 + ni * 16 + lr) * 64 + (kc));
#define RD_AF(dst, asb, mh, kc)                                                   \
  _Pragma("unroll")                                                               \
  for (int mi = 0; mi < 4; ++mi)                                                  \
    dst[mi] = *(const f16x8*)((asb) + (wm * 128 + (mh) * 64 + mi * 16 + lr) * 64 + (kc));
#define MF16(af_, bf_, mo)                                                        \
  __builtin_amdgcn_s_setprio(1);                                                  \
  _Pragma("unroll")                                                               \
  for (int mi = 0; mi < 4; ++mi)                                                  \
    _Pragma("unroll")                                                             \
    for (int ni = 0; ni < 4; ++ni)                                                \
      acc[(mo) + mi][ni] = __builtin_amdgcn_mfma_f32_16x16x32_f16(af_[mi], bf_[ni], \
                                                                  acc[(mo) + mi][ni], 0, 0, 0); \
  __builtin_amdgcn_s_setprio(0);

  const int nt = 16;
  // prologue: stage tile 0 in consumption order
  SB(0, 0, 0); SB(0, 0, 1); SB(0, 0, 2); SB(0, 0, 3);
  SA(0, 0, 0); SA(0, 0, 2); SA(0, 0, 1); SA(0, 0, 3);

  int cur = 0;
  for (int t = 0; t < nt; ++t) {
    const f16* asb = &As[cur][0];
    const f16* bsb = &Bs[cur][0];
    const int nb = cur ^ 1;
    const bool st = (t + 1 < nt);
    f16x8 bf[4], af[4];

    // ---- P0: (mh0, ks0) ----
    asm volatile("s_waitcnt vmcnt(2)" ::: "memory");   // 6 oldest of tile t landed (per wave)
    asm volatile("s_barrier" ::: "memory");            // ...for ALL waves -> B0-3,A0,A2 readable
    RD_BF(bf, bsb, kc0);
    RD_AF(af, asb, 0, kc0);
    if (st) { SB(nb, t + 1, 0); SB(nb, t + 1, 1); }
    asm volatile("s_waitcnt lgkmcnt(0)" ::: "memory");
    MF16(af, bf, 0);
    asm volatile("s_barrier" ::: "memory");

    // ---- P1: (mh1, ks0) ----
    if (st) asm volatile("s_waitcnt vmcnt(2)" ::: "memory");  // A1,A3 of tile t landed
    else    asm volatile("s_waitcnt vmcnt(0)" ::: "memory");  // last iter: only A1,A3 outstanding
    asm volatile("s_barrier" ::: "memory");
    RD_AF(af, asb, 1, kc0);
    if (st) { SB(nb, t + 1, 2); SB(nb, t + 1, 3); }
    asm volatile("s_waitcnt lgkmcnt(0)" ::: "memory");
    MF16(af, bf, 4);
    asm volatile("s_barrier" ::: "memory");

    // ---- P2: (mh0, ks1) — quadrants already verified ----
    RD_BF(bf, bsb, kc1);
    RD_AF(af, asb, 0, kc1);
    if (st) { SA(nb, t + 1, 0); SA(nb, t + 1, 2); }
    asm volatile("s_waitcnt lgkmcnt(0)" ::: "memory");
    MF16(af, bf, 0);
    asm volatile("s_barrier" ::: "memory");

    // ---- P3: (mh1, ks1) ----
    RD_AF(af, asb, 1, kc1);
    if (st) { SA(nb, t + 1, 1); SA(nb, t + 1, 3); }
    asm volatile("s_waitcnt lgkmcnt(0)" ::: "memory");
    MF16(af, bf, 4);
    asm volatile("s_barrier" ::: "memory");

    cur ^= 1;
  }
#undef SA
#undef SB
#undef RD_BF
#undef RD_AF
#undef MF16

  // drain any residual DMA before reusing LDS
  asm volatile("s_waitcnt vmcnt(0)" ::: "memory");
  asm volatile("s_barrier" ::: "memory");

  // -------- LDS-staged vectorized epilogue (reuses As) --------
  float* weps = ((float*)&As[0][0]) + wave * 1088;
  const int m0 = ny * 256 + wm * 128;
  const int n0 = nx * 256 + wn * 64;
  const int err = lane >> 3;
  const int ecc = (lane & 7) * 4;
  float4 cc2[2];
#pragma unroll
  for (int q = 0; q < 2; ++q)
    cc2[q] = *(const float4*)&c2v[bb * 1024 + n0 + ecc + 32 * q];

#pragma unroll
  for (int mi = 0; mi < 8; ++mi) {
#pragma unroll
    for (int ni = 0; ni < 4; ++ni)
#pragma unroll
      for (int j = 0; j < 4; ++j)
        weps[(lk * 4 + j) * 68 + ni * 16 + lr] = acc[mi][ni][j];
    asm volatile("s_waitcnt lgkmcnt(0)" ::: "memory");
#pragma unroll
    for (int h = 0; h < 2; ++h)
#pragma unroll
      for (int q = 0; q < 2; ++q) {
        const int rr = err + 8 * h;
        const int cc = ecc + 32 * q;
        float4 o = *(const float4*)&weps[rr * 68 + cc];
        const long gbase = (long)(m0 + mi * 16 + rr) * 1024 + n0 + cc;
        const float4 rv = *(const float4*)&resid[gbase];
        float4 ov;
        ov.x = o.x + rv.x + cc2[q].x;
        ov.y = o.y + rv.y + cc2[q].y;
        ov.z = o.z + rv.z + cc2[q].z;
        ov.w = o.w + rv.w + cc2[q].w;
        *(float4*)&outF[gbase] = ov;
      }
  }
}

// ---------------- reduce triangular G partials -> Gh, mirror ----------------
__global__ __launch_bounds__(256) void treduce(const f16* __restrict__ part,
                                               f16* __restrict__ Gh) {
  const int tileid = blockIdx.x, b = blockIdx.y;
  int ti = 0, trem = tileid;
  while (trem >= 8 - ti) { trem -= 8 - ti; ++ti; }
  const int tj = ti + trem;
  __shared__ f16 tl[128][132];
  const int tid = threadIdx.x;
  f16* Gb = Gh + (long)b * 1048576;
#pragma unroll
  for (int it = 0; it < 16; ++it) {
    const int e = it * 1024 + tid * 4;
    const int r = e >> 7, c = e & 127;
    f16x4 p0 = *(const f16x4*)(part + ((long)(0 * 4 + b) * 36 + tileid) * 16384 + e);
    f16x4 p1 = *(const f16x4*)(part + ((long)(1 * 4 + b) * 36 + tileid) * 16384 + e);
    f16x4 p2 = *(const f16x4*)(part + ((long)(2 * 4 + b) * 36 + tileid) * 16384 + e);
    f16x4 p3 = *(const f16x4*)(part + ((long)(3 * 4 + b) * 36 + tileid) * 16384 + e);
    f16x4 sv;
#pragma unroll
    for (int j = 0; j < 4; ++j)
      sv[j] = (f16)((float)p0[j] + (float)p1[j] + (float)p2[j] + (float)p3[j]);
    *(f16x4*)(Gb + (long)(ti * 128 + r) * 1024 + tj * 128 + c) = sv;
    *(f16x4*)&tl[r][c] = sv;
  }
  if (ti != tj) {
    __syncthreads();
#pragma unroll
    for (int it = 0; it < 16; ++it) {
      const int e = it * 1024 + tid * 4;
      const int r = e >> 7, c = e & 127;
      f16x4 v;
      v[0] = tl[c + 0][r];
      v[1] = tl[c + 1][r];
      v[2] = tl[c + 2][r];
      v[3] = tl[c + 3][r];
      *(f16x4*)(Gb + (long)(tj * 128 + r) * 1024 + ti * 128 + c) = v;
    }
  }
}

extern "C" void kernel_launch(void* const* d_in, const int* in_sizes, int n_in,
                              void* d_out, int out_size, void* d_ws, size_t ws_size,
                              hipStream_t stream) {
  const float* x      = (const float*)d_in[0];
  const float* norm_w = (const float*)d_in[1];
  const float* norm_b = (const float*)d_in[2];
  const float* qkv_w  = (const float*)d_in[3];
  const float* qkv_b  = (const float*)d_in[4];
  const float* proj_w = (const float*)d_in[5];
  const float* proj_b = (const float*)d_in[6];
  float* out = (float*)d_out;
  char* ws = (char*)d_ws;

  const size_t OFF_H    = 0;
  const size_t OFF_HT   = 33554432;
  const size_t OFF_T1   = 33554432;   // alias (Ht dead after gemmGUV)
  const size_t OFF_T2   = 41943040;
  const size_t OFF_WH   = 67108864;
  const size_t OFF_PH   = 73400320;
  const size_t OFF_WT3  = 75497472;
  const size_t OFF_U    = 81788928;
  const size_t OFF_PWV  = 83886080;
  const size_t OFF_GH   = 85983232;
  const size_t OFF_PART = 94371840;
  const size_t OFF_HS   = 115343360;
  const size_t OFF_AYD  = 115392512;
  const size_t OFF_SCAL = 115404800;
  const size_t OFF_EFZ  = 115405824;
  const size_t OFF_C2   = 115471360;

  f16* H    = (f16*)(ws + OFF_H);
  f16* Ht   = (f16*)(ws + OFF_HT);
  f16* T1   = (f16*)(ws + OFF_T1);
  f16* T2   = (f16*)(ws + OFF_T2);
  f16* Wh   = (f16*)(ws + OFF_WH);
  f16* Ph   = (f16*)(ws + OFF_PH);
  f16* WT3  = (f16*)(ws + OFF_WT3);
  f16* U    = (f16*)(ws + OFF_U);
  f16* PWv  = (f16*)(ws + OFF_PWV);
  f16* Gh   = (f16*)(ws + OFF_GH);
  f16* part = (f16*)(ws + OFF_PART);
  float* hs   = (float*)(ws + OFF_HS);
  float* ayd  = (float*)(ws + OFF_AYD);
  float* scal = (float*)(ws + OFF_SCAL);
  float* efz  = (float*)(ws + OFF_EFZ);
  float* c2v  = (float*)(ws + OFF_C2);

  // weight prep (one pass over qkv_w; straight casts fused)
  transcast4<<<dim3(16, 16, 4), 256, 0, stream>>>(qkv_w, proj_w, WT3, Wh, Ph);
  gemv3a<<<dim3(3073), 64, 0, stream>>>(WT3, Ph, qkv_b, ayd, scal);

  // input path (ln block 0 zeroes hs; completes before transpose_cs)
  ln_kernel<<<dim3(4096), 256, 0, stream>>>(x, norm_w, norm_b, H, hs);
  transpose_cs_kernel<<<dim3(16, 64, 4), 256, 0, stream>>>(H, Ht, hs);

  // merged: G tri-tiles (576 blocks, XCD-clustered by K-slice) + U/PWv (128 blocks)
  gemmGUV<<<dim3(704), 256, 0, stream>>>(Ht, WT3, Ph, part, U, PWv);
  treduce<<<dim3(36, 4), 256, 0, stream>>>(part, Gh);

  // merged A: T1_b = U x G_b (256 blocks) + gemv3b cluster (3073 blocks)
  gemmT1_g3b<<<dim3(3329), 256, 0, stream>>>(U, Gh, T1, PWv, hs, ayd, efz, scal);
  // merged B: W2T_b = (PWv x T1_b + rank-1)/32 (256 blocks) + c2 gemv (1024 blocks)
  gemmW2_c2<<<dim3(1280), 256, 0, stream>>>(PWv, T1, T2, ayd, efz, scal, proj_b, c2v);

  // out = X + H (x) W2T + c2
  gemm256f<<<dim3(4, 64), 512, 0, stream>>>(H, T2, x, c2v, out);
}

// Round 21
// 177.448 us; speedup vs baseline: 1.1475x; 1.0059x over previous
//
#include <hip/hip_runtime.h>

typedef _Float16 f16;
typedef _Float16 f16x4 __attribute__((ext_vector_type(4)));
typedef _Float16 f16x8 __attribute__((ext_vector_type(8)));
typedef float f32x4 __attribute__((ext_vector_type(4)));

#define AS1 __attribute__((address_space(1)))
#define AS3 __attribute__((address_space(3)))

__device__ __forceinline__ void gl_lds16(const f16* g, f16* l) {
  __builtin_amdgcn_global_load_lds((const AS1 void*)g, (AS3 void*)l, 16, 0, 0);
}

// ---------------- f16row . f32vec, 1024 elems, one 64-lane wave ----------------
__device__ __forceinline__ float dot1024(const f16* __restrict__ row,
                                         const float* __restrict__ v) {
  const int lane = threadIdx.x & 63;
  float s = 0.f;
#pragma unroll
  for (int j = 0; j < 2; ++j) {
    const int d = (lane + 64 * j) * 8;
    f16x8 a = *(const f16x8*)(row + d);
    float4 h0 = *(const float4*)(v + d);
    float4 h1 = *(const float4*)(v + d + 4);
    s += (float)a[0] * h0.x + (float)a[1] * h0.y + (float)a[2] * h0.z + (float)a[3] * h0.w
       + (float)a[4] * h1.x + (float)a[5] * h1.y + (float)a[6] * h1.z + (float)a[7] * h1.w;
  }
#pragma unroll
  for (int off = 32; off > 0; off >>= 1) s += __shfl_down(s, off);
  return s;
}

__device__ __forceinline__ float dotf1024(const float* __restrict__ a,
                                          const float* __restrict__ v) {
  const int lane = threadIdx.x & 63;
  float s = 0.f;
#pragma unroll
  for (int j = 0; j < 4; ++j) {
    const int d = (lane + 64 * j) * 4;
    float4 x = *(const float4*)(a + d);
    float4 q = *(const float4*)(v + d);
    s += x.x * q.x + x.y * q.y + x.z * q.z + x.w * q.w;
  }
#pragma unroll
  for (int off = 32; off > 0; off >>= 1) s += __shfl_down(s, off);
  return s;
}

// ---------------- MERGED PREP: ln (bid<4096, block 0 zeroes hs) + transcast (bid>=4096) ----------------
__global__ __launch_bounds__(256) void prep_kernel(
    const float* __restrict__ x, const float* __restrict__ gw,
    const float* __restrict__ gb, f16* __restrict__ H, float* __restrict__ hs,
    const float* __restrict__ qkv_w, const float* __restrict__ proj_w,
    f16* __restrict__ WT3, f16* __restrict__ Ph) {
  const int bid = blockIdx.x;
  const int tid = threadIdx.x;
  if (bid >= 4096) {
    // transcast: u = x + 16*y + 256*z  (orig grid 16x16x4)
    const int u = bid - 4096;
    const int z = u >> 8;
    const int r0 = ((u >> 4) & 15) * 64, c0 = (u & 15) * 64;
    const int r = tid >> 2, g0 = tid & 3;
    if (z == 3) {
#pragma unroll
      for (int i = 0; i < 4; ++i) {
        const int g = g0 + i * 4;
        float4 v = *(const float4*)(proj_w + (long)(r0 + r) * 1024 + c0 + g * 4);
        f16x4 h; h[0]=(f16)v.x; h[1]=(f16)v.y; h[2]=(f16)v.z; h[3]=(f16)v.w;
        *(f16x4*)(Ph + (long)(r0 + r) * 1024 + c0 + g * 4) = h;
      }
      return;
    }
    __shared__ f16 tile[64][68];
    const float* W = qkv_w + (long)z * 1048576;
    f16* WT = WT3 + (long)z * 1048576;
#pragma unroll
    for (int i = 0; i < 4; ++i) {
      const int g = g0 + i * 4;
      float4 v = *(const float4*)(W + (long)(r0 + r) * 1024 + c0 + g * 4);
      f16x4 h; h[0]=(f16)v.x; h[1]=(f16)v.y; h[2]=(f16)v.z; h[3]=(f16)v.w;
      *(f16x4*)&tile[r][g * 4] = h;
    }
    __syncthreads();
#pragma unroll
    for (int i = 0; i < 4; ++i) {
      const int g = g0 + i * 4;
      f16x4 v;
      v[0] = tile[g * 4 + 0][r];
      v[1] = tile[g * 4 + 1][r];
      v[2] = tile[g * 4 + 2][r];
      v[3] = tile[g * 4 + 3][r];
      *(f16x4*)(WT + (long)(c0 + r) * 1024 + r0 + g * 4) = v;
    }
    return;
  }
  // ln path
  if (bid == 0) {
#pragma unroll
    for (int j = 0; j < 4; ++j)
      ((float4*)hs)[tid + 256 * j] = make_float4(0.f, 0.f, 0.f, 0.f);
  }
  const int wv = tid >> 6, lane = tid & 63;
  const long row = (long)bid * 4 + wv;
  const float* xr = x + row * 1024;
  float4 v[4];
  float s = 0.f, s2 = 0.f;
#pragma unroll
  for (int j = 0; j < 4; ++j) {
    v[j] = ((const float4*)xr)[lane + 64 * j];
    s  += v[j].x + v[j].y + v[j].z + v[j].w;
    s2 += v[j].x * v[j].x + v[j].y * v[j].y + v[j].z * v[j].z + v[j].w * v[j].w;
  }
#pragma unroll
  for (int off = 32; off > 0; off >>= 1) {
    s  += __shfl_xor(s, off);
    s2 += __shfl_xor(s2, off);
  }
  const float mu = s * (1.0f / 1024.0f);
  const float rstd = rsqrtf(s2 * (1.0f / 1024.0f) - mu * mu + 1e-5f);
#pragma unroll
  for (int j = 0; j < 4; ++j) {
    const float4 w4 = ((const float4*)gw)[lane + 64 * j];
    const float4 b4 = ((const float4*)gb)[lane + 64 * j];
    f16x4 h;
    h[0] = (f16)((v[j].x - mu) * rstd * w4.x + b4.x);
    h[1] = (f16)((v[j].y - mu) * rstd * w4.y + b4.y);
    h[2] = (f16)((v[j].z - mu) * rstd * w4.z + b4.z);
    h[3] = (f16)((v[j].w - mu) * rstd * w4.w + b4.w);
    *(f16x4*)(H + row * 1024 + (lane + 64 * j) * 4) = h;
  }
}

// ---------------- MERGED: transpose_cs (bid<4096) + gemv3a (bid>=4096, 4 rows/block) ----------------
__global__ __launch_bounds__(256) void tcgemv_kernel(
    const f16* __restrict__ H, f16* __restrict__ Ht, float* __restrict__ hs,
    const f16* __restrict__ WT3, const f16* __restrict__ Ph,
    const float* __restrict__ qkv_b, float* __restrict__ ayd,
    float* __restrict__ scal) {
  const int bid = blockIdx.x;
  const int tid = threadIdx.x;
  if (bid >= 4096) {
    const int wave = tid >> 6, lane = tid & 63;
    const int u = (bid - 4096) * 4 + wave;   // 0..3075
    if (u > 3072) return;
    if (u == 3072) {
      float s = dotf1024(qkv_b + 1024, qkv_b);
      if (lane == 0) scal[4] = s;
      return;
    }
    const int which = u >> 10, m = u & 1023;
    const f16* row;
    const float* v;
    if (which == 0)      { row = WT3 + (long)m * 1024;            v = qkv_b + 1024; } // a
    else if (which == 1) { row = WT3 + 1048576 + (long)m * 1024;  v = qkv_b; }        // y
    else                 { row = Ph + (long)m * 1024;             v = qkv_b + 2048; } // d
    float s = dot1024(row, v);
    if (lane == 0) ayd[which * 1024 + m] = s;
    return;
  }
  // transpose_cs: u = x + 16*y + 1024*z (orig grid 16x64x4)
  __shared__ f16 tile[64][68];
  __shared__ float csum[4][64];
  const int b = bid >> 10;
  const long Hb  = (long)b * 4096 * 1024;
  const long Htb = (long)b * 1024 * 4096;
  const int t0 = ((bid >> 4) & 63) * 64, c0 = (bid & 15) * 64;
  const int r = tid >> 2, g0 = tid & 3;
#pragma unroll
  for (int i = 0; i < 4; ++i) {
    const int g = g0 + i * 4;
    f16x4 v = *(const f16x4*)(H + Hb + (long)(t0 + r) * 1024 + c0 + g * 4);
    *(f16x4*)&tile[r][g * 4] = v;
  }
  __syncthreads();
  {
    const int cl = tid & 63, rg = tid >> 6;
    float s = 0.f;
#pragma unroll
    for (int rr = 0; rr < 16; ++rr) s += (float)tile[rg * 16 + rr][cl];
    csum[rg][cl] = s;
  }
#pragma unroll
  for (int i = 0; i < 4; ++i) {
    const int g = g0 + i * 4;
    f16x4 v;
    v[0] = tile[g * 4 + 0][r];
    v[1] = tile[g * 4 + 1][r];
    v[2] = tile[g * 4 + 2][r];
    v[3] = tile[g * 4 + 3][r];
    *(f16x4*)(Ht + Htb + (long)(c0 + r) * 4096 + t0 + g * 4) = v;
  }
  __syncthreads();
  if (tid < 64)
    atomicAdd(&hs[b * 1024 + c0 + tid],
              csum[0][tid] + csum[1][tid] + csum[2][tid] + csum[3][tid]);
}

// ================= shared GEMM machinery (BK = 64) =================
#define GP64_COMMON()                                        \
  const int tid = threadIdx.x;                               \
  const int wave = tid >> 6, lane = tid & 63;                \
  const int lr = lane & 15, lk = lane >> 4;                  \
  const int srow = tid >> 3;                                 \
  const int slc  = (tid & 7) ^ (srow & 7);                   \
  const int kc0 = ((lk) ^ (lr & 7)) * 8;                     \
  const int kc1 = ((4 + lk) ^ (lr & 7)) * 8;

// fine 2-phase K-loop for 4-wave 128x128 (proven r17/r18)
#define FINE2_LOOP(NT_)                                                            \
  SBq(0, 0, 0); SBq(0, 0, 1); SBq(0, 0, 2); SBq(0, 0, 3);                          \
  SAq(0, 0, 0); SAq(0, 0, 2); SAq(0, 0, 1); SAq(0, 0, 3);                          \
  int cur = 0;                                                                     \
  for (int t = 0; t < (NT_); ++t) {                                                \
    const f16* asb = &As[cur][0];                                                  \
    const f16* bsb = &Bs[cur][0];                                                  \
    const int nb = cur ^ 1;                                                        \
    const bool st = (t + 1 < (NT_));                                               \
    f16x8 bf[4][2], af[2][2];                                                      \
    asm volatile("s_waitcnt vmcnt(2)" ::: "memory");                               \
    asm volatile("s_barrier" ::: "memory");                                        \
    _Pragma("unroll")                                                              \
    for (int ni = 0; ni < 4; ++ni) {                                               \
      bf[ni][0] = *(const f16x8*)(bsb + (wn * 64 + ni * 16 + lr) * 64 + kc0);      \
      bf[ni][1] = *(const f16x8*)(bsb + (wn * 64 + ni * 16 + lr) * 64 + kc1);      \
    }                                                                              \
    _Pragma("unroll")                                                              \
    for (int mi = 0; mi < 2; ++mi) {                                               \
      af[mi][0] = *(const f16x8*)(asb + (wm * 64 + mi * 16 + lr) * 64 + kc0);      \
      af[mi][1] = *(const f16x8*)(asb + (wm * 64 + mi * 16 + lr) * 64 + kc1);      \
    }                                                                              \
    if (st) { SBq(nb, t + 1, 0); SBq(nb, t + 1, 1); SBq(nb, t + 1, 2);             \
              SBq(nb, t + 1, 3); SAq(nb, t + 1, 0); SAq(nb, t + 1, 2); }           \
    asm volatile("s_waitcnt lgkmcnt(0)" ::: "memory");                             \
    __builtin_amdgcn_s_setprio(1);                                                 \
    _Pragma("unroll")                                                              \
    for (int ks = 0; ks < 2; ++ks)                                                 \
      _Pragma("unroll")                                                            \
      for (int mi = 0; mi < 2; ++mi)                                               \
        _Pragma("unroll")                                                          \
        for (int ni = 0; ni < 4; ++ni)                                             \
          acc[mi][ni] = __builtin_amdgcn_mfma_f32_16x16x32_f16(af[mi][ks],         \
                            bf[ni][ks], acc[mi][ni], 0, 0, 0);                     \
    __builtin_amdgcn_s_setprio(0);                                                 \
    asm volatile("s_barrier" ::: "memory");                                        \
    if (st) asm volatile("s_waitcnt vmcnt(6)" ::: "memory");                       \
    else    asm volatile("s_waitcnt vmcnt(0)" ::: "memory");                       \
    asm volatile("s_barrier" ::: "memory");                                        \
    _Pragma("unroll")                                                              \
    for (int mi = 0; mi < 2; ++mi) {                                               \
      af[mi][0] = *(const f16x8*)(asb + (wm * 64 + (mi + 2) * 16 + lr) * 64 + kc0);\
      af[mi][1] = *(const f16x8*)(asb + (wm * 64 + (mi + 2) * 16 + lr) * 64 + kc1);\
    }                                                                              \
    if (st) { SAq(nb, t + 1, 1); SAq(nb, t + 1, 3); }                              \
    asm volatile("s_waitcnt lgkmcnt(0)" ::: "memory");                             \
    __builtin_amdgcn_s_setprio(1);                                                 \
    _Pragma("unroll")                                                              \
    for (int ks = 0; ks < 2; ++ks)                                                 \
      _Pragma("unroll")                                                            \
      for (int mi = 0; mi < 2; ++mi)                                               \
        _Pragma("unroll")                                                          \
        for (int ni = 0; ni < 4; ++ni)                                             \
          acc[mi + 2][ni] = __builtin_amdgcn_mfma_f32_16x16x32_f16(af[mi][ks],     \
                                bf[ni][ks], acc[mi + 2][ni], 0, 0, 0);             \
    __builtin_amdgcn_s_setprio(0);                                                 \
    asm volatile("s_barrier" ::: "memory");                                        \
    cur ^= 1;                                                                      \
  }

// ---------------- MERGED A: T1_b = U x G_b  (bid<256)  +  gemv3b cluster (bid>=256) ----------------
__global__ __launch_bounds__(256) void gemmT1_g3b(
    const f16* __restrict__ U, const f16* __restrict__ Gh, f16* __restrict__ T1,
    const f16* __restrict__ PWv, const float* __restrict__ hs,
    const float* __restrict__ ayd, float* __restrict__ efz,
    float* __restrict__ scal) {
  GP64_COMMON();
  __shared__ __align__(16) f16 As[2][8192];
  __shared__ __align__(16) f16 Bs[2][8192];

  const int bid = blockIdx.x;
  if (bid >= 256) {
    const int u = (bid - 256) * 4 + wave;     // 0..12291
    if (u >= 12288) {
      const int b = u - 12288;
      float s = dotf1024(hs + b * 1024, ayd + 1024);
      if (lane == 0) scal[b] = s;
      return;
    }
    const int sel = u >> 12, r = u & 4095;
    const int b = r >> 10, m = r & 1023;
    const f16* row;
    const float* v;
    if (sel == 0)      { row = U + (long)m * 1024;                       v = hs + b * 1024; }
    else if (sel == 1) { row = PWv + (long)m * 1024;                     v = hs + b * 1024; }
    else               { row = Gh + (long)b * 1048576 + (long)m * 1024;  v = ayd + 1024; }
    float s = dot1024(row, v);
    if (lane == 0) efz[sel * 4096 + r] = s;
    return;
  }

  const int ny = bid & 7, nx = (bid >> 3) & 7, b = bid >> 6;
  const int wm = wave >> 1, wn = wave & 1;
  const f16* Ab = U + (long)(ny * 128 + srow) * 1024 + slc * 8;
  const f16* Bb = Gh + (long)b * 1048576 + (long)(nx * 128 + srow) * 1024 + slc * 8;

  f32x4 zero = {0.f, 0.f, 0.f, 0.f};
  f32x4 acc[4][4];
#pragma unroll
  for (int mi = 0; mi < 4; ++mi)
#pragma unroll
    for (int ni = 0; ni < 4; ++ni) acc[mi][ni] = zero;

#define SAq(buf, kt, q) gl_lds16(Ab + (long)(q) * 32768 + (kt) * 64, &As[buf][(q) * 2048] + tid * 8)
#define SBq(buf, kt, q) gl_lds16(Bb + (long)(q) * 32768 + (kt) * 64, &Bs[buf][(q) * 2048] + tid * 8)
  FINE2_LOOP(16)
#undef SAq
#undef SBq

  f16* C = T1 + (long)b * 1048576;
  const int m0 = ny * 128 + wm * 64;
  const int n0 = nx * 128 + wn * 64;
#pragma unroll
  for (int mi = 0; mi < 4; ++mi)
#pragma unroll
    for (int ni = 0; ni < 4; ++ni)
#pragma unroll
      for (int j = 0; j < 4; ++j) {
        const int gm = m0 + mi * 16 + lk * 4 + j;
        const int gn = n0 + ni * 16 + lr;
        C[(long)gm * 1024 + gn] = (f16)acc[mi][ni][j];
      }
}

// ---------------- MERGED B: W2T_b = (PWv x T1_b + rank-1)/32 (bid<256) + c2 gemv (bid>=256) ----------------
__global__ __launch_bounds__(256) void gemmW2_c2(
    const f16* __restrict__ PWv, const f16* __restrict__ T1, f16* __restrict__ T2,
    const float* __restrict__ ayd, const float* __restrict__ efz,
    const float* __restrict__ scal, const float* __restrict__ proj_b,
    float* __restrict__ c2v) {
  GP64_COMMON();
  __shared__ __align__(16) f16 As[2][8192];
  __shared__ __align__(16) f16 Bs[2][8192];

  const int bid = blockIdx.x;
  if (bid >= 256) {
    const int u = (bid - 256) * 4 + wave;     // 0..4095
    const int b = u >> 10, c = u & 1023;
    float s = dot1024(PWv + (long)c * 1024, efz + 8192 + b * 1024);
    if (lane == 0) {
      const float d = ayd[2048 + c];
      c2v[b * 1024 + c] = (s + d * scal[b] + scal[4] * (efz[4096 + b * 1024 + c] + 4096.f * d))
                            * 0.03125f + proj_b[c];
    }
    return;
  }

  const int ny = bid & 7, nx = (bid >> 3) & 7, b = bid >> 6;
  const int wm = wave >> 1, wn = wave & 1;
  const f16* Ab = PWv + (long)(ny * 128 + srow) * 1024 + slc * 8;
  const f16* Bb = T1 + (long)b * 1048576 + (long)(nx * 128 + srow) * 1024 + slc * 8;

  f32x4 zero = {0.f, 0.f, 0.f, 0.f};
  f32x4 acc[4][4];
#pragma unroll
  for (int mi = 0; mi < 4; ++mi)
#pragma unroll
    for (int ni = 0; ni < 4; ++ni) acc[mi][ni] = zero;

#define SAq(buf, kt, q) gl_lds16(Ab + (long)(q) * 32768 + (kt) * 64, &As[buf][(q) * 2048] + tid * 8)
#define SBq(buf, kt, q) gl_lds16(Bb + (long)(q) * 32768 + (kt) * 64, &Bs[buf][(q) * 2048] + tid * 8)
  FINE2_LOOP(16)
#undef SAq
#undef SBq

  f16* C = T2 + (long)b * 1048576;
  const int m0 = ny * 128 + wm * 64;
  const int n0 = nx * 128 + wn * 64;
#pragma unroll
  for (int mi = 0; mi < 4; ++mi)
#pragma unroll
    for (int ni = 0; ni < 4; ++ni)
#pragma unroll
      for (int j = 0; j < 4; ++j) {
        const int gm = m0 + mi * 16 + lk * 4 + j;
        const int gn = n0 + ni * 16 + lr;
        const float dm = ayd[2048 + gm];
        const float fm = efz[4096 + b * 1024 + gm];
        const float en = efz[b * 1024 + gn];
        const float an = ayd[gn];
        float val = (acc[mi][ni][j] + dm * en + (fm + 4096.f * dm) * an) * 0.03125f;
        C[(long)gm * 1024 + gn] = (f16)val;
      }
}

// ---------------- MERGED: G = H^T H (tri, split-K=4) + {U, PWv}; fine 2-phase pipeline ----------------
__global__ __launch_bounds__(256) void gemmGUV(const f16* __restrict__ Ht,
                                               const f16* __restrict__ WT3,
                                               const f16* __restrict__ Ph,
                                               f16* __restrict__ part,
                                               f16* __restrict__ U,
                                               f16* __restrict__ PWv) {
  GP64_COMMON();
  const int wm = wave >> 1, wn = wave & 1;

  __shared__ __align__(16) f16 As[2][8192];
  __shared__ __align__(16) f16 Bs[2][8192];

  const int bid = blockIdx.x;
  const f16 *Ab, *Bb;
  long rs;
  int tileid = 0, zz = 0, selt = 0;
  if (bid < 576) {
    zz = bid & 15;           // K-slice*4 + batch  (XCD class = zz%8)
    tileid = bid >> 4;       // 0..35 triangular tile
    const int b = zz & 3, ks4 = zz >> 2;
    int ti = 0, trem = tileid;
    while (trem >= 8 - ti) { trem -= 8 - ti; ++ti; }
    const int tj = ti + trem;
    const f16* Hb = Ht + (long)b * 4194304;
    rs = 4096;
    Ab = Hb + (long)(ti * 128 + srow) * 4096 + (long)ks4 * 1024 + slc * 8;
    Bb = Hb + (long)(tj * 128 + srow) * 4096 + (long)ks4 * 1024 + slc * 8;
  } else {
    const int u = bid - 576;
    selt = (u >> 6) + 1;                 // 1: U, 2: PWv
    const int t = u & 63;
    const int ny = t >> 3, nxx = t & 7;
    const f16* A0 = (selt == 2) ? Ph : WT3;
    const f16* B0 = (selt == 2) ? (WT3 + 2097152) : (WT3 + 1048576);
    rs = 1024;
    Ab = A0 + (long)(ny * 128 + srow) * 1024 + slc * 8;
    Bb = B0 + (long)(nxx * 128 + srow) * 1024 + slc * 8;
  }

  f32x4 zero = {0.f, 0.f, 0.f, 0.f};
  f32x4 acc[4][4];
#pragma unroll
  for (int mi = 0; mi < 4; ++mi)
#pragma unroll
    for (int ni = 0; ni < 4; ++ni) acc[mi][ni] = zero;

#define SAq(buf, kt, q) gl_lds16(Ab + (long)(q) * 32 * rs + (kt) * 64, &As[buf][(q) * 2048] + tid * 8)
#define SBq(buf, kt, q) gl_lds16(Bb + (long)(q) * 32 * rs + (kt) * 64, &Bs[buf][(q) * 2048] + tid * 8)
  FINE2_LOOP(16)
#undef SAq
#undef SBq

  if (selt == 0) {
    f16* P = part + ((long)zz * 36 + tileid) * 16384;
#pragma unroll
    for (int mi = 0; mi < 4; ++mi)
#pragma unroll
      for (int ni = 0; ni < 4; ++ni)
#pragma unroll
        for (int j = 0; j < 4; ++j) {
          const int gm = wm * 64 + mi * 16 + lk * 4 + j;
          const int gn = wn * 64 + ni * 16 + lr;
          P[gm * 128 + gn] = (f16)acc[mi][ni][j];
        }
  } else {
    const int u = bid - 576;
    const int t = u & 63;
    const int ny = t >> 3, nxx = t & 7;
    f16* C = (selt == 2) ? PWv : U;
    const int m0 = ny * 128 + wm * 64;
    const int n0 = nxx * 128 + wn * 64;
#pragma unroll
    for (int mi = 0; mi < 4; ++mi)
#pragma unroll
      for (int ni = 0; ni < 4; ++ni)
#pragma unroll
        for (int j = 0; j < 4; ++j) {
          const int gm = m0 + mi * 16 + lk * 4 + j;
          const int gn = n0 + ni * 16 + lr;
          C[(long)gm * 1024 + gn] = (f16)acc[mi][ni][j];
        }
  }
}

// ---------------- FINAL GEMM: 256x256 tile, 8 waves, BK=64, fine 4-phase with correct sync ----------------
__global__ __launch_bounds__(512) void gemm256f(
    const f16* __restrict__ A,       // H flat [16384][1024]
    const f16* __restrict__ Bw,      // W2T [4][1024][1024]
    const float* __restrict__ resid,
    const float* __restrict__ c2v,
    float* __restrict__ outF) {
  const int lin = blockIdx.y * 4 + blockIdx.x;
  const int xcd = lin & 7, slot = lin >> 3;
  const int ny = xcd * 8 + (slot >> 2);          // 0..63  (M tile)
  const int nx = slot & 3;                       // 0..3   (N tile)
  const int bb = ny >> 4;

  GP64_COMMON();
  const int wm = wave >> 2, wn = wave & 3;       // 2 x 4 wave grid

  __shared__ __align__(16) f16 As[2][16384];
  __shared__ __align__(16) f16 Bs[2][16384];

  const f16* Ab = A + (long)ny * 262144;
  const f16* Bb = Bw + (long)bb * 1048576 + (long)nx * 262144;
  const long offs = (long)srow * 1024 + slc * 8;

  f32x4 zero = {0.f, 0.f, 0.f, 0.f};
  f32x4 acc[8][4];
#pragma unroll
  for (int mi = 0; mi < 8; ++mi)
#pragma unroll
    for (int ni = 0; ni < 4; ++ni) acc[mi][ni] = zero;

#define SA(buf, kt, q) gl_lds16(Ab + offs + (long)(q) * 65536 + (kt) * 64, &As[buf][(q) * 4096] + tid * 8)
#define SB(buf, kt, q) gl_lds16(Bb + offs + (long)(q) * 65536 + (kt) * 64, &Bs[buf][(q) * 4096] + tid * 8)

#define RD_BF(dst, bsb, kc)                                                       \
  _Pragma("unroll")                                                               \
  for (int ni = 0; ni < 4; ++ni)                                                  \
    dst[ni] = *(const f16x8*)((bsb) + (wn * 64 + ni * 16 + lr) * 64 + (kc));
#define RD_AF(dst, asb, mh, kc)                                                   \
  _Pragma("unroll")                                                               \
  for (int mi = 0; mi < 4; ++mi)                                                  \
    dst[mi] = *(const f16x8*)((asb) + (wm * 128 + (mh) * 64 + mi * 16 + lr) * 64 + (kc));
#define MF16(af_, bf_, mo)                                                        \
  __builtin_amdgcn_s_setprio(1);                                                  \
  _Pragma("unroll")                                                               \
  for (int mi = 0; mi < 4; ++mi)                                                  \
    _Pragma("unroll")                                                             \
    for (int ni = 0; ni < 4; ++ni)                                                \
      acc[(mo) + mi][ni] = __builtin_amdgcn_mfma_f32_16x16x32_f16(af_[mi], bf_[ni], \
                                                                  acc[(mo) + mi][ni], 0, 0, 0); \
  __builtin_amdgcn_s_setprio(0);

  const int nt = 16;
  // prologue: stage tile 0 in consumption order
  SB(0, 0, 0); SB(0, 0, 1); SB(0, 0, 2); SB(0, 0, 3);
  SA(0, 0, 0); SA(0, 0, 2); SA(0, 0, 1); SA(0, 0, 3);

  int cur = 0;
  for (int t = 0; t < nt; ++t) {
    const f16* asb = &As[cur][0];
    const f16* bsb = &Bs[cur][0];
    const int nb = cur ^ 1;
    const bool st = (t + 1 < nt);
    f16x8 bf[4], af[4];

    // ---- P0: (mh0, ks0) ----
    asm volatile("s_waitcnt vmcnt(2)" ::: "memory");   // 6 oldest of tile t landed (per wave)
    asm volatile("s_barrier" ::: "memory");            // ...for ALL waves -> B0-3,A0,A2 readable
    RD_BF(bf, bsb, kc0);
    RD_AF(af, asb, 0, kc0);
    if (st) { SB(nb, t + 1, 0); SB(nb, t + 1, 1); }
    asm volatile("s_waitcnt lgkmcnt(0)" ::: "memory");
    MF16(af, bf, 0);
    asm volatile("s_barrier" ::: "memory");

    // ---- P1: (mh1, ks0) ----
    if (st) asm volatile("s_waitcnt vmcnt(2)" ::: "memory");  // A1,A3 of tile t landed
    else    asm volatile("s_waitcnt vmcnt(0)" ::: "memory");  // last iter: only A1,A3 outstanding
    asm volatile("s_barrier" ::: "memory");
    RD_AF(af, asb, 1, kc0);
    if (st) { SB(nb, t + 1, 2); SB(nb, t + 1, 3); }
    asm volatile("s_waitcnt lgkmcnt(0)" ::: "memory");
    MF16(af, bf, 4);
    asm volatile("s_barrier" ::: "memory");

    // ---- P2: (mh0, ks1) — quadrants already verified ----
    RD_BF(bf, bsb, kc1);
    RD_AF(af, asb, 0, kc1);
    if (st) { SA(nb, t + 1, 0); SA(nb, t + 1, 2); }
    asm volatile("s_waitcnt lgkmcnt(0)" ::: "memory");
    MF16(af, bf, 0);
    asm volatile("s_barrier" ::: "memory");

    // ---- P3: (mh1, ks1) ----
    RD_AF(af, asb, 1, kc1);
    if (st) { SA(nb, t + 1, 1); SA(nb, t + 1, 3); }
    asm volatile("s_waitcnt lgkmcnt(0)" ::: "memory");
    MF16(af, bf, 4);
    asm volatile("s_barrier" ::: "memory");

    cur ^= 1;
  }
#undef SA
#undef SB
#undef RD_BF
#undef RD_AF
#undef MF16

  // drain any residual DMA before reusing LDS
  asm volatile("s_waitcnt vmcnt(0)" ::: "memory");
  asm volatile("s_barrier" ::: "memory");

  // -------- LDS-staged vectorized epilogue (reuses As) --------
  float* weps = ((float*)&As[0][0]) + wave * 1088;
  const int m0 = ny * 256 + wm * 128;
  const int n0 = nx * 256 + wn * 64;
  const int err = lane >> 3;
  const int ecc = (lane & 7) * 4;
  float4 cc2[2];
#pragma unroll
  for (int q = 0; q < 2; ++q)
    cc2[q] = *(const float4*)&c2v[bb * 1024 + n0 + ecc + 32 * q];

#pragma unroll
  for (int mi = 0; mi < 8; ++mi) {
#pragma unroll
    for (int ni = 0; ni < 4; ++ni)
#pragma unroll
      for (int j = 0; j < 4; ++j)
        weps[(lk * 4 + j) * 68 + ni * 16 + lr] = acc[mi][ni][j];
    asm volatile("s_waitcnt lgkmcnt(0)" ::: "memory");
#pragma unroll
    for (int h = 0; h < 2; ++h)
#pragma unroll
      for (int q = 0; q < 2; ++q) {
        const int rr = err + 8 * h;
        const int cc = ecc + 32 * q;
        float4 o = *(const float4*)&weps[rr * 68 + cc];
        const long gbase = (long)(m0 + mi * 16 + rr) * 1024 + n0 + cc;
        const float4 rv = *(const float4*)&resid[gbase];
        float4 ov;
        ov.x = o.x + rv.x + cc2[q].x;
        ov.y = o.y + rv.y + cc2[q].y;
        ov.z = o.z + rv.z + cc2[q].z;
        ov.w = o.w + rv.w + cc2[q].w;
        *(float4*)&outF[gbase] = ov;
      }
  }
}

// ---------------- reduce triangular G partials -> Gh, mirror ----------------
__global__ __launch_bounds__(256) void treduce(const f16* __restrict__ part,
                                               f16* __restrict__ Gh) {
  const int tileid = blockIdx.x, b = blockIdx.y;
  int ti = 0, trem = tileid;
  while (trem >= 8 - ti) { trem -= 8 - ti; ++ti; }
  const int tj = ti + trem;
  __shared__ f16 tl[128][132];
  const int tid = threadIdx.x;
  f16* Gb = Gh + (long)b * 1048576;
#pragma unroll
  for (int it = 0; it < 16; ++it) {
    const int e = it * 1024 + tid * 4;
    const int r = e >> 7, c = e & 127;
    f16x4 p0 = *(const f16x4*)(part + ((long)(0 * 4 + b) * 36 + tileid) * 16384 + e);
    f16x4 p1 = *(const f16x4*)(part + ((long)(1 * 4 + b) * 36 + tileid) * 16384 + e);
    f16x4 p2 = *(const f16x4*)(part + ((long)(2 * 4 + b) * 36 + tileid) * 16384 + e);
    f16x4 p3 = *(const f16x4*)(part + ((long)(3 * 4 + b) * 36 + tileid) * 16384 + e);
    f16x4 sv;
#pragma unroll
    for (int j = 0; j < 4; ++j)
      sv[j] = (f16)((float)p0[j] + (float)p1[j] + (float)p2[j] + (float)p3[j]);
    *(f16x4*)(Gb + (long)(ti * 128 + r) * 1024 + tj * 128 + c) = sv;
    *(f16x4*)&tl[r][c] = sv;
  }
  if (ti != tj) {
    __syncthreads();
#pragma unroll
    for (int it = 0; it < 16; ++it) {
      const int e = it * 1024 + tid * 4;
      const int r = e >> 7, c = e & 127;
      f16x4 v;
      v[0] = tl[c + 0][r];
      v[1] = tl[c + 1][r];
      v[2] = tl[c + 2][r];
      v[3] = tl[c + 3][r];
      *(f16x4*)(Gb + (long)(tj * 128 + r) * 1024 + ti * 128 + c) = v;
    }
  }
}

extern "C" void kernel_launch(void* const* d_in, const int* in_sizes, int n_in,
                              void* d_out, int out_size, void* d_ws, size_t ws_size,
                              hipStream_t stream) {
  const float* x      = (const float*)d_in[0];
  const float* norm_w = (const float*)d_in[1];
  const float* norm_b = (const float*)d_in[2];
  const float* qkv_w  = (const float*)d_in[3];
  const float* qkv_b  = (const float*)d_in[4];
  const float* proj_w = (const float*)d_in[5];
  const float* proj_b = (const float*)d_in[6];
  float* out = (float*)d_out;
  char* ws = (char*)d_ws;

  const size_t OFF_H    = 0;
  const size_t OFF_HT   = 33554432;
  const size_t OFF_T1   = 33554432;   // alias (Ht dead after gemmGUV)
  const size_t OFF_T2   = 41943040;
  const size_t OFF_PH   = 73400320;
  const size_t OFF_WT3  = 75497472;
  const size_t OFF_U    = 81788928;
  const size_t OFF_PWV  = 83886080;
  const size_t OFF_GH   = 85983232;
  const size_t OFF_PART = 94371840;
  const size_t OFF_HS   = 115343360;
  const size_t OFF_AYD  = 115392512;
  const size_t OFF_SCAL = 115404800;
  const size_t OFF_EFZ  = 115405824;
  const size_t OFF_C2   = 115471360;

  f16* H    = (f16*)(ws + OFF_H);
  f16* Ht   = (f16*)(ws + OFF_HT);
  f16* T1   = (f16*)(ws + OFF_T1);
  f16* T2   = (f16*)(ws + OFF_T2);
  f16* Ph   = (f16*)(ws + OFF_PH);
  f16* WT3  = (f16*)(ws + OFF_WT3);
  f16* U    = (f16*)(ws + OFF_U);
  f16* PWv  = (f16*)(ws + OFF_PWV);
  f16* Gh   = (f16*)(ws + OFF_GH);
  f16* part = (f16*)(ws + OFF_PART);
  float* hs   = (float*)(ws + OFF_HS);
  float* ayd  = (float*)(ws + OFF_AYD);
  float* scal = (float*)(ws + OFF_SCAL);
  float* efz  = (float*)(ws + OFF_EFZ);
  float* c2v  = (float*)(ws + OFF_C2);

  // merged prep: ln (4096 blocks, blk0 zeroes hs) + weight transcast (1024 blocks)
  prep_kernel<<<dim3(5120), 256, 0, stream>>>(x, norm_w, norm_b, H, hs,
                                              qkv_w, proj_w, WT3, Ph);
  // merged: transpose_cs (4096 blocks) + gemv3a (769 blocks)
  tcgemv_kernel<<<dim3(4865), 256, 0, stream>>>(H, Ht, hs, WT3, Ph, qkv_b, ayd, scal);

  // merged: G tri-tiles (576 blocks, XCD-clustered by K-slice) + U/PWv (128 blocks)
  gemmGUV<<<dim3(704), 256, 0, stream>>>(Ht, WT3, Ph, part, U, PWv);
  treduce<<<dim3(36, 4), 256, 0, stream>>>(part, Gh);

  // merged A: T1_b = U x G_b (256 blocks) + gemv3b cluster (3073 blocks)
  gemmT1_g3b<<<dim3(3329), 256, 0, stream>>>(U, Gh, T1, PWv, hs, ayd, efz, scal);
  // merged B: W2T_b = (PWv x T1_b + rank-1)/32 (256 blocks) + c2 gemv (1024 blocks)
  gemmW2_c2<<<dim3(1280), 256, 0, stream>>>(PWv, T1, T2, ayd, efz, scal, proj_b, c2v);

  // out = X + H (x) W2T + c2
  gemm256f<<<dim3(4, 64), 512, 0, stream>>>(H, T2, x, c2v, out);
}